// Round 11
// baseline (2386.281 us; speedup 1.0000x reference)
//
#include <hip/hip_runtime.h>
#include <hip/hip_bf16.h>

typedef _Float16 f16x8 __attribute__((ext_vector_type(8)));
typedef _Float16 f16x4 __attribute__((ext_vector_type(4)));
typedef float f32x4 __attribute__((ext_vector_type(4)));

#define BN_S 0.99999500003749975f  // 1/sqrt(1+1e-5)

__device__ inline f16x8 f16x8_zero() {
  f16x8 v = {(_Float16)0.f, (_Float16)0.f, (_Float16)0.f, (_Float16)0.f,
             (_Float16)0.f, (_Float16)0.f, (_Float16)0.f, (_Float16)0.f};
  return v;
}

__device__ __forceinline__ void load_lds16(const _Float16* g, _Float16* l) {
  __builtin_amdgcn_global_load_lds(
      (const __attribute__((address_space(1))) void*)g,
      (__attribute__((address_space(3))) void*)l, 16, 0, 0);
}

__global__ void zero_out_k(float* __restrict__ out, int n) {
  const int idx = blockIdx.x * 256 + threadIdx.x;
  if (idx < n) out[idx] = 0.f;
}

// zero n16 16-byte blocks
__global__ void zero16_k(_Float16* __restrict__ p, int n16) {
  const int idx = blockIdx.x * 256 + threadIdx.x;
  if (idx < n16) ((f16x8*)p)[idx] = f16x8_zero();
}

// ---------------------------------------------------------------------------
// Weight transform: OIHW fp32 -> [25][O][C] fp16, pre-scaled by g*BN_S.
// ---------------------------------------------------------------------------
__global__ void wtrans16(const float* __restrict__ src, _Float16* __restrict__ dst,
                         const float* __restrict__ g, int O, int C, int total) {
  const int idx = blockIdx.x * 256 + threadIdx.x;  // (t, o, c)
  if (idx >= total) return;
  const int OC = O * C;
  const int t = idx / OC;
  const int rem = idx - t * OC;
  const int o = rem / C;
  const int c = rem - o * C;
  dst[idx] = (_Float16)(src[(size_t)(o * C + c) * 25 + t] * g[o] * BN_S);
}

// conv8 weights: OIHW fp32 (O=3,C=384) -> [48 chunks][25 taps][3][8] fp16.
__global__ void wtrans8(const float* __restrict__ src, _Float16* __restrict__ dst,
                        const float* __restrict__ g) {
  const int idx = blockIdx.x * 256 + threadIdx.x;
  if (idx >= 28800) return;
  const int c = idx / 600;
  const int r = idx - c * 600;
  const int tap = r / 24;
  const int q = r - tap * 24;
  const int o = q >> 3, j = q & 7;
  const int cin = (c < 16) ? (c * 8 + j) : (128 + (c - 16) * 8 + j);
  dst[idx] = (_Float16)(src[((size_t)o * 384 + cin) * 25 + tap] * g[o] * BN_S);
}

// ---------------------------------------------------------------------------
// Implicit-GEMM 5x5 conv + BN + ReLU.  Cin%(32*KS)==0, Cout%BM==0, px%BN==0.
// Block tile BM(cout) x BN(px); 4 waves 2x2; KS k-steps staged per barrier
// into double-buffered LDS via global_load_lds(16B). XOR-swizzled LDS.
// TAG gives each layer a distinct symbol for profiling.
// Tile-shrink rule (r5/r9): shrink BM (re-reads small activation panel),
// never BN (re-reads large weight panel -> 6x FETCH blowup).
// XCD swizzle (T1): each XCD owns a contiguous x-major chunk -> weight
// panel cached once per XCD L2. Requires grid total % 8 == 0 (all sites).
// ---------------------------------------------------------------------------
template <int MF, int NF, int KS, int TAG>
__global__ __launch_bounds__(256) void conv_gemm(
    const _Float16* __restrict__ in, const _Float16* __restrict__ wt,
    const float* __restrict__ gg, const float* __restrict__ bbv,
    const float* __restrict__ ev, _Float16* __restrict__ out,
    int Cin, int Cout, int lw, int lh,
    int inS, int Wpi, int bsi, int ibase,
    int outS, int outOff, int Wpo, int bso, int obase) {
  constexpr int BM = MF * 32;
  constexpr int BN = NF * 32;
  constexpr int SUB_A = BM * 32;  // halfwords per k-substep
  constexpr int SUB_B = BN * 32;
  __shared__ _Float16 sA[2][SUB_A * KS];
  __shared__ _Float16 sB[2][SUB_B * KS];

  const int tid = threadIdx.x;
  const int lane = tid & 63;
  const int wid = tid >> 6;
  const int wm = wid >> 1, wn = wid & 1;
  const int lr = lane >> 4, lc = lane & 15;

  // XCD-aware bijective block swizzle (total blocks % 8 == 0 at every site)
  int bx, by;
  {
    const int gx = gridDim.x;
    const int flat = blockIdx.y * gx + blockIdx.x;
    const int q = (gx * gridDim.y) >> 3;
    const int nf = (flat & 7) * q + (flat >> 3);
    bx = nf % gx;
    by = nf / gx;
  }
  const int n0 = bx * BN;
  const int m0 = by * BM;
  const int H = 1 << lh, W = 1 << lw;
  const int nkb = Cin >> 5;

  // staging identity: linear g = issue*256 + tid; row=g>>2, slot=g&3
  const int r0 = tid >> 2;
  const int chunk = (tid & 3) ^ ((r0 >> 1) & 3);  // same for row r0+64

  const _Float16* a0 = wt + (size_t)(m0 + r0) * Cin + (chunk << 3);
  const _Float16* a1 = a0 + ((size_t)Cin << 6);  // used only if BM==128
  const int t0off = -2 * Wpi - 2;  // tap (dy=0,dx=0)
  const _Float16 *b0, *b1 = nullptr;
  {
    int n = n0 + r0;
    int pix0 = (n >> (lw + lh)) * bsi + ((n >> lw) & (H - 1)) * Wpi + (n & (W - 1)) + ibase;
    b0 = in + (size_t)(pix0 + t0off) * inS + (chunk << 3);
    if constexpr (BN == 128) {
      n = n0 + r0 + 64;
      int pix1 = (n >> (lw + lh)) * bsi + ((n >> lw) & (H - 1)) * Wpi + (n & (W - 1)) + ibase;
      b1 = in + (size_t)(pix1 + t0off) * inS + (chunk << 3);
    }
  }

  // ds_read fragment swizzle (halfwords)
  const int swz = (lr ^ ((lc >> 1) & 3)) << 3;

  f32x4 acc[MF][NF];
  const f32x4 vz = {0.f, 0.f, 0.f, 0.f};
#pragma unroll
  for (int i = 0; i < MF; ++i)
#pragma unroll
    for (int j = 0; j < NF; ++j) acc[i][j] = vz;

  const int np = 25 * nkb / KS;  // staged groups
  int kb = 0, dx = 0;
  const size_t a_tap = (size_t)Cout * Cin - ((size_t)nkb << 5);
  const int woff = wid << 9;  // wave LDS base within a 4KB issue (halfwords)

  // advance staging pointers by one group (KS k-steps)
  auto advance = [&]() {
    a0 += 32 * KS; b0 += 32 * KS;
    if constexpr (BM == 128) a1 += 32 * KS;
    if constexpr (BN == 128) b1 += 32 * KS;
    kb += KS;
    if (kb == nkb) {
      kb = 0;
      a0 += a_tap;
      if constexpr (BM == 128) a1 += a_tap;
      int pd;
      if (++dx == 5) { dx = 0; pd = Wpi - 4; } else pd = 1;
      const ptrdiff_t bd = (ptrdiff_t)pd * inS - ((ptrdiff_t)nkb << 5);
      b0 += bd;
      if constexpr (BN == 128) b1 += bd;
    }
  };
  auto stage = [&](int buf) {
#pragma unroll
    for (int s = 0; s < KS; ++s) {
      _Float16* sa = sA[buf] + s * SUB_A + woff;
      _Float16* sb = sB[buf] + s * SUB_B + woff;
      load_lds16(a0 + 32 * s, sa);
      if constexpr (BM == 128) load_lds16(a1 + 32 * s, sa + 2048);
      load_lds16(b0 + 32 * s, sb);
      if constexpr (BN == 128) load_lds16(b1 + 32 * s, sb + 2048);
    }
  };

  // prologue: stage group 0 into buf 0
  stage(0);
  __syncthreads();

  int cur = 0;
  for (int t = 0; t < np; ++t) {
    if (t + 1 < np) {
      advance();
      stage(cur ^ 1);
    }
    const _Float16* pA = sA[cur];
    const _Float16* pB = sB[cur];
#pragma unroll
    for (int s = 0; s < KS; ++s) {
      f16x8 af[MF], bf[NF];
#pragma unroll
      for (int i = 0; i < MF; ++i)
        af[i] = *(const f16x8*)(pA + s * SUB_A + ((wm * (MF * 16) + (i << 4) + lc) << 5) + swz);
#pragma unroll
      for (int i = 0; i < NF; ++i)
        bf[i] = *(const f16x8*)(pB + s * SUB_B + ((wn * (NF * 16) + (i << 4) + lc) << 5) + swz);
#pragma unroll
      for (int mi = 0; mi < MF; ++mi)
#pragma unroll
        for (int ni = 0; ni < NF; ++ni)
          acc[mi][ni] =
              __builtin_amdgcn_mfma_f32_16x16x32_f16(af[mi], bf[ni], acc[mi][ni], 0, 0, 0);
    }
    __syncthreads();  // drains stage(cur^1) loads + fences buf reuse
    cur ^= 1;
  }

  // Epilogue: D col = lane&15 -> pixel, row = lr*4+j -> cout
#pragma unroll
  for (int mi = 0; mi < MF; ++mi) {
    const int ob = m0 + wm * (MF * 16) + (mi << 4) + (lr << 2);
    const f32x4 gv = *(const f32x4*)(gg + ob);
    const f32x4 bv = *(const f32x4*)(bbv + ob);
    const f32x4 evv = *(const f32x4*)(ev + ob);
#pragma unroll
    for (int ni = 0; ni < NF; ++ni) {
      const int n = n0 + wn * (NF * 16) + (ni << 4) + lc;
      const int y = (n >> lw) & (H - 1);
      const int x = n & (W - 1);
      const int bb_ = n >> (lw + lh);
      const size_t op = (size_t)(bb_ * bso + y * Wpo + x + obase) * outS + outOff + ob;
      f16x4 h;
#pragma unroll
      for (int j = 0; j < 4; ++j) {
        const float s = gv[j] * BN_S;
        float v = acc[mi][ni][j] + (bv[j] * s + evv[j]);
        v = v > 0.f ? v : 0.f;
        h[j] = (_Float16)v;
      }
      *(f16x4*)(out + op) = h;
    }
  }
}

// ---------------------------------------------------------------------------
// conv1: Cin=3, Cout=64, 512x512, fp32 NCHW data + raw fp32 weights.
// ---------------------------------------------------------------------------
__global__ __launch_bounds__(256) void conv1_k(
    const float* __restrict__ data, const float* __restrict__ w1,
    const float* __restrict__ g1, const float* __restrict__ b1,
    const float* __restrict__ e1, _Float16* __restrict__ out) {
  __shared__ float patch[3][20][20];
  const int tid = threadIdx.x;
  const int bid = blockIdx.x;
  const int tx = bid & 31, ty = (bid >> 5) & 31, b = bid >> 10;

  for (int i = tid; i < 1200; i += 256) {
    const int c = i / 400;
    const int r = i - c * 400;
    const int pyy = r / 20;
    const int pxx = r - pyy * 20;
    const int gy = (ty << 4) + pyy - 2, gx = (tx << 4) + pxx - 2;
    float v = 0.f;
    if ((unsigned)gy < 512u && (unsigned)gx < 512u)
      v = data[((size_t)(b * 3 + c) << 18) + (gy << 9) + gx];
    patch[c][pyy][pxx] = v;
  }
  __syncthreads();

  const int py = tid >> 4, px = tid & 15;
  float acc[64];
#pragma unroll
  for (int o = 0; o < 64; ++o) acc[o] = 0.f;

  for (int c = 0; c < 3; ++c)
    for (int dy = 0; dy < 5; ++dy) {
#pragma unroll
      for (int dx = 0; dx < 5; ++dx) {
        const float v = patch[c][py + dy][px + dx];
        const float* wb = w1 + c * 25 + dy * 5 + dx;
#pragma unroll
        for (int o = 0; o < 64; ++o) acc[o] = fmaf(v, wb[o * 75], acc[o]);
      }
    }

  const int y = (ty << 4) + py, x = (tx << 4) + px;
  _Float16* op = out + ((size_t)(((b << 9) + y) << 9) + x) * 64;
#pragma unroll
  for (int oc = 0; oc < 8; ++oc) {
    f16x8 h;
#pragma unroll
    for (int j = 0; j < 8; ++j) {
      const int o = (oc << 3) + j;
      const float s = g1[o] * BN_S;
      const float t = b1[o] * s + e1[o];
      float v = fmaf(acc[o], s, t);
      v = v > 0.f ? v : 0.f;
      h[j] = (_Float16)v;
    }
    *(f16x8*)(op + (oc << 3)) = h;
  }
}

// ---------------------------------------------------------------------------
// avg-pool 2x2 stride 2, NHWC fp16, generic padded/unpadded addressing
// ---------------------------------------------------------------------------
__global__ void pool_k(const _Float16* __restrict__ in, _Float16* __restrict__ out,
                       int inS, int outS, int Wpi, int bsi, int ibase,
                       int Wpo, int bso, int obase,
                       int lwo, int lho, int lcc, int total) {
  const int idx = blockIdx.x * 256 + threadIdx.x;
  if (idx >= total) return;
  const int cc = idx & ((1 << lcc) - 1);
  const int pix = idx >> lcc;
  const int x = pix & ((1 << lwo) - 1);
  const int y = (pix >> lwo) & ((1 << lho) - 1);
  const int b = pix >> (lwo + lho);
  const int ip = b * bsi + (y << 1) * Wpi + (x << 1) + ibase;
  const _Float16* p = in + (size_t)ip * inS + (cc << 3);
  const f16x8 v00 = *(const f16x8*)p;
  const f16x8 v01 = *(const f16x8*)(p + inS);
  const f16x8 v10 = *(const f16x8*)(p + (size_t)Wpi * inS);
  const f16x8 v11 = *(const f16x8*)(p + (size_t)(Wpi + 1) * inS);
  f16x8 r;
#pragma unroll
  for (int j = 0; j < 8; ++j)
    r[j] = (_Float16)(((float)v00[j] + (float)v01[j] + (float)v10[j] + (float)v11[j]) * 0.25f);
  const int op = b * bso + y * Wpo + x + obase;
  *(f16x8*)(out + (size_t)op * outS + (cc << 3)) = r;
}

// ---------------------------------------------------------------------------
// bilinear 2x upsample (align_corners=True), NHWC fp16
// ---------------------------------------------------------------------------
__global__ void up_k(const _Float16* __restrict__ in, _Float16* __restrict__ out,
                     int inS, int outS, int outOff,
                     int Wpi, int bsi, int ibase,
                     int Wpo, int bso, int obase,
                     int lwi, int lhi, int lcc, float scale, int total) {
  const int idx = blockIdx.x * 256 + threadIdx.x;
  if (idx >= total) return;
  const int cc = idx & ((1 << lcc) - 1);
  const int pix = idx >> lcc;
  const int lwo = lwi + 1, lho = lhi + 1;
  const int ox = pix & ((1 << lwo) - 1);
  const int oy = (pix >> lwo) & ((1 << lho) - 1);
  const int b = pix >> (lwo + lho);
  const int Hi = 1 << lhi, Wi = 1 << lwi;
  const float fy = oy * scale;
  const int y0 = (int)fy;
  const float wy = fy - y0;
  const int y1 = min(y0 + 1, Hi - 1);
  const float fx = ox * scale;
  const int x0 = (int)fx;
  const float wx = fx - x0;
  const int x1 = min(x0 + 1, Wi - 1);
  const int rbase = b * bsi + ibase;
  const _Float16* basep = in + (cc << 3);
  const f16x8 v00 = *(const f16x8*)(basep + (size_t)(rbase + y0 * Wpi + x0) * inS);
  const f16x8 v01 = *(const f16x8*)(basep + (size_t)(rbase + y0 * Wpi + x1) * inS);
  const f16x8 v10 = *(const f16x8*)(basep + (size_t)(rbase + y1 * Wpi + x0) * inS);
  const f16x8 v11 = *(const f16x8*)(basep + (size_t)(rbase + y1 * Wpi + x1) * inS);
  f16x8 r;
#pragma unroll
  for (int j = 0; j < 8; ++j) {
    const float top = (float)v00[j] * (1.f - wx) + (float)v01[j] * wx;
    const float bot = (float)v10[j] * (1.f - wx) + (float)v11[j] * wx;
    r[j] = (_Float16)(top * (1.f - wy) + bot * wy);
  }
  const int op = b * bso + oy * Wpo + ox + obase;
  *(f16x8*)(out + (size_t)op * outS + outOff + (cc << 3)) = r;
}

// ---------------------------------------------------------------------------
// conv8 (LDS-tiled): Cin=384 (= c2[128ch] ++ up7[256ch]), Cout=3, 256x256.
// ---------------------------------------------------------------------------
__global__ __launch_bounds__(256) void conv8_lds(
    const _Float16* __restrict__ inA, const _Float16* __restrict__ inB,
    const _Float16* __restrict__ wt, const float* __restrict__ b8,
    const float* __restrict__ g8, const float* __restrict__ e8,
    _Float16* __restrict__ out) {
  __shared__ f16x8 patch[2][20][20];
  const int tid = threadIdx.x;
  const int bid = blockIdx.x;  // 512
  const int tx = bid & 15, ty = (bid >> 4) & 15, b = bid >> 8;
  const int px = tid & 15, py = tid >> 4;
  const int x0 = tx << 4, y0 = ty << 4;

  float a0 = 0.f, a1 = 0.f, a2 = 0.f;
  for (int c = 0; c < 48; ++c) {
    const _Float16* sbase;
    int str;
    if (c < 16) { sbase = inA + ((size_t)b << 23) + (c << 3); str = 128; }
    else        { sbase = inB + ((size_t)b << 24) + ((c - 16) << 3); str = 256; }
    for (int i = tid; i < 400; i += 256) {
      const int pyy = i / 20, pxx = i - pyy * 20;
      const int gy = y0 + pyy - 2, gx = x0 + pxx - 2;
      f16x8 v = f16x8_zero();
      if ((unsigned)gy < 256u && (unsigned)gx < 256u)
        v = *(const f16x8*)(sbase + (size_t)((gy << 8) + gx) * str);
      patch[c & 1][pyy][pxx] = v;
    }
    __syncthreads();
    const _Float16* wb_c = wt + c * 600;
#pragma unroll
    for (int dy = 0; dy < 5; ++dy) {
#pragma unroll
      for (int dxx = 0; dxx < 5; ++dxx) {
        const f16x8 v = patch[c & 1][py + dy][px + dxx];
        const _Float16* wb = wb_c + (dy * 5 + dxx) * 24;
#pragma unroll
        for (int j = 0; j < 8; ++j) {
          const float f = (float)v[j];
          a0 = fmaf(f, (float)wb[j], a0);
          a1 = fmaf(f, (float)wb[8 + j], a1);
          a2 = fmaf(f, (float)wb[16 + j], a2);
        }
      }
    }
  }

  const float s0 = g8[0] * BN_S, t0 = b8[0] * s0 + e8[0];
  const float s1 = g8[1] * BN_S, t1 = b8[1] * s1 + e8[1];
  const float s2 = g8[2] * BN_S, t2 = b8[2] * s2 + e8[2];
  float r0 = a0 + t0, r1 = a1 + t1, r2 = a2 + t2;
  r0 = r0 > 0.f ? r0 : 0.f;
  r1 = r1 > 0.f ? r1 : 0.f;
  r2 = r2 > 0.f ? r2 : 0.f;
  f16x4 h;
  h[0] = (_Float16)r0; h[1] = (_Float16)r1; h[2] = (_Float16)r2; h[3] = (_Float16)0.f;
  const int opix = (b << 16) + ((y0 + py) << 8) + (x0 + px);
  *(f16x4*)(out + (size_t)opix * 4) = h;
}

// ---------------------------------------------------------------------------
// final: bilinear up(c8, 256->512) + 1x1 conv (wo,bo) + out = data*core (fp32)
// ---------------------------------------------------------------------------
__global__ void final_k(const float* __restrict__ data, const _Float16* __restrict__ c8,
                        const float* __restrict__ wo, const float* __restrict__ bo,
                        float* __restrict__ out) {
  const int idx = blockIdx.x * 256 + threadIdx.x;  // < 524288
  const int x = idx & 511, y = (idx >> 9) & 511, b = idx >> 18;
  const float sc = 255.f / 511.f;
  const float fy = y * sc;
  const int y0 = (int)fy;
  const float wy = fy - y0;
  const int y1 = min(y0 + 1, 255);
  const float fx = x * sc;
  const int x0 = (int)fx;
  const float wx = fx - x0;
  const int x1 = min(x0 + 1, 255);
  const f16x4 v00 = *(const f16x4*)(c8 + (size_t)((((b << 8) + y0) << 8) + x0) * 4);
  const f16x4 v01 = *(const f16x4*)(c8 + (size_t)((((b << 8) + y0) << 8) + x1) * 4);
  const f16x4 v10 = *(const f16x4*)(c8 + (size_t)((((b << 8) + y1) << 8) + x0) * 4);
  const f16x4 v11 = *(const f16x4*)(c8 + (size_t)((((b << 8) + y1) << 8) + x1) * 4);
  float u[3];
#pragma unroll
  for (int j = 0; j < 3; ++j) {
    const float top = (float)v00[j] * (1.f - wx) + (float)v01[j] * wx;
    const float bot = (float)v10[j] * (1.f - wx) + (float)v11[j] * wx;
    u[j] = top * (1.f - wy) + bot * wy;
  }
#pragma unroll
  for (int c = 0; c < 3; ++c) {
    const float core = bo[c] + wo[c * 3 + 0] * u[0] + wo[c * 3 + 1] * u[1] + wo[c * 3 + 2] * u[2];
    const size_t oi = ((size_t)(b * 3 + c) << 18) + (y << 9) + x;
    out[oi] = data[oi] * core;
  }
}

// ---------------------------------------------------------------------------
extern "C" void kernel_launch(void* const* d_in, const int* in_sizes, int n_in,
                              void* d_out, int out_size, void* d_ws, size_t ws_size,
                              hipStream_t stream) {
  const float* data = (const float*)d_in[0];
  const float *w[9], *bb[9], *gg[9], *ee[9];
  for (int n = 1; n <= 8; ++n) {
    w[n] = (const float*)d_in[1 + (n - 1) * 4];
    bb[n] = (const float*)d_in[2 + (n - 1) * 4];
    gg[n] = (const float*)d_in[3 + (n - 1) * 4];
    ee[n] = (const float*)d_in[4 + (n - 1) * 4];
  }
  const float* wo = (const float*)d_in[33];
  const float* bo = (const float*)d_in[34];
  float* out = (float*)d_out;
  (void)in_sizes; (void)n_in;

  // ---- workspace layout (aliased; padded activations; 194,810,112 B) ----
  // LIVENESS NOTE (r9 lesson): cat7's c3-half is live conv3 -> conv7 (skip
  // connection); the cat7 region must NOT be reused between those points.
  const size_t NEEDED = 194810112ull;
  if (ws_size < NEEDED) {
    zero_out_k<<<(out_size + 255) / 256, 256, 0, stream>>>(out, out_size);
    return;
  }
  char* base = (char*)d_ws;
  size_t off = 0;
  auto alloc = [&](size_t bytes) -> char* {
    char* p = base + off;
    off += (bytes + 255) & ~(size_t)255;
    return p;
  };
  _Float16* W2t = (_Float16*)alloc(409600);     // 25*128*64*2
  _Float16* W3t = (_Float16*)alloc(1638400);    // 25*256*128*2
  _Float16* W4t = (_Float16*)alloc(6553600);    // 25*512*256*2
  _Float16* W5t = (_Float16*)alloc(13107200);   // 25*512*512*2
  _Float16* W6t = (_Float16*)alloc(26214400);   // 25*512*1024*2
  _Float16* W7t = (_Float16*)alloc(9830400);    // 25*256*768*2
  _Float16* W8t = (_Float16*)alloc(57600);      // 48*25*24 fp16
  char* Rbig = alloc(72466432);   // c1(67.1M) | cat7(53.5M)+cat6(18.9M) | up7(67.1M)
  char* c2b_ = alloc(33554432);   // c2 (2,256,256,128) unpadded
  char* R1 = alloc(17305600);     // p1(17.3M) | c6(8.4M) | c7(16.8M) | c8(1M)
  char* R2 = alloc(13672448);     // p2(8.9M) ; [p3(4.7M) | p4(2.65M)+c5(2.1M)]

  _Float16* c1 = (_Float16*)Rbig;                    // (2,512,512,64) unpadded
  _Float16* cat7 = (_Float16*)Rbig;                  // (2,132,132,768) padded
  _Float16* cat6 = (_Float16*)(Rbig + 53526528);     // (2,68,68,1024) padded
  _Float16* up7b = (_Float16*)Rbig;                  // (2,256,256,256) unpadded
  _Float16* c2buf = (_Float16*)c2b_;                 // (2,256,256,128) unpadded
  _Float16* p1 = (_Float16*)R1;                      // (2,260,260,64) padded
  _Float16* c6 = (_Float16*)R1;                      // (2,64,64,512) unpadded
  _Float16* c7 = (_Float16*)R1;                      // (2,128,128,256) unpadded
  _Float16* c8 = (_Float16*)R1;                      // (2,256,256,4) unpadded
  _Float16* p2 = (_Float16*)R2;                      // (2,132,132,128) padded
  _Float16* p3 = (_Float16*)(R2 + 8921088);          // (2,68,68,256) padded
  _Float16* p4 = (_Float16*)(R2 + 8921088);          // (2,36,36,512) padded (aliases p3!)
  _Float16* c5 = (_Float16*)(R2 + 8921088 + 2654208);// (2,32,32,512) unpadded

  // zero halo buffers not aliased with earlier-live data.
  // NOTE: p4 aliases p3, so p4's halo must be zeroed AFTER conv4 (p3 dead).
  zero16_k<<<(1081600 + 255) / 256, 256, 0, stream>>>(p1, 1081600);   // 17.3MB
  zero16_k<<<(557568 + 255) / 256, 256, 0, stream>>>(p2, 557568);     // 8.9MB
  zero16_k<<<(295936 + 255) / 256, 256, 0, stream>>>(p3, 295936);     // 4.7MB

  // weight transforms (fold BN scale into weights)
  wtrans16<<<(25 * 128 * 64 + 255) / 256, 256, 0, stream>>>(w[2], W2t, gg[2], 128, 64, 25 * 128 * 64);
  wtrans16<<<(25 * 256 * 128 + 255) / 256, 256, 0, stream>>>(w[3], W3t, gg[3], 256, 128, 25 * 256 * 128);
  wtrans16<<<(25 * 512 * 256 + 255) / 256, 256, 0, stream>>>(w[4], W4t, gg[4], 512, 256, 25 * 512 * 256);
  wtrans16<<<(25 * 512 * 512 + 255) / 256, 256, 0, stream>>>(w[5], W5t, gg[5], 512, 512, 25 * 512 * 512);
  wtrans16<<<(25 * 512 * 1024 + 255) / 256, 256, 0, stream>>>(w[6], W6t, gg[6], 512, 1024, 25 * 512 * 1024);
  wtrans16<<<(25 * 256 * 768 + 255) / 256, 256, 0, stream>>>(w[7], W7t, gg[7], 256, 768, 25 * 256 * 768);
  wtrans8<<<(28800 + 255) / 256, 256, 0, stream>>>(w[8], W8t, gg[8]);

  conv1_k<<<2048, 256, 0, stream>>>(data, w[1], gg[1], bb[1], ee[1], c1);
  pool_k<<<1048576 / 256, 256, 0, stream>>>(c1, p1, 64, 64, 512, 262144, 0,
                                            260, 67600, 522, 8, 8, 3, 1048576);
  // c1 dead -> zero cat7/cat6 (they alias c1's region)
  zero16_k<<<(3345408 + 255) / 256, 256, 0, stream>>>(cat7, 3345408);  // 53.5MB
  zero16_k<<<(1183744 + 255) / 256, 256, 0, stream>>>(cat6, 1183744);  // 18.9MB

  conv_gemm<4, 4, 1, 2><<<dim3(1024, 1), 256, 0, stream>>>(p1, W2t, gg[2], bb[2], ee[2], c2buf,
      64, 128, 8, 8, 64, 260, 67600, 522, 128, 0, 256, 65536, 0);
  pool_k<<<524288 / 256, 256, 0, stream>>>(c2buf, p2, 128, 128, 256, 65536, 0,
                                           132, 17424, 266, 7, 7, 4, 524288);
  // conv3: BM=64 M-split -> 1024 blocks (3/CU at 48KB LDS)
  conv_gemm<2, 4, 2, 3><<<dim3(256, 4), 256, 0, stream>>>(p2, W3t, gg[3], bb[3], ee[3], cat7,
      128, 256, 7, 7, 128, 132, 17424, 266, 768, 0, 132, 17424, 266);
  pool_k<<<262144 / 256, 256, 0, stream>>>(cat7, p3, 768, 256, 132, 17424, 266,
                                           68, 4624, 138, 6, 6, 5, 262144);
  // conv4: BM=64 M-split -> 512 blocks (2/CU)
  conv_gemm<2, 4, 2, 4><<<dim3(64, 8), 256, 0, stream>>>(p3, W4t, gg[4], bb[4], ee[4], cat6,
      256, 512, 6, 6, 256, 68, 4624, 138, 1024, 0, 68, 4624, 138);
  // p3 dead -> now safe to zero p4's halo (p4 aliases p3's bytes)
  zero16_k<<<(165888 + 255) / 256, 256, 0, stream>>>(p4, 165888);      // 2.65MB
  pool_k<<<131072 / 256, 256, 0, stream>>>(cat6, p4, 1024, 512, 68, 4624, 138,
                                           36, 1296, 74, 5, 5, 6, 131072);
  conv_gemm<2, 2, 2, 5><<<dim3(32, 8), 256, 0, stream>>>(p4, W5t, gg[5], bb[5], ee[5], c5,
      512, 512, 5, 5, 512, 36, 1296, 74, 512, 0, 32, 1024, 0);
  up_k<<<524288 / 256, 256, 0, stream>>>(c5, cat6, 512, 1024, 512,
                                         32, 1024, 0, 68, 4624, 138,
                                         5, 5, 6, 31.f / 63.f, 524288);
  // conv6: BM=64 M-split -> 512 blocks (2/CU)
  conv_gemm<2, 4, 2, 6><<<dim3(64, 8), 256, 0, stream>>>(cat6, W6t, gg[6], bb[6], ee[6], c6,
      1024, 512, 6, 6, 1024, 68, 4624, 138, 512, 0, 64, 4096, 0);
  up_k<<<2097152 / 256, 256, 0, stream>>>(c6, cat7, 512, 768, 256,
                                          64, 4096, 0, 132, 17424, 266,
                                          6, 6, 6, 63.f / 127.f, 2097152);
  // conv7: BM=64 M-split -> 1024 blocks (3/CU at 48KB LDS)
  conv_gemm<2, 4, 2, 7><<<dim3(256, 4), 256, 0, stream>>>(cat7, W7t, gg[7], bb[7], ee[7], c7,
      768, 256, 7, 7, 768, 132, 17424, 266, 256, 0, 128, 16384, 0);
  up_k<<<4194304 / 256, 256, 0, stream>>>(c7, up7b, 256, 256, 0,
                                          128, 16384, 0, 256, 65536, 0,
                                          7, 7, 5, 127.f / 255.f, 4194304);
  conv8_lds<<<512, 256, 0, stream>>>(c2buf, up7b, W8t, bb[8], gg[8], ee[8], c8);
  final_k<<<524288 / 256, 256, 0, stream>>>(data, c8, wo, bo, out);
}

// Round 12
// 1989.191 us; speedup vs baseline: 1.1996x; 1.1996x over previous
//
#include <hip/hip_runtime.h>
#include <hip/hip_bf16.h>

typedef _Float16 f16x8 __attribute__((ext_vector_type(8)));
typedef _Float16 f16x4 __attribute__((ext_vector_type(4)));
typedef float f32x4 __attribute__((ext_vector_type(4)));

#define BN_S 0.99999500003749975f  // 1/sqrt(1+1e-5)

__device__ inline f16x8 f16x8_zero() {
  f16x8 v = {(_Float16)0.f, (_Float16)0.f, (_Float16)0.f, (_Float16)0.f,
             (_Float16)0.f, (_Float16)0.f, (_Float16)0.f, (_Float16)0.f};
  return v;
}

__device__ __forceinline__ void load_lds16(const _Float16* g, _Float16* l) {
  __builtin_amdgcn_global_load_lds(
      (const __attribute__((address_space(1))) void*)g,
      (__attribute__((address_space(3))) void*)l, 16, 0, 0);
}

__global__ void zero_out_k(float* __restrict__ out, int n) {
  const int idx = blockIdx.x * 256 + threadIdx.x;
  if (idx < n) out[idx] = 0.f;
}

// zero n16 16-byte blocks
__global__ void zero16_k(_Float16* __restrict__ p, int n16) {
  const int idx = blockIdx.x * 256 + threadIdx.x;
  if (idx < n16) ((f16x8*)p)[idx] = f16x8_zero();
}

// ---------------------------------------------------------------------------
// Weight transform: OIHW fp32 -> [25][O][C] fp16, pre-scaled by g*BN_S.
// ---------------------------------------------------------------------------
__global__ void wtrans16(const float* __restrict__ src, _Float16* __restrict__ dst,
                         const float* __restrict__ g, int O, int C, int total) {
  const int idx = blockIdx.x * 256 + threadIdx.x;  // (t, o, c)
  if (idx >= total) return;
  const int OC = O * C;
  const int t = idx / OC;
  const int rem = idx - t * OC;
  const int o = rem / C;
  const int c = rem - o * C;
  dst[idx] = (_Float16)(src[(size_t)(o * C + c) * 25 + t] * g[o] * BN_S);
}

// conv8 weights: OIHW fp32 (O=3,C=384) -> [48 chunks][25 taps][3][8] fp16.
__global__ void wtrans8(const float* __restrict__ src, _Float16* __restrict__ dst,
                        const float* __restrict__ g) {
  const int idx = blockIdx.x * 256 + threadIdx.x;
  if (idx >= 28800) return;
  const int c = idx / 600;
  const int r = idx - c * 600;
  const int tap = r / 24;
  const int q = r - tap * 24;
  const int o = q >> 3, j = q & 7;
  const int cin = (c < 16) ? (c * 8 + j) : (128 + (c - 16) * 8 + j);
  dst[idx] = (_Float16)(src[((size_t)o * 384 + cin) * 25 + tap] * g[o] * BN_S);
}

// ---------------------------------------------------------------------------
// Implicit-GEMM 5x5 conv + BN + ReLU.  Cin%(32*KS)==0, Cout%BM==0, px%BN==0.
// Block tile BM(cout) x BN(px); 4 waves 2x2; KS k-steps staged per barrier
// into double-buffered LDS via global_load_lds(16B). XOR-swizzled LDS.
// TAG gives each layer a distinct symbol for profiling.
// Tile-split rule (r5/r9/r11): split along the dimension whose operand
// panel is SMALLER (BM-split re-reads activations, BN-split re-reads
// weights). conv4/conv6: act < wt -> BM-split OK. conv3/conv7: act > wt
// -> keep BM=128 (r11: <2,4> on conv7 = 3.8x FETCH, 2x slower).
// XCD swizzle (T1): each XCD owns a contiguous x-major chunk -> weight
// panel cached once per XCD L2. Requires grid total % 8 == 0 (all sites).
// ---------------------------------------------------------------------------
template <int MF, int NF, int KS, int TAG>
__global__ __launch_bounds__(256) void conv_gemm(
    const _Float16* __restrict__ in, const _Float16* __restrict__ wt,
    const float* __restrict__ gg, const float* __restrict__ bbv,
    const float* __restrict__ ev, _Float16* __restrict__ out,
    int Cin, int Cout, int lw, int lh,
    int inS, int Wpi, int bsi, int ibase,
    int outS, int outOff, int Wpo, int bso, int obase) {
  constexpr int BM = MF * 32;
  constexpr int BN = NF * 32;
  constexpr int SUB_A = BM * 32;  // halfwords per k-substep
  constexpr int SUB_B = BN * 32;
  __shared__ _Float16 sA[2][SUB_A * KS];
  __shared__ _Float16 sB[2][SUB_B * KS];

  const int tid = threadIdx.x;
  const int lane = tid & 63;
  const int wid = tid >> 6;
  const int wm = wid >> 1, wn = wid & 1;
  const int lr = lane >> 4, lc = lane & 15;

  // XCD-aware bijective block swizzle (total blocks % 8 == 0 at every site)
  int bx, by;
  {
    const int gx = gridDim.x;
    const int flat = blockIdx.y * gx + blockIdx.x;
    const int q = (gx * gridDim.y) >> 3;
    const int nf = (flat & 7) * q + (flat >> 3);
    bx = nf % gx;
    by = nf / gx;
  }
  const int n0 = bx * BN;
  const int m0 = by * BM;
  const int H = 1 << lh, W = 1 << lw;
  const int nkb = Cin >> 5;

  // staging identity: linear g = issue*256 + tid; row=g>>2, slot=g&3
  const int r0 = tid >> 2;
  const int chunk = (tid & 3) ^ ((r0 >> 1) & 3);  // same for row r0+64

  const _Float16* a0 = wt + (size_t)(m0 + r0) * Cin + (chunk << 3);
  const _Float16* a1 = a0 + ((size_t)Cin << 6);  // used only if BM==128
  const int t0off = -2 * Wpi - 2;  // tap (dy=0,dx=0)
  const _Float16 *b0, *b1 = nullptr;
  {
    int n = n0 + r0;
    int pix0 = (n >> (lw + lh)) * bsi + ((n >> lw) & (H - 1)) * Wpi + (n & (W - 1)) + ibase;
    b0 = in + (size_t)(pix0 + t0off) * inS + (chunk << 3);
    if constexpr (BN == 128) {
      n = n0 + r0 + 64;
      int pix1 = (n >> (lw + lh)) * bsi + ((n >> lw) & (H - 1)) * Wpi + (n & (W - 1)) + ibase;
      b1 = in + (size_t)(pix1 + t0off) * inS + (chunk << 3);
    }
  }

  // ds_read fragment swizzle (halfwords)
  const int swz = (lr ^ ((lc >> 1) & 3)) << 3;

  f32x4 acc[MF][NF];
  const f32x4 vz = {0.f, 0.f, 0.f, 0.f};
#pragma unroll
  for (int i = 0; i < MF; ++i)
#pragma unroll
    for (int j = 0; j < NF; ++j) acc[i][j] = vz;

  const int np = 25 * nkb / KS;  // staged groups
  int kb = 0, dx = 0;
  const size_t a_tap = (size_t)Cout * Cin - ((size_t)nkb << 5);
  const int woff = wid << 9;  // wave LDS base within a 4KB issue (halfwords)

  // advance staging pointers by one group (KS k-steps)
  auto advance = [&]() {
    a0 += 32 * KS; b0 += 32 * KS;
    if constexpr (BM == 128) a1 += 32 * KS;
    if constexpr (BN == 128) b1 += 32 * KS;
    kb += KS;
    if (kb == nkb) {
      kb = 0;
      a0 += a_tap;
      if constexpr (BM == 128) a1 += a_tap;
      int pd;
      if (++dx == 5) { dx = 0; pd = Wpi - 4; } else pd = 1;
      const ptrdiff_t bd = (ptrdiff_t)pd * inS - ((ptrdiff_t)nkb << 5);
      b0 += bd;
      if constexpr (BN == 128) b1 += bd;
    }
  };
  auto stage = [&](int buf) {
#pragma unroll
    for (int s = 0; s < KS; ++s) {
      _Float16* sa = sA[buf] + s * SUB_A + woff;
      _Float16* sb = sB[buf] + s * SUB_B + woff;
      load_lds16(a0 + 32 * s, sa);
      if constexpr (BM == 128) load_lds16(a1 + 32 * s, sa + 2048);
      load_lds16(b0 + 32 * s, sb);
      if constexpr (BN == 128) load_lds16(b1 + 32 * s, sb + 2048);
    }
  };

  // prologue: stage group 0 into buf 0
  stage(0);
  __syncthreads();

  int cur = 0;
  for (int t = 0; t < np; ++t) {
    if (t + 1 < np) {
      advance();
      stage(cur ^ 1);
    }
    const _Float16* pA = sA[cur];
    const _Float16* pB = sB[cur];
#pragma unroll
    for (int s = 0; s < KS; ++s) {
      f16x8 af[MF], bf[NF];
#pragma unroll
      for (int i = 0; i < MF; ++i)
        af[i] = *(const f16x8*)(pA + s * SUB_A + ((wm * (MF * 16) + (i << 4) + lc) << 5) + swz);
#pragma unroll
      for (int i = 0; i < NF; ++i)
        bf[i] = *(const f16x8*)(pB + s * SUB_B + ((wn * (NF * 16) + (i << 4) + lc) << 5) + swz);
#pragma unroll
      for (int mi = 0; mi < MF; ++mi)
#pragma unroll
        for (int ni = 0; ni < NF; ++ni)
          acc[mi][ni] =
              __builtin_amdgcn_mfma_f32_16x16x32_f16(af[mi], bf[ni], acc[mi][ni], 0, 0, 0);
    }
    __syncthreads();  // drains stage(cur^1) loads + fences buf reuse
    cur ^= 1;
  }

  // Epilogue: D col = lane&15 -> pixel, row = lr*4+j -> cout
#pragma unroll
  for (int mi = 0; mi < MF; ++mi) {
    const int ob = m0 + wm * (MF * 16) + (mi << 4) + (lr << 2);
    const f32x4 gv = *(const f32x4*)(gg + ob);
    const f32x4 bv = *(const f32x4*)(bbv + ob);
    const f32x4 evv = *(const f32x4*)(ev + ob);
#pragma unroll
    for (int ni = 0; ni < NF; ++ni) {
      const int n = n0 + wn * (NF * 16) + (ni << 4) + lc;
      const int y = (n >> lw) & (H - 1);
      const int x = n & (W - 1);
      const int bb_ = n >> (lw + lh);
      const size_t op = (size_t)(bb_ * bso + y * Wpo + x + obase) * outS + outOff + ob;
      f16x4 h;
#pragma unroll
      for (int j = 0; j < 4; ++j) {
        const float s = gv[j] * BN_S;
        float v = acc[mi][ni][j] + (bv[j] * s + evv[j]);
        v = v > 0.f ? v : 0.f;
        h[j] = (_Float16)v;
      }
      *(f16x4*)(out + op) = h;
    }
  }
}

// ---------------------------------------------------------------------------
// conv1: Cin=3, Cout=64, 512x512, fp32 NCHW data + raw fp32 weights.
// ---------------------------------------------------------------------------
__global__ __launch_bounds__(256) void conv1_k(
    const float* __restrict__ data, const float* __restrict__ w1,
    const float* __restrict__ g1, const float* __restrict__ b1,
    const float* __restrict__ e1, _Float16* __restrict__ out) {
  __shared__ float patch[3][20][20];
  const int tid = threadIdx.x;
  const int bid = blockIdx.x;
  const int tx = bid & 31, ty = (bid >> 5) & 31, b = bid >> 10;

  for (int i = tid; i < 1200; i += 256) {
    const int c = i / 400;
    const int r = i - c * 400;
    const int pyy = r / 20;
    const int pxx = r - pyy * 20;
    const int gy = (ty << 4) + pyy - 2, gx = (tx << 4) + pxx - 2;
    float v = 0.f;
    if ((unsigned)gy < 512u && (unsigned)gx < 512u)
      v = data[((size_t)(b * 3 + c) << 18) + (gy << 9) + gx];
    patch[c][pyy][pxx] = v;
  }
  __syncthreads();

  const int py = tid >> 4, px = tid & 15;
  float acc[64];
#pragma unroll
  for (int o = 0; o < 64; ++o) acc[o] = 0.f;

  for (int c = 0; c < 3; ++c)
    for (int dy = 0; dy < 5; ++dy) {
#pragma unroll
      for (int dx = 0; dx < 5; ++dx) {
        const float v = patch[c][py + dy][px + dx];
        const float* wb = w1 + c * 25 + dy * 5 + dx;
#pragma unroll
        for (int o = 0; o < 64; ++o) acc[o] = fmaf(v, wb[o * 75], acc[o]);
      }
    }

  const int y = (ty << 4) + py, x = (tx << 4) + px;
  _Float16* op = out + ((size_t)(((b << 9) + y) << 9) + x) * 64;
#pragma unroll
  for (int oc = 0; oc < 8; ++oc) {
    f16x8 h;
#pragma unroll
    for (int j = 0; j < 8; ++j) {
      const int o = (oc << 3) + j;
      const float s = g1[o] * BN_S;
      const float t = b1[o] * s + e1[o];
      float v = fmaf(acc[o], s, t);
      v = v > 0.f ? v : 0.f;
      h[j] = (_Float16)v;
    }
    *(f16x8*)(op + (oc << 3)) = h;
  }
}

// ---------------------------------------------------------------------------
// avg-pool 2x2 stride 2, NHWC fp16, generic padded/unpadded addressing
// ---------------------------------------------------------------------------
__global__ void pool_k(const _Float16* __restrict__ in, _Float16* __restrict__ out,
                       int inS, int outS, int Wpi, int bsi, int ibase,
                       int Wpo, int bso, int obase,
                       int lwo, int lho, int lcc, int total) {
  const int idx = blockIdx.x * 256 + threadIdx.x;
  if (idx >= total) return;
  const int cc = idx & ((1 << lcc) - 1);
  const int pix = idx >> lcc;
  const int x = pix & ((1 << lwo) - 1);
  const int y = (pix >> lwo) & ((1 << lho) - 1);
  const int b = pix >> (lwo + lho);
  const int ip = b * bsi + (y << 1) * Wpi + (x << 1) + ibase;
  const _Float16* p = in + (size_t)ip * inS + (cc << 3);
  const f16x8 v00 = *(const f16x8*)p;
  const f16x8 v01 = *(const f16x8*)(p + inS);
  const f16x8 v10 = *(const f16x8*)(p + (size_t)Wpi * inS);
  const f16x8 v11 = *(const f16x8*)(p + (size_t)(Wpi + 1) * inS);
  f16x8 r;
#pragma unroll
  for (int j = 0; j < 8; ++j)
    r[j] = (_Float16)(((float)v00[j] + (float)v01[j] + (float)v10[j] + (float)v11[j]) * 0.25f);
  const int op = b * bso + y * Wpo + x + obase;
  *(f16x8*)(out + (size_t)op * outS + (cc << 3)) = r;
}

// ---------------------------------------------------------------------------
// bilinear 2x upsample (align_corners=True), NHWC fp16
// ---------------------------------------------------------------------------
__global__ void up_k(const _Float16* __restrict__ in, _Float16* __restrict__ out,
                     int inS, int outS, int outOff,
                     int Wpi, int bsi, int ibase,
                     int Wpo, int bso, int obase,
                     int lwi, int lhi, int lcc, float scale, int total) {
  const int idx = blockIdx.x * 256 + threadIdx.x;
  if (idx >= total) return;
  const int cc = idx & ((1 << lcc) - 1);
  const int pix = idx >> lcc;
  const int lwo = lwi + 1, lho = lhi + 1;
  const int ox = pix & ((1 << lwo) - 1);
  const int oy = (pix >> lwo) & ((1 << lho) - 1);
  const int b = pix >> (lwo + lho);
  const int Hi = 1 << lhi, Wi = 1 << lwi;
  const float fy = oy * scale;
  const int y0 = (int)fy;
  const float wy = fy - y0;
  const int y1 = min(y0 + 1, Hi - 1);
  const float fx = ox * scale;
  const int x0 = (int)fx;
  const float wx = fx - x0;
  const int x1 = min(x0 + 1, Wi - 1);
  const int rbase = b * bsi + ibase;
  const _Float16* basep = in + (cc << 3);
  const f16x8 v00 = *(const f16x8*)(basep + (size_t)(rbase + y0 * Wpi + x0) * inS);
  const f16x8 v01 = *(const f16x8*)(basep + (size_t)(rbase + y0 * Wpi + x1) * inS);
  const f16x8 v10 = *(const f16x8*)(basep + (size_t)(rbase + y1 * Wpi + x0) * inS);
  const f16x8 v11 = *(const f16x8*)(basep + (size_t)(rbase + y1 * Wpi + x1) * inS);
  f16x8 r;
#pragma unroll
  for (int j = 0; j < 8; ++j) {
    const float top = (float)v00[j] * (1.f - wx) + (float)v01[j] * wx;
    const float bot = (float)v10[j] * (1.f - wx) + (float)v11[j] * wx;
    r[j] = (_Float16)(top * (1.f - wy) + bot * wy);
  }
  const int op = b * bso + oy * Wpo + ox + obase;
  *(f16x8*)(out + (size_t)op * outS + outOff + (cc << 3)) = r;
}

// ---------------------------------------------------------------------------
// conv8 (LDS-tiled): Cin=384 (= c2[128ch] ++ up7[256ch]), Cout=3, 256x256.
// ---------------------------------------------------------------------------
__global__ __launch_bounds__(256) void conv8_lds(
    const _Float16* __restrict__ inA, const _Float16* __restrict__ inB,
    const _Float16* __restrict__ wt, const float* __restrict__ b8,
    const float* __restrict__ g8, const float* __restrict__ e8,
    _Float16* __restrict__ out) {
  __shared__ f16x8 patch[2][20][20];
  const int tid = threadIdx.x;
  const int bid = blockIdx.x;  // 512
  const int tx = bid & 15, ty = (bid >> 4) & 15, b = bid >> 8;
  const int px = tid & 15, py = tid >> 4;
  const int x0 = tx << 4, y0 = ty << 4;

  float a0 = 0.f, a1 = 0.f, a2 = 0.f;
  for (int c = 0; c < 48; ++c) {
    const _Float16* sbase;
    int str;
    if (c < 16) { sbase = inA + ((size_t)b << 23) + (c << 3); str = 128; }
    else        { sbase = inB + ((size_t)b << 24) + ((c - 16) << 3); str = 256; }
    for (int i = tid; i < 400; i += 256) {
      const int pyy = i / 20, pxx = i - pyy * 20;
      const int gy = y0 + pyy - 2, gx = x0 + pxx - 2;
      f16x8 v = f16x8_zero();
      if ((unsigned)gy < 256u && (unsigned)gx < 256u)
        v = *(const f16x8*)(sbase + (size_t)((gy << 8) + gx) * str);
      patch[c & 1][pyy][pxx] = v;
    }
    __syncthreads();
    const _Float16* wb_c = wt + c * 600;
#pragma unroll
    for (int dy = 0; dy < 5; ++dy) {
#pragma unroll
      for (int dxx = 0; dxx < 5; ++dxx) {
        const f16x8 v = patch[c & 1][py + dy][px + dxx];
        const _Float16* wb = wb_c + (dy * 5 + dxx) * 24;
#pragma unroll
        for (int j = 0; j < 8; ++j) {
          const float f = (float)v[j];
          a0 = fmaf(f, (float)wb[j], a0);
          a1 = fmaf(f, (float)wb[8 + j], a1);
          a2 = fmaf(f, (float)wb[16 + j], a2);
        }
      }
    }
  }

  const float s0 = g8[0] * BN_S, t0 = b8[0] * s0 + e8[0];
  const float s1 = g8[1] * BN_S, t1 = b8[1] * s1 + e8[1];
  const float s2 = g8[2] * BN_S, t2 = b8[2] * s2 + e8[2];
  float r0 = a0 + t0, r1 = a1 + t1, r2 = a2 + t2;
  r0 = r0 > 0.f ? r0 : 0.f;
  r1 = r1 > 0.f ? r1 : 0.f;
  r2 = r2 > 0.f ? r2 : 0.f;
  f16x4 h;
  h[0] = (_Float16)r0; h[1] = (_Float16)r1; h[2] = (_Float16)r2; h[3] = (_Float16)0.f;
  const int opix = (b << 16) + ((y0 + py) << 8) + (x0 + px);
  *(f16x4*)(out + (size_t)opix * 4) = h;
}

// ---------------------------------------------------------------------------
// final: bilinear up(c8, 256->512) + 1x1 conv (wo,bo) + out = data*core (fp32)
// ---------------------------------------------------------------------------
__global__ void final_k(const float* __restrict__ data, const _Float16* __restrict__ c8,
                        const float* __restrict__ wo, const float* __restrict__ bo,
                        float* __restrict__ out) {
  const int idx = blockIdx.x * 256 + threadIdx.x;  // < 524288
  const int x = idx & 511, y = (idx >> 9) & 511, b = idx >> 18;
  const float sc = 255.f / 511.f;
  const float fy = y * sc;
  const int y0 = (int)fy;
  const float wy = fy - y0;
  const int y1 = min(y0 + 1, 255);
  const float fx = x * sc;
  const int x0 = (int)fx;
  const float wx = fx - x0;
  const int x1 = min(x0 + 1, 255);
  const f16x4 v00 = *(const f16x4*)(c8 + (size_t)((((b << 8) + y0) << 8) + x0) * 4);
  const f16x4 v01 = *(const f16x4*)(c8 + (size_t)((((b << 8) + y0) << 8) + x1) * 4);
  const f16x4 v10 = *(const f16x4*)(c8 + (size_t)((((b << 8) + y1) << 8) + x0) * 4);
  const f16x4 v11 = *(const f16x4*)(c8 + (size_t)((((b << 8) + y1) << 8) + x1) * 4);
  float u[3];
#pragma unroll
  for (int j = 0; j < 3; ++j) {
    const float top = (float)v00[j] * (1.f - wx) + (float)v01[j] * wx;
    const float bot = (float)v10[j] * (1.f - wx) + (float)v11[j] * wx;
    u[j] = top * (1.f - wy) + bot * wy;
  }
#pragma unroll
  for (int c = 0; c < 3; ++c) {
    const float core = bo[c] + wo[c * 3 + 0] * u[0] + wo[c * 3 + 1] * u[1] + wo[c * 3 + 2] * u[2];
    const size_t oi = ((size_t)(b * 3 + c) << 18) + (y << 9) + x;
    out[oi] = data[oi] * core;
  }
}

// ---------------------------------------------------------------------------
extern "C" void kernel_launch(void* const* d_in, const int* in_sizes, int n_in,
                              void* d_out, int out_size, void* d_ws, size_t ws_size,
                              hipStream_t stream) {
  const float* data = (const float*)d_in[0];
  const float *w[9], *bb[9], *gg[9], *ee[9];
  for (int n = 1; n <= 8; ++n) {
    w[n] = (const float*)d_in[1 + (n - 1) * 4];
    bb[n] = (const float*)d_in[2 + (n - 1) * 4];
    gg[n] = (const float*)d_in[3 + (n - 1) * 4];
    ee[n] = (const float*)d_in[4 + (n - 1) * 4];
  }
  const float* wo = (const float*)d_in[33];
  const float* bo = (const float*)d_in[34];
  float* out = (float*)d_out;
  (void)in_sizes; (void)n_in;

  // ---- workspace layout (aliased; padded activations; 194,810,112 B) ----
  // LIVENESS NOTE (r9 lesson): cat7's c3-half is live conv3 -> conv7 (skip
  // connection); the cat7 region must NOT be reused between those points.
  const size_t NEEDED = 194810112ull;
  if (ws_size < NEEDED) {
    zero_out_k<<<(out_size + 255) / 256, 256, 0, stream>>>(out, out_size);
    return;
  }
  char* base = (char*)d_ws;
  size_t off = 0;
  auto alloc = [&](size_t bytes) -> char* {
    char* p = base + off;
    off += (bytes + 255) & ~(size_t)255;
    return p;
  };
  _Float16* W2t = (_Float16*)alloc(409600);     // 25*128*64*2
  _Float16* W3t = (_Float16*)alloc(1638400);    // 25*256*128*2
  _Float16* W4t = (_Float16*)alloc(6553600);    // 25*512*256*2
  _Float16* W5t = (_Float16*)alloc(13107200);   // 25*512*512*2
  _Float16* W6t = (_Float16*)alloc(26214400);   // 25*512*1024*2
  _Float16* W7t = (_Float16*)alloc(9830400);    // 25*256*768*2
  _Float16* W8t = (_Float16*)alloc(57600);      // 48*25*24 fp16
  char* Rbig = alloc(72466432);   // c1(67.1M) | cat7(53.5M)+cat6(18.9M) | up7(67.1M)
  char* c2b_ = alloc(33554432);   // c2 (2,256,256,128) unpadded
  char* R1 = alloc(17305600);     // p1(17.3M) | c6(8.4M) | c7(16.8M) | c8(1M)
  char* R2 = alloc(13672448);     // p2(8.9M) ; [p3(4.7M) | p4(2.65M)+c5(2.1M)]

  _Float16* c1 = (_Float16*)Rbig;                    // (2,512,512,64) unpadded
  _Float16* cat7 = (_Float16*)Rbig;                  // (2,132,132,768) padded
  _Float16* cat6 = (_Float16*)(Rbig + 53526528);     // (2,68,68,1024) padded
  _Float16* up7b = (_Float16*)Rbig;                  // (2,256,256,256) unpadded
  _Float16* c2buf = (_Float16*)c2b_;                 // (2,256,256,128) unpadded
  _Float16* p1 = (_Float16*)R1;                      // (2,260,260,64) padded
  _Float16* c6 = (_Float16*)R1;                      // (2,64,64,512) unpadded
  _Float16* c7 = (_Float16*)R1;                      // (2,128,128,256) unpadded
  _Float16* c8 = (_Float16*)R1;                      // (2,256,256,4) unpadded
  _Float16* p2 = (_Float16*)R2;                      // (2,132,132,128) padded
  _Float16* p3 = (_Float16*)(R2 + 8921088);          // (2,68,68,256) padded
  _Float16* p4 = (_Float16*)(R2 + 8921088);          // (2,36,36,512) padded (aliases p3!)
  _Float16* c5 = (_Float16*)(R2 + 8921088 + 2654208);// (2,32,32,512) unpadded

  // zero halo buffers not aliased with earlier-live data.
  // NOTE: p4 aliases p3, so p4's halo must be zeroed AFTER conv4 (p3 dead).
  zero16_k<<<(1081600 + 255) / 256, 256, 0, stream>>>(p1, 1081600);   // 17.3MB
  zero16_k<<<(557568 + 255) / 256, 256, 0, stream>>>(p2, 557568);     // 8.9MB
  zero16_k<<<(295936 + 255) / 256, 256, 0, stream>>>(p3, 295936);     // 4.7MB

  // weight transforms (fold BN scale into weights)
  wtrans16<<<(25 * 128 * 64 + 255) / 256, 256, 0, stream>>>(w[2], W2t, gg[2], 128, 64, 25 * 128 * 64);
  wtrans16<<<(25 * 256 * 128 + 255) / 256, 256, 0, stream>>>(w[3], W3t, gg[3], 256, 128, 25 * 256 * 128);
  wtrans16<<<(25 * 512 * 256 + 255) / 256, 256, 0, stream>>>(w[4], W4t, gg[4], 512, 256, 25 * 512 * 256);
  wtrans16<<<(25 * 512 * 512 + 255) / 256, 256, 0, stream>>>(w[5], W5t, gg[5], 512, 512, 25 * 512 * 512);
  wtrans16<<<(25 * 512 * 1024 + 255) / 256, 256, 0, stream>>>(w[6], W6t, gg[6], 512, 1024, 25 * 512 * 1024);
  wtrans16<<<(25 * 256 * 768 + 255) / 256, 256, 0, stream>>>(w[7], W7t, gg[7], 256, 768, 25 * 256 * 768);
  wtrans8<<<(28800 + 255) / 256, 256, 0, stream>>>(w[8], W8t, gg[8]);

  conv1_k<<<2048, 256, 0, stream>>>(data, w[1], gg[1], bb[1], ee[1], c1);
  pool_k<<<1048576 / 256, 256, 0, stream>>>(c1, p1, 64, 64, 512, 262144, 0,
                                            260, 67600, 522, 8, 8, 3, 1048576);
  // c1 dead -> zero cat7/cat6 (they alias c1's region)
  zero16_k<<<(3345408 + 255) / 256, 256, 0, stream>>>(cat7, 3345408);  // 53.5MB
  zero16_k<<<(1183744 + 255) / 256, 256, 0, stream>>>(cat6, 1183744);  // 18.9MB

  conv_gemm<4, 4, 1, 2><<<dim3(1024, 1), 256, 0, stream>>>(p1, W2t, gg[2], bb[2], ee[2], c2buf,
      64, 128, 8, 8, 64, 260, 67600, 522, 128, 0, 256, 65536, 0);
  pool_k<<<524288 / 256, 256, 0, stream>>>(c2buf, p2, 128, 128, 256, 65536, 0,
                                           132, 17424, 266, 7, 7, 4, 524288);
  // conv3: act(8.9M) > wt(1.6M) -> keep BM=128 (r11 rule)
  conv_gemm<4, 4, 2, 3><<<dim3(256, 2), 256, 0, stream>>>(p2, W3t, gg[3], bb[3], ee[3], cat7,
      128, 256, 7, 7, 128, 132, 17424, 266, 768, 0, 132, 17424, 266);
  pool_k<<<262144 / 256, 256, 0, stream>>>(cat7, p3, 768, 256, 132, 17424, 266,
                                           68, 4624, 138, 6, 6, 5, 262144);
  // conv4: act(4.7M) < wt(6.5M) -> BM-split, 512 blocks (2/CU)
  conv_gemm<2, 4, 2, 4><<<dim3(64, 8), 256, 0, stream>>>(p3, W4t, gg[4], bb[4], ee[4], cat6,
      256, 512, 6, 6, 256, 68, 4624, 138, 1024, 0, 68, 4624, 138);
  // p3 dead -> now safe to zero p4's halo (p4 aliases p3's bytes)
  zero16_k<<<(165888 + 255) / 256, 256, 0, stream>>>(p4, 165888);      // 2.65MB
  pool_k<<<131072 / 256, 256, 0, stream>>>(cat6, p4, 1024, 512, 68, 4624, 138,
                                           36, 1296, 74, 5, 5, 6, 131072);
  conv_gemm<2, 2, 2, 5><<<dim3(32, 8), 256, 0, stream>>>(p4, W5t, gg[5], bb[5], ee[5], c5,
      512, 512, 5, 5, 512, 36, 1296, 74, 512, 0, 32, 1024, 0);
  up_k<<<524288 / 256, 256, 0, stream>>>(c5, cat6, 512, 1024, 512,
                                         32, 1024, 0, 68, 4624, 138,
                                         5, 5, 6, 31.f / 63.f, 524288);
  // conv6: act(18.9M) < wt(26M) -> BM-split, 512 blocks (2/CU)
  conv_gemm<2, 4, 2, 6><<<dim3(64, 8), 256, 0, stream>>>(cat6, W6t, gg[6], bb[6], ee[6], c6,
      1024, 512, 6, 6, 1024, 68, 4624, 138, 512, 0, 64, 4096, 0);
  up_k<<<2097152 / 256, 256, 0, stream>>>(c6, cat7, 512, 768, 256,
                                          64, 4096, 0, 132, 17424, 266,
                                          6, 6, 6, 63.f / 127.f, 2097152);
  // conv7: act(53.5M) > wt(9.8M) -> keep BM=128 (r11: <2,4> was 2x slower)
  conv_gemm<4, 4, 2, 7><<<dim3(256, 2), 256, 0, stream>>>(cat7, W7t, gg[7], bb[7], ee[7], c7,
      768, 256, 7, 7, 768, 132, 17424, 266, 256, 0, 128, 16384, 0);
  up_k<<<4194304 / 256, 256, 0, stream>>>(c7, up7b, 256, 256, 0,
                                          128, 16384, 0, 256, 65536, 0,
                                          7, 7, 5, 127.f / 255.f, 4194304);
  conv8_lds<<<512, 256, 0, stream>>>(c2buf, up7b, W8t, bb[8], gg[8], ee[8], c8);
  final_k<<<524288 / 256, 256, 0, stream>>>(data, c8, wo, bo, out);
}

// Round 13
// 1813.043 us; speedup vs baseline: 1.3162x; 1.0972x over previous
//
#include <hip/hip_runtime.h>
#include <hip/hip_bf16.h>

typedef _Float16 f16x8 __attribute__((ext_vector_type(8)));
typedef _Float16 f16x4 __attribute__((ext_vector_type(4)));
typedef float f32x4 __attribute__((ext_vector_type(4)));

#define BN_S 0.99999500003749975f  // 1/sqrt(1+1e-5)

__device__ inline f16x8 f16x8_zero() {
  f16x8 v = {(_Float16)0.f, (_Float16)0.f, (_Float16)0.f, (_Float16)0.f,
             (_Float16)0.f, (_Float16)0.f, (_Float16)0.f, (_Float16)0.f};
  return v;
}

__device__ __forceinline__ void load_lds16(const _Float16* g, _Float16* l) {
  __builtin_amdgcn_global_load_lds(
      (const __attribute__((address_space(1))) void*)g,
      (__attribute__((address_space(3))) void*)l, 16, 0, 0);
}

__global__ void zero_out_k(float* __restrict__ out, int n) {
  const int idx = blockIdx.x * 256 + threadIdx.x;
  if (idx < n) out[idx] = 0.f;
}

// zero n16 16-byte blocks
__global__ void zero16_k(_Float16* __restrict__ p, int n16) {
  const int idx = blockIdx.x * 256 + threadIdx.x;
  if (idx < n16) ((f16x8*)p)[idx] = f16x8_zero();
}

// ---------------------------------------------------------------------------
// Weight transform: OIHW fp32 -> [25][O][C] fp16, pre-scaled by g*BN_S.
// ---------------------------------------------------------------------------
__global__ void wtrans16(const float* __restrict__ src, _Float16* __restrict__ dst,
                         const float* __restrict__ g, int O, int C, int total) {
  const int idx = blockIdx.x * 256 + threadIdx.x;  // (t, o, c)
  if (idx >= total) return;
  const int OC = O * C;
  const int t = idx / OC;
  const int rem = idx - t * OC;
  const int o = rem / C;
  const int c = rem - o * C;
  dst[idx] = (_Float16)(src[(size_t)(o * C + c) * 25 + t] * g[o] * BN_S);
}

// conv8 weights: OIHW fp32 (O=3,C=384) -> [48 chunks][25 taps][3][8] fp16.
__global__ void wtrans8(const float* __restrict__ src, _Float16* __restrict__ dst,
                        const float* __restrict__ g) {
  const int idx = blockIdx.x * 256 + threadIdx.x;
  if (idx >= 28800) return;
  const int c = idx / 600;
  const int r = idx - c * 600;
  const int tap = r / 24;
  const int q = r - tap * 24;
  const int o = q >> 3, j = q & 7;
  const int cin = (c < 16) ? (c * 8 + j) : (128 + (c - 16) * 8 + j);
  dst[idx] = (_Float16)(src[((size_t)o * 384 + cin) * 25 + tap] * g[o] * BN_S);
}

// ---------------------------------------------------------------------------
// Implicit-GEMM 5x5 conv + BN + ReLU.  Cin%(32*KS)==0, Cout%BM==0, px%BN==0.
// Block tile BM(cout) x BN(px); 4 waves 2x2; KS k-steps staged per barrier
// into double-buffered LDS via global_load_lds(16B). XOR-swizzled LDS.
// TAG gives each layer a distinct symbol for profiling.
// Tile-split rule (r5/r9/r11): split along the dimension whose operand
// panel is SMALLER. conv4/conv6: act < wt -> BM-split OK. conv3/conv7:
// act > wt -> keep BM=128.
// NO XCD blockIdx swizzle (r12: it broke the natural round-robin's
// x-column sharing across y-slices; FETCH 1.65GB on conv6, -185us total).
// ---------------------------------------------------------------------------
template <int MF, int NF, int KS, int TAG>
__global__ __launch_bounds__(256) void conv_gemm(
    const _Float16* __restrict__ in, const _Float16* __restrict__ wt,
    const float* __restrict__ gg, const float* __restrict__ bbv,
    const float* __restrict__ ev, _Float16* __restrict__ out,
    int Cin, int Cout, int lw, int lh,
    int inS, int Wpi, int bsi, int ibase,
    int outS, int outOff, int Wpo, int bso, int obase) {
  constexpr int BM = MF * 32;
  constexpr int BN = NF * 32;
  constexpr int SUB_A = BM * 32;  // halfwords per k-substep
  constexpr int SUB_B = BN * 32;
  __shared__ _Float16 sA[2][SUB_A * KS];
  __shared__ _Float16 sB[2][SUB_B * KS];

  const int tid = threadIdx.x;
  const int lane = tid & 63;
  const int wid = tid >> 6;
  const int wm = wid >> 1, wn = wid & 1;
  const int lr = lane >> 4, lc = lane & 15;
  const int n0 = blockIdx.x * BN;
  const int m0 = blockIdx.y * BM;
  const int H = 1 << lh, W = 1 << lw;
  const int nkb = Cin >> 5;

  // staging identity: linear g = issue*256 + tid; row=g>>2, slot=g&3
  const int r0 = tid >> 2;
  const int chunk = (tid & 3) ^ ((r0 >> 1) & 3);  // same for row r0+64

  const _Float16* a0 = wt + (size_t)(m0 + r0) * Cin + (chunk << 3);
  const _Float16* a1 = a0 + ((size_t)Cin << 6);  // used only if BM==128
  const int t0off = -2 * Wpi - 2;  // tap (dy=0,dx=0)
  const _Float16 *b0, *b1 = nullptr;
  {
    int n = n0 + r0;
    int pix0 = (n >> (lw + lh)) * bsi + ((n >> lw) & (H - 1)) * Wpi + (n & (W - 1)) + ibase;
    b0 = in + (size_t)(pix0 + t0off) * inS + (chunk << 3);
    if constexpr (BN == 128) {
      n = n0 + r0 + 64;
      int pix1 = (n >> (lw + lh)) * bsi + ((n >> lw) & (H - 1)) * Wpi + (n & (W - 1)) + ibase;
      b1 = in + (size_t)(pix1 + t0off) * inS + (chunk << 3);
    }
  }

  // ds_read fragment swizzle (halfwords)
  const int swz = (lr ^ ((lc >> 1) & 3)) << 3;

  f32x4 acc[MF][NF];
  const f32x4 vz = {0.f, 0.f, 0.f, 0.f};
#pragma unroll
  for (int i = 0; i < MF; ++i)
#pragma unroll
    for (int j = 0; j < NF; ++j) acc[i][j] = vz;

  const int np = 25 * nkb / KS;  // staged groups
  int kb = 0, dx = 0;
  const size_t a_tap = (size_t)Cout * Cin - ((size_t)nkb << 5);
  const int woff = wid << 9;  // wave LDS base within a 4KB issue (halfwords)

  // advance staging pointers by one group (KS k-steps)
  auto advance = [&]() {
    a0 += 32 * KS; b0 += 32 * KS;
    if constexpr (BM == 128) a1 += 32 * KS;
    if constexpr (BN == 128) b1 += 32 * KS;
    kb += KS;
    if (kb == nkb) {
      kb = 0;
      a0 += a_tap;
      if constexpr (BM == 128) a1 += a_tap;
      int pd;
      if (++dx == 5) { dx = 0; pd = Wpi - 4; } else pd = 1;
      const ptrdiff_t bd = (ptrdiff_t)pd * inS - ((ptrdiff_t)nkb << 5);
      b0 += bd;
      if constexpr (BN == 128) b1 += bd;
    }
  };
  auto stage = [&](int buf) {
#pragma unroll
    for (int s = 0; s < KS; ++s) {
      _Float16* sa = sA[buf] + s * SUB_A + woff;
      _Float16* sb = sB[buf] + s * SUB_B + woff;
      load_lds16(a0 + 32 * s, sa);
      if constexpr (BM == 128) load_lds16(a1 + 32 * s, sa + 2048);
      load_lds16(b0 + 32 * s, sb);
      if constexpr (BN == 128) load_lds16(b1 + 32 * s, sb + 2048);
    }
  };

  // prologue: stage group 0 into buf 0
  stage(0);
  __syncthreads();

  int cur = 0;
  for (int t = 0; t < np; ++t) {
    if (t + 1 < np) {
      advance();
      stage(cur ^ 1);
    }
    const _Float16* pA = sA[cur];
    const _Float16* pB = sB[cur];
#pragma unroll
    for (int s = 0; s < KS; ++s) {
      f16x8 af[MF], bf[NF];
#pragma unroll
      for (int i = 0; i < MF; ++i)
        af[i] = *(const f16x8*)(pA + s * SUB_A + ((wm * (MF * 16) + (i << 4) + lc) << 5) + swz);
#pragma unroll
      for (int i = 0; i < NF; ++i)
        bf[i] = *(const f16x8*)(pB + s * SUB_B + ((wn * (NF * 16) + (i << 4) + lc) << 5) + swz);
#pragma unroll
      for (int mi = 0; mi < MF; ++mi)
#pragma unroll
        for (int ni = 0; ni < NF; ++ni)
          acc[mi][ni] =
              __builtin_amdgcn_mfma_f32_16x16x32_f16(af[mi], bf[ni], acc[mi][ni], 0, 0, 0);
    }
    __syncthreads();  // drains stage(cur^1) loads + fences buf reuse
    cur ^= 1;
  }

  // Epilogue: D col = lane&15 -> pixel, row = lr*4+j -> cout
#pragma unroll
  for (int mi = 0; mi < MF; ++mi) {
    const int ob = m0 + wm * (MF * 16) + (mi << 4) + (lr << 2);
    const f32x4 gv = *(const f32x4*)(gg + ob);
    const f32x4 bv = *(const f32x4*)(bbv + ob);
    const f32x4 evv = *(const f32x4*)(ev + ob);
#pragma unroll
    for (int ni = 0; ni < NF; ++ni) {
      const int n = n0 + wn * (NF * 16) + (ni << 4) + lc;
      const int y = (n >> lw) & (H - 1);
      const int x = n & (W - 1);
      const int bb_ = n >> (lw + lh);
      const size_t op = (size_t)(bb_ * bso + y * Wpo + x + obase) * outS + outOff + ob;
      f16x4 h;
#pragma unroll
      for (int j = 0; j < 4; ++j) {
        const float s = gv[j] * BN_S;
        float v = acc[mi][ni][j] + (bv[j] * s + evv[j]);
        v = v > 0.f ? v : 0.f;
        h[j] = (_Float16)v;
      }
      *(f16x4*)(out + op) = h;
    }
  }
}

// ---------------------------------------------------------------------------
// conv1: Cin=3, Cout=64, 512x512, fp32 NCHW data + raw fp32 weights.
// ---------------------------------------------------------------------------
__global__ __launch_bounds__(256) void conv1_k(
    const float* __restrict__ data, const float* __restrict__ w1,
    const float* __restrict__ g1, const float* __restrict__ b1,
    const float* __restrict__ e1, _Float16* __restrict__ out) {
  __shared__ float patch[3][20][20];
  const int tid = threadIdx.x;
  const int bid = blockIdx.x;
  const int tx = bid & 31, ty = (bid >> 5) & 31, b = bid >> 10;

  for (int i = tid; i < 1200; i += 256) {
    const int c = i / 400;
    const int r = i - c * 400;
    const int pyy = r / 20;
    const int pxx = r - pyy * 20;
    const int gy = (ty << 4) + pyy - 2, gx = (tx << 4) + pxx - 2;
    float v = 0.f;
    if ((unsigned)gy < 512u && (unsigned)gx < 512u)
      v = data[((size_t)(b * 3 + c) << 18) + (gy << 9) + gx];
    patch[c][pyy][pxx] = v;
  }
  __syncthreads();

  const int py = tid >> 4, px = tid & 15;
  float acc[64];
#pragma unroll
  for (int o = 0; o < 64; ++o) acc[o] = 0.f;

  for (int c = 0; c < 3; ++c)
    for (int dy = 0; dy < 5; ++dy) {
#pragma unroll
      for (int dx = 0; dx < 5; ++dx) {
        const float v = patch[c][py + dy][px + dx];
        const float* wb = w1 + c * 25 + dy * 5 + dx;
#pragma unroll
        for (int o = 0; o < 64; ++o) acc[o] = fmaf(v, wb[o * 75], acc[o]);
      }
    }

  const int y = (ty << 4) + py, x = (tx << 4) + px;
  _Float16* op = out + ((size_t)(((b << 9) + y) << 9) + x) * 64;
#pragma unroll
  for (int oc = 0; oc < 8; ++oc) {
    f16x8 h;
#pragma unroll
    for (int j = 0; j < 8; ++j) {
      const int o = (oc << 3) + j;
      const float s = g1[o] * BN_S;
      const float t = b1[o] * s + e1[o];
      float v = fmaf(acc[o], s, t);
      v = v > 0.f ? v : 0.f;
      h[j] = (_Float16)v;
    }
    *(f16x8*)(op + (oc << 3)) = h;
  }
}

// ---------------------------------------------------------------------------
// avg-pool 2x2 stride 2, NHWC fp16, generic padded/unpadded addressing
// ---------------------------------------------------------------------------
__global__ void pool_k(const _Float16* __restrict__ in, _Float16* __restrict__ out,
                       int inS, int outS, int Wpi, int bsi, int ibase,
                       int Wpo, int bso, int obase,
                       int lwo, int lho, int lcc, int total) {
  const int idx = blockIdx.x * 256 + threadIdx.x;
  if (idx >= total) return;
  const int cc = idx & ((1 << lcc) - 1);
  const int pix = idx >> lcc;
  const int x = pix & ((1 << lwo) - 1);
  const int y = (pix >> lwo) & ((1 << lho) - 1);
  const int b = pix >> (lwo + lho);
  const int ip = b * bsi + (y << 1) * Wpi + (x << 1) + ibase;
  const _Float16* p = in + (size_t)ip * inS + (cc << 3);
  const f16x8 v00 = *(const f16x8*)p;
  const f16x8 v01 = *(const f16x8*)(p + inS);
  const f16x8 v10 = *(const f16x8*)(p + (size_t)Wpi * inS);
  const f16x8 v11 = *(const f16x8*)(p + (size_t)(Wpi + 1) * inS);
  f16x8 r;
#pragma unroll
  for (int j = 0; j < 8; ++j)
    r[j] = (_Float16)(((float)v00[j] + (float)v01[j] + (float)v10[j] + (float)v11[j]) * 0.25f);
  const int op = b * bso + y * Wpo + x + obase;
  *(f16x8*)(out + (size_t)op * outS + (cc << 3)) = r;
}

// ---------------------------------------------------------------------------
// bilinear 2x upsample (align_corners=True), NHWC fp16
// ---------------------------------------------------------------------------
__global__ void up_k(const _Float16* __restrict__ in, _Float16* __restrict__ out,
                     int inS, int outS, int outOff,
                     int Wpi, int bsi, int ibase,
                     int Wpo, int bso, int obase,
                     int lwi, int lhi, int lcc, float scale, int total) {
  const int idx = blockIdx.x * 256 + threadIdx.x;
  if (idx >= total) return;
  const int cc = idx & ((1 << lcc) - 1);
  const int pix = idx >> lcc;
  const int lwo = lwi + 1, lho = lhi + 1;
  const int ox = pix & ((1 << lwo) - 1);
  const int oy = (pix >> lwo) & ((1 << lho) - 1);
  const int b = pix >> (lwo + lho);
  const int Hi = 1 << lhi, Wi = 1 << lwi;
  const float fy = oy * scale;
  const int y0 = (int)fy;
  const float wy = fy - y0;
  const int y1 = min(y0 + 1, Hi - 1);
  const float fx = ox * scale;
  const int x0 = (int)fx;
  const float wx = fx - x0;
  const int x1 = min(x0 + 1, Wi - 1);
  const int rbase = b * bsi + ibase;
  const _Float16* basep = in + (cc << 3);
  const f16x8 v00 = *(const f16x8*)(basep + (size_t)(rbase + y0 * Wpi + x0) * inS);
  const f16x8 v01 = *(const f16x8*)(basep + (size_t)(rbase + y0 * Wpi + x1) * inS);
  const f16x8 v10 = *(const f16x8*)(basep + (size_t)(rbase + y1 * Wpi + x0) * inS);
  const f16x8 v11 = *(const f16x8*)(basep + (size_t)(rbase + y1 * Wpi + x1) * inS);
  f16x8 r;
#pragma unroll
  for (int j = 0; j < 8; ++j) {
    const float top = (float)v00[j] * (1.f - wx) + (float)v01[j] * wx;
    const float bot = (float)v10[j] * (1.f - wx) + (float)v11[j] * wx;
    r[j] = (_Float16)(top * (1.f - wy) + bot * wy);
  }
  const int op = b * bso + oy * Wpo + ox + obase;
  *(f16x8*)(out + (size_t)op * outS + outOff + (cc << 3)) = r;
}

// ---------------------------------------------------------------------------
// conv8 split: Cin=384 (= c2[128ch] ++ up7[256ch]), Cout=3, 256x256.
// blockIdx.y = channel group (12 chunks of 8ch); fp32 partials (no bias).
// 2048 blocks (8/CU) vs 512 -> 4x latency hiding (r12: grid-starved at 2/CU).
// ---------------------------------------------------------------------------
__global__ __launch_bounds__(256) void conv8_split(
    const _Float16* __restrict__ inA, const _Float16* __restrict__ inB,
    const _Float16* __restrict__ wt, float* __restrict__ part) {
  __shared__ f16x8 patch[2][20][20];
  const int tid = threadIdx.x;
  const int bid = blockIdx.x;  // 512
  const int z = blockIdx.y;    // 4 chunk groups
  const int tx = bid & 15, ty = (bid >> 4) & 15, b = bid >> 8;
  const int px = tid & 15, py = tid >> 4;
  const int x0 = tx << 4, y0 = ty << 4;

  float a0 = 0.f, a1 = 0.f, a2 = 0.f;
  const int c0 = z * 12;
  for (int c = c0; c < c0 + 12; ++c) {
    const _Float16* sbase;
    int str;
    if (c < 16) { sbase = inA + ((size_t)b << 23) + (c << 3); str = 128; }
    else        { sbase = inB + ((size_t)b << 24) + ((c - 16) << 3); str = 256; }
    for (int i = tid; i < 400; i += 256) {
      const int pyy = i / 20, pxx = i - pyy * 20;
      const int gy = y0 + pyy - 2, gx = x0 + pxx - 2;
      f16x8 v = f16x8_zero();
      if ((unsigned)gy < 256u && (unsigned)gx < 256u)
        v = *(const f16x8*)(sbase + (size_t)((gy << 8) + gx) * str);
      patch[c & 1][pyy][pxx] = v;
    }
    __syncthreads();
    const _Float16* wb_c = wt + c * 600;
#pragma unroll
    for (int dy = 0; dy < 5; ++dy) {
#pragma unroll
      for (int dxx = 0; dxx < 5; ++dxx) {
        const f16x8 v = patch[c & 1][py + dy][px + dxx];
        const _Float16* wb = wb_c + (dy * 5 + dxx) * 24;
#pragma unroll
        for (int j = 0; j < 8; ++j) {
          const float f = (float)v[j];
          a0 = fmaf(f, (float)wb[j], a0);
          a1 = fmaf(f, (float)wb[8 + j], a1);
          a2 = fmaf(f, (float)wb[16 + j], a2);
        }
      }
    }
    __syncthreads();  // fence patch reuse across parity (12 chunks/group)
  }

  const int opix = (b << 16) + ((y0 + py) << 8) + (x0 + px);
  f32x4 r = {a0, a1, a2, 0.f};
  *(f32x4*)(part + ((size_t)(z << 17) + opix) * 4) = r;
}

// reduce conv8 partials: sum 4 + bias + ReLU -> c8 fp16x4 (pad ch 3)
__global__ void reduce8_k(const float* __restrict__ part, _Float16* __restrict__ c8,
                          const float* __restrict__ b8, const float* __restrict__ g8,
                          const float* __restrict__ e8) {
  const int idx = blockIdx.x * 256 + threadIdx.x;  // < 131072
  const f32x4 v0 = *(const f32x4*)(part + (size_t)idx * 4);
  const f32x4 v1 = *(const f32x4*)(part + ((size_t)(1 << 17) + idx) * 4);
  const f32x4 v2 = *(const f32x4*)(part + ((size_t)(2 << 17) + idx) * 4);
  const f32x4 v3 = *(const f32x4*)(part + ((size_t)(3 << 17) + idx) * 4);
  f16x4 h;
#pragma unroll
  for (int j = 0; j < 3; ++j) {
    const float s = g8[j] * BN_S;
    float v = v0[j] + v1[j] + v2[j] + v3[j] + (b8[j] * s + e8[j]);
    v = v > 0.f ? v : 0.f;
    h[j] = (_Float16)v;
  }
  h[3] = (_Float16)0.f;
  *(f16x4*)(c8 + (size_t)idx * 4) = h;
}

// ---------------------------------------------------------------------------
// final: bilinear up(c8, 256->512) + 1x1 conv (wo,bo) + out = data*core (fp32)
// ---------------------------------------------------------------------------
__global__ void final_k(const float* __restrict__ data, const _Float16* __restrict__ c8,
                        const float* __restrict__ wo, const float* __restrict__ bo,
                        float* __restrict__ out) {
  const int idx = blockIdx.x * 256 + threadIdx.x;  // < 524288
  const int x = idx & 511, y = (idx >> 9) & 511, b = idx >> 18;
  const float sc = 255.f / 511.f;
  const float fy = y * sc;
  const int y0 = (int)fy;
  const float wy = fy - y0;
  const int y1 = min(y0 + 1, 255);
  const float fx = x * sc;
  const int x0 = (int)fx;
  const float wx = fx - x0;
  const int x1 = min(x0 + 1, 255);
  const f16x4 v00 = *(const f16x4*)(c8 + (size_t)((((b << 8) + y0) << 8) + x0) * 4);
  const f16x4 v01 = *(const f16x4*)(c8 + (size_t)((((b << 8) + y0) << 8) + x1) * 4);
  const f16x4 v10 = *(const f16x4*)(c8 + (size_t)((((b << 8) + y1) << 8) + x0) * 4);
  const f16x4 v11 = *(const f16x4*)(c8 + (size_t)((((b << 8) + y1) << 8) + x1) * 4);
  float u[3];
#pragma unroll
  for (int j = 0; j < 3; ++j) {
    const float top = (float)v00[j] * (1.f - wx) + (float)v01[j] * wx;
    const float bot = (float)v10[j] * (1.f - wx) + (float)v11[j] * wx;
    u[j] = top * (1.f - wy) + bot * wy;
  }
#pragma unroll
  for (int c = 0; c < 3; ++c) {
    const float core = bo[c] + wo[c * 3 + 0] * u[0] + wo[c * 3 + 1] * u[1] + wo[c * 3 + 2] * u[2];
    const size_t oi = ((size_t)(b * 3 + c) << 18) + (y << 9) + x;
    out[oi] = data[oi] * core;
  }
}

// ---------------------------------------------------------------------------
extern "C" void kernel_launch(void* const* d_in, const int* in_sizes, int n_in,
                              void* d_out, int out_size, void* d_ws, size_t ws_size,
                              hipStream_t stream) {
  const float* data = (const float*)d_in[0];
  const float *w[9], *bb[9], *gg[9], *ee[9];
  for (int n = 1; n <= 8; ++n) {
    w[n] = (const float*)d_in[1 + (n - 1) * 4];
    bb[n] = (const float*)d_in[2 + (n - 1) * 4];
    gg[n] = (const float*)d_in[3 + (n - 1) * 4];
    ee[n] = (const float*)d_in[4 + (n - 1) * 4];
  }
  const float* wo = (const float*)d_in[33];
  const float* bo = (const float*)d_in[34];
  float* out = (float*)d_out;
  (void)in_sizes; (void)n_in;

  // ---- workspace layout (aliased; padded activations; 194,810,112 B) ----
  // LIVENESS (r9): cat7's c3-half is live conv3->conv7; don't reuse between.
  const size_t NEEDED = 194810112ull;
  if (ws_size < NEEDED) {
    zero_out_k<<<(out_size + 255) / 256, 256, 0, stream>>>(out, out_size);
    return;
  }
  char* base = (char*)d_ws;
  size_t off = 0;
  auto alloc = [&](size_t bytes) -> char* {
    char* p = base + off;
    off += (bytes + 255) & ~(size_t)255;
    return p;
  };
  _Float16* W2t = (_Float16*)alloc(409600);     // 25*128*64*2
  _Float16* W3t = (_Float16*)alloc(1638400);    // 25*256*128*2
  _Float16* W4t = (_Float16*)alloc(6553600);    // 25*512*256*2
  _Float16* W5t = (_Float16*)alloc(13107200);   // 25*512*512*2
  _Float16* W6t = (_Float16*)alloc(26214400);   // 25*512*1024*2
  _Float16* W7t = (_Float16*)alloc(9830400);    // 25*256*768*2
  _Float16* W8t = (_Float16*)alloc(57600);      // 48*25*24 fp16
  char* Rbig = alloc(72466432);   // c1(67.1M) | cat7(53.5M)+cat6(18.9M) | up7(67.1M)
  char* c2b_ = alloc(33554432);   // c2 (2,256,256,128) unpadded
  char* R1 = alloc(17305600);     // p1(17.3M) | c6(8.4M) | c7(16.8M) | c8(1M)+part8(8M)
  char* R2 = alloc(13672448);     // p2(8.9M) ; [p3(4.7M) | p4(2.65M)+c5(2.1M)]

  _Float16* c1 = (_Float16*)Rbig;                    // (2,512,512,64) unpadded
  _Float16* cat7 = (_Float16*)Rbig;                  // (2,132,132,768) padded
  _Float16* cat6 = (_Float16*)(Rbig + 53526528);     // (2,68,68,1024) padded
  _Float16* up7b = (_Float16*)Rbig;                  // (2,256,256,256) unpadded
  _Float16* c2buf = (_Float16*)c2b_;                 // (2,256,256,128) unpadded
  _Float16* p1 = (_Float16*)R1;                      // (2,260,260,64) padded
  _Float16* c6 = (_Float16*)R1;                      // (2,64,64,512) unpadded
  _Float16* c7 = (_Float16*)R1;                      // (2,128,128,256) unpadded
  _Float16* c8 = (_Float16*)R1;                      // (2,256,256,4) unpadded
  float* part8 = (float*)(R1 + 1048576);             // [4][131072][4] fp32 (8MB; c7 dead)
  _Float16* p2 = (_Float16*)R2;                      // (2,132,132,128) padded
  _Float16* p3 = (_Float16*)(R2 + 8921088);          // (2,68,68,256) padded
  _Float16* p4 = (_Float16*)(R2 + 8921088);          // (2,36,36,512) padded (aliases p3!)
  _Float16* c5 = (_Float16*)(R2 + 8921088 + 2654208);// (2,32,32,512) unpadded

  // zero halo buffers not aliased with earlier-live data.
  // NOTE: p4 aliases p3, so p4's halo must be zeroed AFTER conv4 (p3 dead).
  zero16_k<<<(1081600 + 255) / 256, 256, 0, stream>>>(p1, 1081600);   // 17.3MB
  zero16_k<<<(557568 + 255) / 256, 256, 0, stream>>>(p2, 557568);     // 8.9MB
  zero16_k<<<(295936 + 255) / 256, 256, 0, stream>>>(p3, 295936);     // 4.7MB

  // weight transforms (fold BN scale into weights)
  wtrans16<<<(25 * 128 * 64 + 255) / 256, 256, 0, stream>>>(w[2], W2t, gg[2], 128, 64, 25 * 128 * 64);
  wtrans16<<<(25 * 256 * 128 + 255) / 256, 256, 0, stream>>>(w[3], W3t, gg[3], 256, 128, 25 * 256 * 128);
  wtrans16<<<(25 * 512 * 256 + 255) / 256, 256, 0, stream>>>(w[4], W4t, gg[4], 512, 256, 25 * 512 * 256);
  wtrans16<<<(25 * 512 * 512 + 255) / 256, 256, 0, stream>>>(w[5], W5t, gg[5], 512, 512, 25 * 512 * 512);
  wtrans16<<<(25 * 512 * 1024 + 255) / 256, 256, 0, stream>>>(w[6], W6t, gg[6], 512, 1024, 25 * 512 * 1024);
  wtrans16<<<(25 * 256 * 768 + 255) / 256, 256, 0, stream>>>(w[7], W7t, gg[7], 256, 768, 25 * 256 * 768);
  wtrans8<<<(28800 + 255) / 256, 256, 0, stream>>>(w[8], W8t, gg[8]);

  conv1_k<<<2048, 256, 0, stream>>>(data, w[1], gg[1], bb[1], ee[1], c1);
  pool_k<<<1048576 / 256, 256, 0, stream>>>(c1, p1, 64, 64, 512, 262144, 0,
                                            260, 67600, 522, 8, 8, 3, 1048576);
  // c1 dead -> zero cat7/cat6 (they alias c1's region)
  zero16_k<<<(3345408 + 255) / 256, 256, 0, stream>>>(cat7, 3345408);  // 53.5MB
  zero16_k<<<(1183744 + 255) / 256, 256, 0, stream>>>(cat6, 1183744);  // 18.9MB

  conv_gemm<4, 4, 1, 2><<<dim3(1024, 1), 256, 0, stream>>>(p1, W2t, gg[2], bb[2], ee[2], c2buf,
      64, 128, 8, 8, 64, 260, 67600, 522, 128, 0, 256, 65536, 0);
  pool_k<<<524288 / 256, 256, 0, stream>>>(c2buf, p2, 128, 128, 256, 65536, 0,
                                           132, 17424, 266, 7, 7, 4, 524288);
  // conv3: act(8.9M) > wt(1.6M) -> keep BM=128
  conv_gemm<4, 4, 2, 3><<<dim3(256, 2), 256, 0, stream>>>(p2, W3t, gg[3], bb[3], ee[3], cat7,
      128, 256, 7, 7, 128, 132, 17424, 266, 768, 0, 132, 17424, 266);
  pool_k<<<262144 / 256, 256, 0, stream>>>(cat7, p3, 768, 256, 132, 17424, 266,
                                           68, 4624, 138, 6, 6, 5, 262144);
  // conv4: act(4.7M) < wt(6.5M) -> BM-split, 512 blocks (2/CU)
  conv_gemm<2, 4, 2, 4><<<dim3(64, 8), 256, 0, stream>>>(p3, W4t, gg[4], bb[4], ee[4], cat6,
      256, 512, 6, 6, 256, 68, 4624, 138, 1024, 0, 68, 4624, 138);
  // p3 dead -> now safe to zero p4's halo (p4 aliases p3's bytes)
  zero16_k<<<(165888 + 255) / 256, 256, 0, stream>>>(p4, 165888);      // 2.65MB
  pool_k<<<131072 / 256, 256, 0, stream>>>(cat6, p4, 1024, 512, 68, 4624, 138,
                                           36, 1296, 74, 5, 5, 6, 131072);
  conv_gemm<2, 2, 2, 5><<<dim3(32, 8), 256, 0, stream>>>(p4, W5t, gg[5], bb[5], ee[5], c5,
      512, 512, 5, 5, 512, 36, 1296, 74, 512, 0, 32, 1024, 0);
  up_k<<<524288 / 256, 256, 0, stream>>>(c5, cat6, 512, 1024, 512,
                                         32, 1024, 0, 68, 4624, 138,
                                         5, 5, 6, 31.f / 63.f, 524288);
  // conv6: act(18.9M) < wt(26M) -> BM-split, 512 blocks (2/CU)
  conv_gemm<2, 4, 2, 6><<<dim3(64, 8), 256, 0, stream>>>(cat6, W6t, gg[6], bb[6], ee[6], c6,
      1024, 512, 6, 6, 1024, 68, 4624, 138, 512, 0, 64, 4096, 0);
  up_k<<<2097152 / 256, 256, 0, stream>>>(c6, cat7, 512, 768, 256,
                                          64, 4096, 0, 132, 17424, 266,
                                          6, 6, 6, 63.f / 127.f, 2097152);
  // conv7: act(53.5M) > wt(9.8M) -> keep BM=128
  conv_gemm<4, 4, 2, 7><<<dim3(256, 2), 256, 0, stream>>>(cat7, W7t, gg[7], bb[7], ee[7], c7,
      768, 256, 7, 7, 768, 132, 17424, 266, 256, 0, 128, 16384, 0);
  up_k<<<4194304 / 256, 256, 0, stream>>>(c7, up7b, 256, 256, 0,
                                          128, 16384, 0, 256, 65536, 0,
                                          7, 7, 5, 127.f / 255.f, 4194304);
  conv8_split<<<dim3(512, 4), 256, 0, stream>>>(c2buf, up7b, W8t, part8);
  reduce8_k<<<512, 256, 0, stream>>>(part8, c8, bb[8], gg[8], ee[8]);
  final_k<<<524288 / 256, 256, 0, stream>>>(data, c8, wo, bo, out);
}

// Round 14
// 1797.698 us; speedup vs baseline: 1.3274x; 1.0085x over previous
//
#include <hip/hip_runtime.h>
#include <hip/hip_bf16.h>

typedef _Float16 f16x8 __attribute__((ext_vector_type(8)));
typedef _Float16 f16x4 __attribute__((ext_vector_type(4)));
typedef float f32x4 __attribute__((ext_vector_type(4)));

#define BN_S 0.99999500003749975f  // 1/sqrt(1+1e-5)

__device__ inline f16x8 f16x8_zero() {
  f16x8 v = {(_Float16)0.f, (_Float16)0.f, (_Float16)0.f, (_Float16)0.f,
             (_Float16)0.f, (_Float16)0.f, (_Float16)0.f, (_Float16)0.f};
  return v;
}

__device__ __forceinline__ void load_lds16(const _Float16* g, _Float16* l) {
  __builtin_amdgcn_global_load_lds(
      (const __attribute__((address_space(1))) void*)g,
      (__attribute__((address_space(3))) void*)l, 16, 0, 0);
}

__global__ void zero_out_k(float* __restrict__ out, int n) {
  const int idx = blockIdx.x * 256 + threadIdx.x;
  if (idx < n) out[idx] = 0.f;
}

// ---------------------------------------------------------------------------
// Zero only the 2-pixel halo ring of a padded square NHWC buffer.
// Wp = padded width (= height), C8 = channels/8, nb = 4*C8*(2*Wp-4) per batch,
// total = 2*nb. Interiors are fully overwritten by producers (audited r13).
// ---------------------------------------------------------------------------
__global__ void halo_k(_Float16* __restrict__ p, int Wp, int C8, int nb, int total) {
  const int idx = blockIdx.x * 256 + threadIdx.x;
  if (idx >= total) return;
  const int b = idx / nb;
  const int r = idx - b * nb;
  const int tb = 4 * Wp * C8;  // top+bottom strips
  int pix, cc;
  if (r < tb) {
    const int s = r / C8;
    cc = r - s * C8;
    pix = (s < 2 * Wp) ? s : (Wp * Wp - 4 * Wp + s);  // rows {0,1} | {Wp-2,Wp-1}
  } else {
    const int r2 = r - tb;
    const int s = r2 / C8;
    cc = r2 - s * C8;
    const int row = 2 + (s >> 2);
    const int k = s & 3;
    const int col = (k < 2) ? k : (Wp - 4 + k);       // cols {0,1,Wp-2,Wp-1}
    pix = row * Wp + col;
  }
  ((f16x8*)p)[(size_t)(b * Wp * Wp + pix) * C8 + cc] = f16x8_zero();
}

// ---------------------------------------------------------------------------
// Weight transform: OIHW fp32 -> [25][O][C] fp16, pre-scaled by g*BN_S.
// ---------------------------------------------------------------------------
__global__ void wtrans16(const float* __restrict__ src, _Float16* __restrict__ dst,
                         const float* __restrict__ g, int O, int C, int total) {
  const int idx = blockIdx.x * 256 + threadIdx.x;  // (t, o, c)
  if (idx >= total) return;
  const int OC = O * C;
  const int t = idx / OC;
  const int rem = idx - t * OC;
  const int o = rem / C;
  const int c = rem - o * C;
  dst[idx] = (_Float16)(src[(size_t)(o * C + c) * 25 + t] * g[o] * BN_S);
}

// conv8 weights: OIHW fp32 (O=3,C=384) -> [48 chunks][25 taps][3][8] fp16.
__global__ void wtrans8(const float* __restrict__ src, _Float16* __restrict__ dst,
                        const float* __restrict__ g) {
  const int idx = blockIdx.x * 256 + threadIdx.x;
  if (idx >= 28800) return;
  const int c = idx / 600;
  const int r = idx - c * 600;
  const int tap = r / 24;
  const int q = r - tap * 24;
  const int o = q >> 3, j = q & 7;
  const int cin = (c < 16) ? (c * 8 + j) : (128 + (c - 16) * 8 + j);
  dst[idx] = (_Float16)(src[((size_t)o * 384 + cin) * 25 + tap] * g[o] * BN_S);
}

// ---------------------------------------------------------------------------
// Implicit-GEMM 5x5 conv + BN + ReLU.  Cin%(32*KS)==0, Cout%BM==0, px%BN==0.
// Block tile BM(cout) x BN(px); 4 waves 2x2; KS k-steps staged per barrier
// into double-buffered LDS via global_load_lds(16B). XOR-swizzled LDS.
// TAG gives each layer a distinct symbol for profiling.
// Tile-split rule (r5/r9/r11): split along the dimension whose operand
// panel is SMALLER. conv4/conv6: act < wt -> BM-split OK. conv3/conv7:
// act > wt -> keep BM=128.
// NO XCD blockIdx swizzle (r12: it broke the natural round-robin's
// x-column sharing across y-slices; FETCH 1.65GB on conv6, -185us total).
// ---------------------------------------------------------------------------
template <int MF, int NF, int KS, int TAG>
__global__ __launch_bounds__(256) void conv_gemm(
    const _Float16* __restrict__ in, const _Float16* __restrict__ wt,
    const float* __restrict__ gg, const float* __restrict__ bbv,
    const float* __restrict__ ev, _Float16* __restrict__ out,
    int Cin, int Cout, int lw, int lh,
    int inS, int Wpi, int bsi, int ibase,
    int outS, int outOff, int Wpo, int bso, int obase) {
  constexpr int BM = MF * 32;
  constexpr int BN = NF * 32;
  constexpr int SUB_A = BM * 32;  // halfwords per k-substep
  constexpr int SUB_B = BN * 32;
  __shared__ _Float16 sA[2][SUB_A * KS];
  __shared__ _Float16 sB[2][SUB_B * KS];

  const int tid = threadIdx.x;
  const int lane = tid & 63;
  const int wid = tid >> 6;
  const int wm = wid >> 1, wn = wid & 1;
  const int lr = lane >> 4, lc = lane & 15;
  const int n0 = blockIdx.x * BN;
  const int m0 = blockIdx.y * BM;
  const int H = 1 << lh, W = 1 << lw;
  const int nkb = Cin >> 5;

  // staging identity: linear g = issue*256 + tid; row=g>>2, slot=g&3
  const int r0 = tid >> 2;
  const int chunk = (tid & 3) ^ ((r0 >> 1) & 3);  // same for row r0+64

  const _Float16* a0 = wt + (size_t)(m0 + r0) * Cin + (chunk << 3);
  const _Float16* a1 = a0 + ((size_t)Cin << 6);  // used only if BM==128
  const int t0off = -2 * Wpi - 2;  // tap (dy=0,dx=0)
  const _Float16 *b0, *b1 = nullptr;
  {
    int n = n0 + r0;
    int pix0 = (n >> (lw + lh)) * bsi + ((n >> lw) & (H - 1)) * Wpi + (n & (W - 1)) + ibase;
    b0 = in + (size_t)(pix0 + t0off) * inS + (chunk << 3);
    if constexpr (BN == 128) {
      n = n0 + r0 + 64;
      int pix1 = (n >> (lw + lh)) * bsi + ((n >> lw) & (H - 1)) * Wpi + (n & (W - 1)) + ibase;
      b1 = in + (size_t)(pix1 + t0off) * inS + (chunk << 3);
    }
  }

  // ds_read fragment swizzle (halfwords)
  const int swz = (lr ^ ((lc >> 1) & 3)) << 3;

  f32x4 acc[MF][NF];
  const f32x4 vz = {0.f, 0.f, 0.f, 0.f};
#pragma unroll
  for (int i = 0; i < MF; ++i)
#pragma unroll
    for (int j = 0; j < NF; ++j) acc[i][j] = vz;

  const int np = 25 * nkb / KS;  // staged groups
  int kb = 0, dx = 0;
  const size_t a_tap = (size_t)Cout * Cin - ((size_t)nkb << 5);
  const int woff = wid << 9;  // wave LDS base within a 4KB issue (halfwords)

  // advance staging pointers by one group (KS k-steps)
  auto advance = [&]() {
    a0 += 32 * KS; b0 += 32 * KS;
    if constexpr (BM == 128) a1 += 32 * KS;
    if constexpr (BN == 128) b1 += 32 * KS;
    kb += KS;
    if (kb == nkb) {
      kb = 0;
      a0 += a_tap;
      if constexpr (BM == 128) a1 += a_tap;
      int pd;
      if (++dx == 5) { dx = 0; pd = Wpi - 4; } else pd = 1;
      const ptrdiff_t bd = (ptrdiff_t)pd * inS - ((ptrdiff_t)nkb << 5);
      b0 += bd;
      if constexpr (BN == 128) b1 += bd;
    }
  };
  auto stage = [&](int buf) {
#pragma unroll
    for (int s = 0; s < KS; ++s) {
      _Float16* sa = sA[buf] + s * SUB_A + woff;
      _Float16* sb = sB[buf] + s * SUB_B + woff;
      load_lds16(a0 + 32 * s, sa);
      if constexpr (BM == 128) load_lds16(a1 + 32 * s, sa + 2048);
      load_lds16(b0 + 32 * s, sb);
      if constexpr (BN == 128) load_lds16(b1 + 32 * s, sb + 2048);
    }
  };

  // prologue: stage group 0 into buf 0
  stage(0);
  __syncthreads();

  int cur = 0;
  for (int t = 0; t < np; ++t) {
    if (t + 1 < np) {
      advance();
      stage(cur ^ 1);
    }
    const _Float16* pA = sA[cur];
    const _Float16* pB = sB[cur];
#pragma unroll
    for (int s = 0; s < KS; ++s) {
      f16x8 af[MF], bf[NF];
#pragma unroll
      for (int i = 0; i < MF; ++i)
        af[i] = *(const f16x8*)(pA + s * SUB_A + ((wm * (MF * 16) + (i << 4) + lc) << 5) + swz);
#pragma unroll
      for (int i = 0; i < NF; ++i)
        bf[i] = *(const f16x8*)(pB + s * SUB_B + ((wn * (NF * 16) + (i << 4) + lc) << 5) + swz);
#pragma unroll
      for (int mi = 0; mi < MF; ++mi)
#pragma unroll
        for (int ni = 0; ni < NF; ++ni)
          acc[mi][ni] =
              __builtin_amdgcn_mfma_f32_16x16x32_f16(af[mi], bf[ni], acc[mi][ni], 0, 0, 0);
    }
    __syncthreads();  // drains stage(cur^1) loads + fences buf reuse
    cur ^= 1;
  }

  // Epilogue: D col = lane&15 -> pixel, row = lr*4+j -> cout
#pragma unroll
  for (int mi = 0; mi < MF; ++mi) {
    const int ob = m0 + wm * (MF * 16) + (mi << 4) + (lr << 2);
    const f32x4 gv = *(const f32x4*)(gg + ob);
    const f32x4 bv = *(const f32x4*)(bbv + ob);
    const f32x4 evv = *(const f32x4*)(ev + ob);
#pragma unroll
    for (int ni = 0; ni < NF; ++ni) {
      const int n = n0 + wn * (NF * 16) + (ni << 4) + lc;
      const int y = (n >> lw) & (H - 1);
      const int x = n & (W - 1);
      const int bb_ = n >> (lw + lh);
      const size_t op = (size_t)(bb_ * bso + y * Wpo + x + obase) * outS + outOff + ob;
      f16x4 h;
#pragma unroll
      for (int j = 0; j < 4; ++j) {
        const float s = gv[j] * BN_S;
        float v = acc[mi][ni][j] + (bv[j] * s + evv[j]);
        v = v > 0.f ? v : 0.f;
        h[j] = (_Float16)v;
      }
      *(f16x4*)(out + op) = h;
    }
  }
}

// ---------------------------------------------------------------------------
// conv1: Cin=3, Cout=64, 512x512, fp32 NCHW data + raw fp32 weights.
// ---------------------------------------------------------------------------
__global__ __launch_bounds__(256) void conv1_k(
    const float* __restrict__ data, const float* __restrict__ w1,
    const float* __restrict__ g1, const float* __restrict__ b1,
    const float* __restrict__ e1, _Float16* __restrict__ out) {
  __shared__ float patch[3][20][20];
  const int tid = threadIdx.x;
  const int bid = blockIdx.x;
  const int tx = bid & 31, ty = (bid >> 5) & 31, b = bid >> 10;

  for (int i = tid; i < 1200; i += 256) {
    const int c = i / 400;
    const int r = i - c * 400;
    const int pyy = r / 20;
    const int pxx = r - pyy * 20;
    const int gy = (ty << 4) + pyy - 2, gx = (tx << 4) + pxx - 2;
    float v = 0.f;
    if ((unsigned)gy < 512u && (unsigned)gx < 512u)
      v = data[((size_t)(b * 3 + c) << 18) + (gy << 9) + gx];
    patch[c][pyy][pxx] = v;
  }
  __syncthreads();

  const int py = tid >> 4, px = tid & 15;
  float acc[64];
#pragma unroll
  for (int o = 0; o < 64; ++o) acc[o] = 0.f;

  for (int c = 0; c < 3; ++c)
    for (int dy = 0; dy < 5; ++dy) {
#pragma unroll
      for (int dx = 0; dx < 5; ++dx) {
        const float v = patch[c][py + dy][px + dx];
        const float* wb = w1 + c * 25 + dy * 5 + dx;
#pragma unroll
        for (int o = 0; o < 64; ++o) acc[o] = fmaf(v, wb[o * 75], acc[o]);
      }
    }

  const int y = (ty << 4) + py, x = (tx << 4) + px;
  _Float16* op = out + ((size_t)(((b << 9) + y) << 9) + x) * 64;
#pragma unroll
  for (int oc = 0; oc < 8; ++oc) {
    f16x8 h;
#pragma unroll
    for (int j = 0; j < 8; ++j) {
      const int o = (oc << 3) + j;
      const float s = g1[o] * BN_S;
      const float t = b1[o] * s + e1[o];
      float v = fmaf(acc[o], s, t);
      v = v > 0.f ? v : 0.f;
      h[j] = (_Float16)v;
    }
    *(f16x8*)(op + (oc << 3)) = h;
  }
}

// ---------------------------------------------------------------------------
// avg-pool 2x2 stride 2, NHWC fp16, generic padded/unpadded addressing
// ---------------------------------------------------------------------------
__global__ void pool_k(const _Float16* __restrict__ in, _Float16* __restrict__ out,
                       int inS, int outS, int Wpi, int bsi, int ibase,
                       int Wpo, int bso, int obase,
                       int lwo, int lho, int lcc, int total) {
  const int idx = blockIdx.x * 256 + threadIdx.x;
  if (idx >= total) return;
  const int cc = idx & ((1 << lcc) - 1);
  const int pix = idx >> lcc;
  const int x = pix & ((1 << lwo) - 1);
  const int y = (pix >> lwo) & ((1 << lho) - 1);
  const int b = pix >> (lwo + lho);
  const int ip = b * bsi + (y << 1) * Wpi + (x << 1) + ibase;
  const _Float16* p = in + (size_t)ip * inS + (cc << 3);
  const f16x8 v00 = *(const f16x8*)p;
  const f16x8 v01 = *(const f16x8*)(p + inS);
  const f16x8 v10 = *(const f16x8*)(p + (size_t)Wpi * inS);
  const f16x8 v11 = *(const f16x8*)(p + (size_t)(Wpi + 1) * inS);
  f16x8 r;
#pragma unroll
  for (int j = 0; j < 8; ++j)
    r[j] = (_Float16)(((float)v00[j] + (float)v01[j] + (float)v10[j] + (float)v11[j]) * 0.25f);
  const int op = b * bso + y * Wpo + x + obase;
  *(f16x8*)(out + (size_t)op * outS + (cc << 3)) = r;
}

// ---------------------------------------------------------------------------
// bilinear 2x upsample (align_corners=True), NHWC fp16
// ---------------------------------------------------------------------------
__global__ void up_k(const _Float16* __restrict__ in, _Float16* __restrict__ out,
                     int inS, int outS, int outOff,
                     int Wpi, int bsi, int ibase,
                     int Wpo, int bso, int obase,
                     int lwi, int lhi, int lcc, float scale, int total) {
  const int idx = blockIdx.x * 256 + threadIdx.x;
  if (idx >= total) return;
  const int cc = idx & ((1 << lcc) - 1);
  const int pix = idx >> lcc;
  const int lwo = lwi + 1, lho = lhi + 1;
  const int ox = pix & ((1 << lwo) - 1);
  const int oy = (pix >> lwo) & ((1 << lho) - 1);
  const int b = pix >> (lwo + lho);
  const int Hi = 1 << lhi, Wi = 1 << lwi;
  const float fy = oy * scale;
  const int y0 = (int)fy;
  const float wy = fy - y0;
  const int y1 = min(y0 + 1, Hi - 1);
  const float fx = ox * scale;
  const int x0 = (int)fx;
  const float wx = fx - x0;
  const int x1 = min(x0 + 1, Wi - 1);
  const int rbase = b * bsi + ibase;
  const _Float16* basep = in + (cc << 3);
  const f16x8 v00 = *(const f16x8*)(basep + (size_t)(rbase + y0 * Wpi + x0) * inS);
  const f16x8 v01 = *(const f16x8*)(basep + (size_t)(rbase + y0 * Wpi + x1) * inS);
  const f16x8 v10 = *(const f16x8*)(basep + (size_t)(rbase + y1 * Wpi + x0) * inS);
  const f16x8 v11 = *(const f16x8*)(basep + (size_t)(rbase + y1 * Wpi + x1) * inS);
  f16x8 r;
#pragma unroll
  for (int j = 0; j < 8; ++j) {
    const float top = (float)v00[j] * (1.f - wx) + (float)v01[j] * wx;
    const float bot = (float)v10[j] * (1.f - wx) + (float)v11[j] * wx;
    r[j] = (_Float16)(top * (1.f - wy) + bot * wy);
  }
  const int op = b * bso + oy * Wpo + ox + obase;
  *(f16x8*)(out + (size_t)op * outS + outOff + (cc << 3)) = r;
}

// ---------------------------------------------------------------------------
// conv8 (LDS-tiled): Cin=384 (= c2[128ch] ++ up7[256ch]), Cout=3, 256x256.
// ---------------------------------------------------------------------------
__global__ __launch_bounds__(256) void conv8_lds(
    const _Float16* __restrict__ inA, const _Float16* __restrict__ inB,
    const _Float16* __restrict__ wt, const float* __restrict__ b8,
    const float* __restrict__ g8, const float* __restrict__ e8,
    _Float16* __restrict__ out) {
  __shared__ f16x8 patch[2][20][20];
  const int tid = threadIdx.x;
  const int bid = blockIdx.x;  // 512
  const int tx = bid & 15, ty = (bid >> 4) & 15, b = bid >> 8;
  const int px = tid & 15, py = tid >> 4;
  const int x0 = tx << 4, y0 = ty << 4;

  float a0 = 0.f, a1 = 0.f, a2 = 0.f;
  for (int c = 0; c < 48; ++c) {
    const _Float16* sbase;
    int str;
    if (c < 16) { sbase = inA + ((size_t)b << 23) + (c << 3); str = 128; }
    else        { sbase = inB + ((size_t)b << 24) + ((c - 16) << 3); str = 256; }
    for (int i = tid; i < 400; i += 256) {
      const int pyy = i / 20, pxx = i - pyy * 20;
      const int gy = y0 + pyy - 2, gx = x0 + pxx - 2;
      f16x8 v = f16x8_zero();
      if ((unsigned)gy < 256u && (unsigned)gx < 256u)
        v = *(const f16x8*)(sbase + (size_t)((gy << 8) + gx) * str);
      patch[c & 1][pyy][pxx] = v;
    }
    __syncthreads();
    const _Float16* wb_c = wt + c * 600;
#pragma unroll
    for (int dy = 0; dy < 5; ++dy) {
#pragma unroll
      for (int dxx = 0; dxx < 5; ++dxx) {
        const f16x8 v = patch[c & 1][py + dy][px + dxx];
        const _Float16* wb = wb_c + (dy * 5 + dxx) * 24;
#pragma unroll
        for (int j = 0; j < 8; ++j) {
          const float f = (float)v[j];
          a0 = fmaf(f, (float)wb[j], a0);
          a1 = fmaf(f, (float)wb[8 + j], a1);
          a2 = fmaf(f, (float)wb[16 + j], a2);
        }
      }
    }
  }

  const float s0 = g8[0] * BN_S, t0 = b8[0] * s0 + e8[0];
  const float s1 = g8[1] * BN_S, t1 = b8[1] * s1 + e8[1];
  const float s2 = g8[2] * BN_S, t2 = b8[2] * s2 + e8[2];
  float r0 = a0 + t0, r1 = a1 + t1, r2 = a2 + t2;
  r0 = r0 > 0.f ? r0 : 0.f;
  r1 = r1 > 0.f ? r1 : 0.f;
  r2 = r2 > 0.f ? r2 : 0.f;
  f16x4 h;
  h[0] = (_Float16)r0; h[1] = (_Float16)r1; h[2] = (_Float16)r2; h[3] = (_Float16)0.f;
  const int opix = (b << 16) + ((y0 + py) << 8) + (x0 + px);
  *(f16x4*)(out + (size_t)opix * 4) = h;
}

// ---------------------------------------------------------------------------
// final: bilinear up(c8, 256->512) + 1x1 conv (wo,bo) + out = data*core (fp32)
// ---------------------------------------------------------------------------
__global__ void final_k(const float* __restrict__ data, const _Float16* __restrict__ c8,
                        const float* __restrict__ wo, const float* __restrict__ bo,
                        float* __restrict__ out) {
  const int idx = blockIdx.x * 256 + threadIdx.x;  // < 524288
  const int x = idx & 511, y = (idx >> 9) & 511, b = idx >> 18;
  const float sc = 255.f / 511.f;
  const float fy = y * sc;
  const int y0 = (int)fy;
  const float wy = fy - y0;
  const int y1 = min(y0 + 1, 255);
  const float fx = x * sc;
  const int x0 = (int)fx;
  const float wx = fx - x0;
  const int x1 = min(x0 + 1, 255);
  const f16x4 v00 = *(const f16x4*)(c8 + (size_t)((((b << 8) + y0) << 8) + x0) * 4);
  const f16x4 v01 = *(const f16x4*)(c8 + (size_t)((((b << 8) + y0) << 8) + x1) * 4);
  const f16x4 v10 = *(const f16x4*)(c8 + (size_t)((((b << 8) + y1) << 8) + x0) * 4);
  const f16x4 v11 = *(const f16x4*)(c8 + (size_t)((((b << 8) + y1) << 8) + x1) * 4);
  float u[3];
#pragma unroll
  for (int j = 0; j < 3; ++j) {
    const float top = (float)v00[j] * (1.f - wx) + (float)v01[j] * wx;
    const float bot = (float)v10[j] * (1.f - wx) + (float)v11[j] * wx;
    u[j] = top * (1.f - wy) + bot * wy;
  }
#pragma unroll
  for (int c = 0; c < 3; ++c) {
    const float core = bo[c] + wo[c * 3 + 0] * u[0] + wo[c * 3 + 1] * u[1] + wo[c * 3 + 2] * u[2];
    const size_t oi = ((size_t)(b * 3 + c) << 18) + (y << 9) + x;
    out[oi] = data[oi] * core;
  }
}

// ---------------------------------------------------------------------------
extern "C" void kernel_launch(void* const* d_in, const int* in_sizes, int n_in,
                              void* d_out, int out_size, void* d_ws, size_t ws_size,
                              hipStream_t stream) {
  const float* data = (const float*)d_in[0];
  const float *w[9], *bb[9], *gg[9], *ee[9];
  for (int n = 1; n <= 8; ++n) {
    w[n] = (const float*)d_in[1 + (n - 1) * 4];
    bb[n] = (const float*)d_in[2 + (n - 1) * 4];
    gg[n] = (const float*)d_in[3 + (n - 1) * 4];
    ee[n] = (const float*)d_in[4 + (n - 1) * 4];
  }
  const float* wo = (const float*)d_in[33];
  const float* bo = (const float*)d_in[34];
  float* out = (float*)d_out;
  (void)in_sizes; (void)n_in;

  // ---- workspace layout (aliased; padded activations; 194,810,112 B) ----
  // LIVENESS (r9): cat7's c3-half is live conv3->conv7; don't reuse between.
  const size_t NEEDED = 194810112ull;
  if (ws_size < NEEDED) {
    zero_out_k<<<(out_size + 255) / 256, 256, 0, stream>>>(out, out_size);
    return;
  }
  char* base = (char*)d_ws;
  size_t off = 0;
  auto alloc = [&](size_t bytes) -> char* {
    char* p = base + off;
    off += (bytes + 255) & ~(size_t)255;
    return p;
  };
  _Float16* W2t = (_Float16*)alloc(409600);     // 25*128*64*2
  _Float16* W3t = (_Float16*)alloc(1638400);    // 25*256*128*2
  _Float16* W4t = (_Float16*)alloc(6553600);    // 25*512*256*2
  _Float16* W5t = (_Float16*)alloc(13107200);   // 25*512*512*2
  _Float16* W6t = (_Float16*)alloc(26214400);   // 25*512*1024*2
  _Float16* W7t = (_Float16*)alloc(9830400);    // 25*256*768*2
  _Float16* W8t = (_Float16*)alloc(57600);      // 48*25*24 fp16
  char* Rbig = alloc(72466432);   // c1(67.1M) | cat7(53.5M)+cat6(18.9M) | up7(67.1M)
  char* c2b_ = alloc(33554432);   // c2 (2,256,256,128) unpadded
  char* R1 = alloc(17305600);     // p1(17.3M) | c6(8.4M) | c7(16.8M) | c8(1M)
  char* R2 = alloc(13672448);     // p2(8.9M) ; [p3(4.7M) | p4(2.65M)+c5(2.1M)]

  _Float16* c1 = (_Float16*)Rbig;                    // (2,512,512,64) unpadded
  _Float16* cat7 = (_Float16*)Rbig;                  // (2,132,132,768) padded
  _Float16* cat6 = (_Float16*)(Rbig + 53526528);     // (2,68,68,1024) padded
  _Float16* up7b = (_Float16*)Rbig;                  // (2,256,256,256) unpadded
  _Float16* c2buf = (_Float16*)c2b_;                 // (2,256,256,128) unpadded
  _Float16* p1 = (_Float16*)R1;                      // (2,260,260,64) padded
  _Float16* c6 = (_Float16*)R1;                      // (2,64,64,512) unpadded
  _Float16* c7 = (_Float16*)R1;                      // (2,128,128,256) unpadded
  _Float16* c8 = (_Float16*)R1;                      // (2,256,256,4) unpadded
  _Float16* p2 = (_Float16*)R2;                      // (2,132,132,128) padded
  _Float16* p3 = (_Float16*)(R2 + 8921088);          // (2,68,68,256) padded
  _Float16* p4 = (_Float16*)(R2 + 8921088);          // (2,36,36,512) padded (aliases p3!)
  _Float16* c5 = (_Float16*)(R2 + 8921088 + 2654208);// (2,32,32,512) unpadded

  // halo-only zeroing (r14: interiors are fully overwritten by producers).
  // NOTE: p4 aliases p3, so p4's halo is zeroed AFTER conv4 (p3 dead).
  halo_k<<<(33024 + 255) / 256, 256, 0, stream>>>(p1, 260, 8, 16512, 33024);
  halo_k<<<(33280 + 255) / 256, 256, 0, stream>>>(p2, 132, 16, 16640, 33280);
  halo_k<<<(33792 + 255) / 256, 256, 0, stream>>>(p3, 68, 32, 16896, 33792);

  // weight transforms (fold BN scale into weights)
  wtrans16<<<(25 * 128 * 64 + 255) / 256, 256, 0, stream>>>(w[2], W2t, gg[2], 128, 64, 25 * 128 * 64);
  wtrans16<<<(25 * 256 * 128 + 255) / 256, 256, 0, stream>>>(w[3], W3t, gg[3], 256, 128, 25 * 256 * 128);
  wtrans16<<<(25 * 512 * 256 + 255) / 256, 256, 0, stream>>>(w[4], W4t, gg[4], 512, 256, 25 * 512 * 256);
  wtrans16<<<(25 * 512 * 512 + 255) / 256, 256, 0, stream>>>(w[5], W5t, gg[5], 512, 512, 25 * 512 * 512);
  wtrans16<<<(25 * 512 * 1024 + 255) / 256, 256, 0, stream>>>(w[6], W6t, gg[6], 512, 1024, 25 * 512 * 1024);
  wtrans16<<<(25 * 256 * 768 + 255) / 256, 256, 0, stream>>>(w[7], W7t, gg[7], 256, 768, 25 * 256 * 768);
  wtrans8<<<(28800 + 255) / 256, 256, 0, stream>>>(w[8], W8t, gg[8]);

  conv1_k<<<2048, 256, 0, stream>>>(data, w[1], gg[1], bb[1], ee[1], c1);
  pool_k<<<1048576 / 256, 256, 0, stream>>>(c1, p1, 64, 64, 512, 262144, 0,
                                            260, 67600, 522, 8, 8, 3, 1048576);
  // c1 dead -> zero cat7/cat6 halos (they alias c1's region)
  halo_k<<<(199680 + 255) / 256, 256, 0, stream>>>(cat7, 132, 96, 99840, 199680);
  halo_k<<<(135168 + 255) / 256, 256, 0, stream>>>(cat6, 68, 128, 67584, 135168);

  conv_gemm<4, 4, 1, 2><<<dim3(1024, 1), 256, 0, stream>>>(p1, W2t, gg[2], bb[2], ee[2], c2buf,
      64, 128, 8, 8, 64, 260, 67600, 522, 128, 0, 256, 65536, 0);
  pool_k<<<524288 / 256, 256, 0, stream>>>(c2buf, p2, 128, 128, 256, 65536, 0,
                                           132, 17424, 266, 7, 7, 4, 524288);
  // conv3: act(8.9M) > wt(1.6M) -> keep BM=128
  conv_gemm<4, 4, 2, 3><<<dim3(256, 2), 256, 0, stream>>>(p2, W3t, gg[3], bb[3], ee[3], cat7,
      128, 256, 7, 7, 128, 132, 17424, 266, 768, 0, 132, 17424, 266);
  pool_k<<<262144 / 256, 256, 0, stream>>>(cat7, p3, 768, 256, 132, 17424, 266,
                                           68, 4624, 138, 6, 6, 5, 262144);
  // conv4: act(4.7M) < wt(6.5M) -> BM-split, 512 blocks (2/CU)
  conv_gemm<2, 4, 2, 4><<<dim3(64, 8), 256, 0, stream>>>(p3, W4t, gg[4], bb[4], ee[4], cat6,
      256, 512, 6, 6, 256, 68, 4624, 138, 1024, 0, 68, 4624, 138);
  // p3 dead -> now safe to zero p4's halo (p4 aliases p3's bytes)
  halo_k<<<(34816 + 255) / 256, 256, 0, stream>>>(p4, 36, 64, 17408, 34816);
  pool_k<<<131072 / 256, 256, 0, stream>>>(cat6, p4, 1024, 512, 68, 4624, 138,
                                           36, 1296, 74, 5, 5, 6, 131072);
  conv_gemm<2, 2, 2, 5><<<dim3(32, 8), 256, 0, stream>>>(p4, W5t, gg[5], bb[5], ee[5], c5,
      512, 512, 5, 5, 512, 36, 1296, 74, 512, 0, 32, 1024, 0);
  up_k<<<524288 / 256, 256, 0, stream>>>(c5, cat6, 512, 1024, 512,
                                         32, 1024, 0, 68, 4624, 138,
                                         5, 5, 6, 31.f / 63.f, 524288);
  // conv6: act(18.9M) < wt(26M) -> BM-split, 512 blocks (2/CU)
  conv_gemm<2, 4, 2, 6><<<dim3(64, 8), 256, 0, stream>>>(cat6, W6t, gg[6], bb[6], ee[6], c6,
      1024, 512, 6, 6, 1024, 68, 4624, 138, 512, 0, 64, 4096, 0);
  up_k<<<2097152 / 256, 256, 0, stream>>>(c6, cat7, 512, 768, 256,
                                          64, 4096, 0, 132, 17424, 266,
                                          6, 6, 6, 63.f / 127.f, 2097152);
  // conv7: act(53.5M) > wt(9.8M) -> keep BM=128
  conv_gemm<4, 4, 2, 7><<<dim3(256, 2), 256, 0, stream>>>(cat7, W7t, gg[7], bb[7], ee[7], c7,
      768, 256, 7, 7, 768, 132, 17424, 266, 256, 0, 128, 16384, 0);
  up_k<<<4194304 / 256, 256, 0, stream>>>(c7, up7b, 256, 256, 0,
                                          128, 16384, 0, 256, 65536, 0,
                                          7, 7, 5, 127.f / 255.f, 4194304);
  conv8_lds<<<512, 256, 0, stream>>>(c2buf, up7b, W8t, bb[8], gg[8], ee[8], c8);
  final_k<<<524288 / 256, 256, 0, stream>>>(data, c8, wo, bo, out);
}

// Round 15
// 1778.390 us; speedup vs baseline: 1.3418x; 1.0109x over previous
//
#include <hip/hip_runtime.h>
#include <hip/hip_bf16.h>

typedef _Float16 f16x8 __attribute__((ext_vector_type(8)));
typedef _Float16 f16x4 __attribute__((ext_vector_type(4)));
typedef float f32x4 __attribute__((ext_vector_type(4)));

#define BN_S 0.99999500003749975f  // 1/sqrt(1+1e-5)

__device__ inline f16x8 f16x8_zero() {
  f16x8 v = {(_Float16)0.f, (_Float16)0.f, (_Float16)0.f, (_Float16)0.f,
             (_Float16)0.f, (_Float16)0.f, (_Float16)0.f, (_Float16)0.f};
  return v;
}

__device__ __forceinline__ void load_lds16(const _Float16* g, _Float16* l) {
  __builtin_amdgcn_global_load_lds(
      (const __attribute__((address_space(1))) void*)g,
      (__attribute__((address_space(3))) void*)l, 16, 0, 0);
}

__global__ void zero_out_k(float* __restrict__ out, int n) {
  const int idx = blockIdx.x * 256 + threadIdx.x;
  if (idx < n) out[idx] = 0.f;
}

// ---------------------------------------------------------------------------
// Zero only the 2-pixel halo ring of a padded square NHWC buffer.
// ---------------------------------------------------------------------------
__global__ void halo_k(_Float16* __restrict__ p, int Wp, int C8, int nb, int total) {
  const int idx = blockIdx.x * 256 + threadIdx.x;
  if (idx >= total) return;
  const int b = idx / nb;
  const int r = idx - b * nb;
  const int tb = 4 * Wp * C8;  // top+bottom strips
  int pix, cc;
  if (r < tb) {
    const int s = r / C8;
    cc = r - s * C8;
    pix = (s < 2 * Wp) ? s : (Wp * Wp - 4 * Wp + s);  // rows {0,1} | {Wp-2,Wp-1}
  } else {
    const int r2 = r - tb;
    const int s = r2 / C8;
    cc = r2 - s * C8;
    const int row = 2 + (s >> 2);
    const int k = s & 3;
    const int col = (k < 2) ? k : (Wp - 4 + k);       // cols {0,1,Wp-2,Wp-1}
    pix = row * Wp + col;
  }
  ((f16x8*)p)[(size_t)(b * Wp * Wp + pix) * C8 + cc] = f16x8_zero();
}

// ---------------------------------------------------------------------------
// Weight transform: OIHW fp32 -> [25][O][C] fp16, pre-scaled by g*BN_S.
// ---------------------------------------------------------------------------
__global__ void wtrans16(const float* __restrict__ src, _Float16* __restrict__ dst,
                         const float* __restrict__ g, int O, int C, int total) {
  const int idx = blockIdx.x * 256 + threadIdx.x;  // (t, o, c)
  if (idx >= total) return;
  const int OC = O * C;
  const int t = idx / OC;
  const int rem = idx - t * OC;
  const int o = rem / C;
  const int c = rem - o * C;
  dst[idx] = (_Float16)(src[(size_t)(o * C + c) * 25 + t] * g[o] * BN_S);
}

// conv8 weights: OIHW fp32 (O=3,C=384) -> [48 chunks][25 taps][3][8] fp16.
__global__ void wtrans8(const float* __restrict__ src, _Float16* __restrict__ dst,
                        const float* __restrict__ g) {
  const int idx = blockIdx.x * 256 + threadIdx.x;
  if (idx >= 28800) return;
  const int c = idx / 600;
  const int r = idx - c * 600;
  const int tap = r / 24;
  const int q = r - tap * 24;
  const int o = q >> 3, j = q & 7;
  const int cin = (c < 16) ? (c * 8 + j) : (128 + (c - 16) * 8 + j);
  dst[idx] = (_Float16)(src[((size_t)o * 384 + cin) * 25 + tap] * g[o] * BN_S);
}

// ---------------------------------------------------------------------------
// Implicit-GEMM 5x5 conv + BN + ReLU.  Cin%(32*KS)==0, Cout%BM==0, px%BN==0.
// Block tile BM(cout) x BN(px); 4 waves 2x2; KS k-steps staged per barrier
// into double-buffered LDS via global_load_lds(16B). XOR-swizzled LDS.
// Tile-split rule (r5/r9/r11): split along the dimension whose operand
// panel is SMALLER. No XCD swizzle (r12). SPLIT (r14): blockIdx.z picks
// tap range {[0,13),[13,25)}; fp16 partials to `part` (reduce_k finishes).
// Purpose: 2x blocks for grid-starved layers (residency -> m114 overlap).
// ---------------------------------------------------------------------------
template <int MF, int NF, int KS, int TAG, bool SPLIT>
__global__ __launch_bounds__(256) void conv_gemm(
    const _Float16* __restrict__ in, const _Float16* __restrict__ wt,
    const float* __restrict__ gg, const float* __restrict__ bbv,
    const float* __restrict__ ev, _Float16* __restrict__ out,
    int Cin, int Cout, int lw, int lh,
    int inS, int Wpi, int bsi, int ibase,
    int outS, int outOff, int Wpo, int bso, int obase,
    _Float16* __restrict__ part, int partN) {
  constexpr int BM = MF * 32;
  constexpr int BN = NF * 32;
  constexpr int SUB_A = BM * 32;  // halfwords per k-substep
  constexpr int SUB_B = BN * 32;
  __shared__ _Float16 sA[2][SUB_A * KS];
  __shared__ _Float16 sB[2][SUB_B * KS];

  const int tid = threadIdx.x;
  const int lane = tid & 63;
  const int wid = tid >> 6;
  const int wm = wid >> 1, wn = wid & 1;
  const int lr = lane >> 4, lc = lane & 15;
  const int n0 = blockIdx.x * BN;
  const int m0 = blockIdx.y * BM;
  const int H = 1 << lh, W = 1 << lw;
  const int nkb = Cin >> 5;

  int tap0 = 0, ntp = 25;
  if constexpr (SPLIT) {
    tap0 = blockIdx.z ? 13 : 0;
    ntp = blockIdx.z ? 12 : 13;
  }
  const int dy0 = tap0 / 5, dx0 = tap0 - dy0 * 5;

  // staging identity: linear g = issue*256 + tid; row=g>>2, slot=g&3
  const int r0 = tid >> 2;
  const int chunk = (tid & 3) ^ ((r0 >> 1) & 3);  // same for row r0+64

  const _Float16* a0 = wt + ((size_t)tap0 * Cout + m0 + r0) * Cin + (chunk << 3);
  const _Float16* a1 = a0 + ((size_t)Cin << 6);  // used only if BM==128
  const int t0off = (dy0 - 2) * Wpi + (dx0 - 2);
  const _Float16 *b0, *b1 = nullptr;
  {
    int n = n0 + r0;
    int pix0 = (n >> (lw + lh)) * bsi + ((n >> lw) & (H - 1)) * Wpi + (n & (W - 1)) + ibase;
    b0 = in + (size_t)(pix0 + t0off) * inS + (chunk << 3);
    if constexpr (BN == 128) {
      n = n0 + r0 + 64;
      int pix1 = (n >> (lw + lh)) * bsi + ((n >> lw) & (H - 1)) * Wpi + (n & (W - 1)) + ibase;
      b1 = in + (size_t)(pix1 + t0off) * inS + (chunk << 3);
    }
  }

  // ds_read fragment swizzle (halfwords)
  const int swz = (lr ^ ((lc >> 1) & 3)) << 3;

  f32x4 acc[MF][NF];
  const f32x4 vz = {0.f, 0.f, 0.f, 0.f};
#pragma unroll
  for (int i = 0; i < MF; ++i)
#pragma unroll
    for (int j = 0; j < NF; ++j) acc[i][j] = vz;

  const int np = ntp * nkb / KS;  // staged groups
  int kb = 0, dx = dx0;
  const size_t a_tap = (size_t)Cout * Cin - ((size_t)nkb << 5);
  const int woff = wid << 9;  // wave LDS base within a 4KB issue (halfwords)

  // advance staging pointers by one group (KS k-steps)
  auto advance = [&]() {
    a0 += 32 * KS; b0 += 32 * KS;
    if constexpr (BM == 128) a1 += 32 * KS;
    if constexpr (BN == 128) b1 += 32 * KS;
    kb += KS;
    if (kb == nkb) {
      kb = 0;
      a0 += a_tap;
      if constexpr (BM == 128) a1 += a_tap;
      int pd;
      if (++dx == 5) { dx = 0; pd = Wpi - 4; } else pd = 1;
      const ptrdiff_t bd = (ptrdiff_t)pd * inS - ((ptrdiff_t)nkb << 5);
      b0 += bd;
      if constexpr (BN == 128) b1 += bd;
    }
  };
  auto stage = [&](int buf) {
#pragma unroll
    for (int s = 0; s < KS; ++s) {
      _Float16* sa = sA[buf] + s * SUB_A + woff;
      _Float16* sb = sB[buf] + s * SUB_B + woff;
      load_lds16(a0 + 32 * s, sa);
      if constexpr (BM == 128) load_lds16(a1 + 32 * s, sa + 2048);
      load_lds16(b0 + 32 * s, sb);
      if constexpr (BN == 128) load_lds16(b1 + 32 * s, sb + 2048);
    }
  };

  // prologue: stage group 0 into buf 0
  stage(0);
  __syncthreads();

  int cur = 0;
  for (int t = 0; t < np; ++t) {
    if (t + 1 < np) {
      advance();
      stage(cur ^ 1);
    }
    const _Float16* pA = sA[cur];
    const _Float16* pB = sB[cur];
#pragma unroll
    for (int s = 0; s < KS; ++s) {
      f16x8 af[MF], bf[NF];
#pragma unroll
      for (int i = 0; i < MF; ++i)
        af[i] = *(const f16x8*)(pA + s * SUB_A + ((wm * (MF * 16) + (i << 4) + lc) << 5) + swz);
#pragma unroll
      for (int i = 0; i < NF; ++i)
        bf[i] = *(const f16x8*)(pB + s * SUB_B + ((wn * (NF * 16) + (i << 4) + lc) << 5) + swz);
#pragma unroll
      for (int mi = 0; mi < MF; ++mi)
#pragma unroll
        for (int ni = 0; ni < NF; ++ni)
          acc[mi][ni] =
              __builtin_amdgcn_mfma_f32_16x16x32_f16(af[mi], bf[ni], acc[mi][ni], 0, 0, 0);
    }
    __syncthreads();  // drains stage(cur^1) loads + fences buf reuse
    cur ^= 1;
  }

  // Epilogue
  if constexpr (SPLIT) {
    _Float16* pp = part + (size_t)blockIdx.z * partN;
#pragma unroll
    for (int mi = 0; mi < MF; ++mi) {
      const int ob = m0 + wm * (MF * 16) + (mi << 4) + (lr << 2);
#pragma unroll
      for (int ni = 0; ni < NF; ++ni) {
        const int n = n0 + wn * (NF * 16) + (ni << 4) + lc;
        f16x4 h;
#pragma unroll
        for (int j = 0; j < 4; ++j) h[j] = (_Float16)acc[mi][ni][j];
        *(f16x4*)(pp + (size_t)n * Cout + ob) = h;
      }
    }
  } else {
#pragma unroll
    for (int mi = 0; mi < MF; ++mi) {
      const int ob = m0 + wm * (MF * 16) + (mi << 4) + (lr << 2);
      const f32x4 gv = *(const f32x4*)(gg + ob);
      const f32x4 bv = *(const f32x4*)(bbv + ob);
      const f32x4 evv = *(const f32x4*)(ev + ob);
#pragma unroll
      for (int ni = 0; ni < NF; ++ni) {
        const int n = n0 + wn * (NF * 16) + (ni << 4) + lc;
        const int y = (n >> lw) & (H - 1);
        const int x = n & (W - 1);
        const int bb_ = n >> (lw + lh);
        const size_t op = (size_t)(bb_ * bso + y * Wpo + x + obase) * outS + outOff + ob;
        f16x4 h;
#pragma unroll
        for (int j = 0; j < 4; ++j) {
          const float s = gv[j] * BN_S;
          float v = acc[mi][ni][j] + (bv[j] * s + evv[j]);
          v = v > 0.f ? v : 0.f;
          h[j] = (_Float16)v;
        }
        *(f16x4*)(out + op) = h;
      }
    }
  }
}

// ---------------------------------------------------------------------------
// reduce split partials: sum 2 fp16 partials + BN + ReLU -> NHWC fp16 out
// (same out-addressing as conv_gemm epilogue; Cout=512 hardcoded).
// ---------------------------------------------------------------------------
__global__ void reduce_k(const _Float16* __restrict__ part, _Float16* __restrict__ out,
                         const float* __restrict__ g, const float* __restrict__ b,
                         const float* __restrict__ e, int partN,
                         int lw, int lh, int outS, int outOff,
                         int Wpo, int bso, int obase, int total) {
  const int idx = blockIdx.x * 256 + threadIdx.x;
  if (idx >= total) return;
  const int i4 = idx << 2;
  const int n = i4 >> 9;        // Cout = 512
  const int ob = i4 & 511;
  const f16x4 p0 = *(const f16x4*)(part + i4);
  const f16x4 p1 = *(const f16x4*)(part + partN + i4);
  const f32x4 gv = *(const f32x4*)(g + ob);
  const f32x4 bv = *(const f32x4*)(b + ob);
  const f32x4 ev = *(const f32x4*)(e + ob);
  const int H = 1 << lh, W = 1 << lw;
  const int y = (n >> lw) & (H - 1);
  const int x = n & (W - 1);
  const int bb_ = n >> (lw + lh);
  const size_t op = (size_t)(bb_ * bso + y * Wpo + x + obase) * outS + outOff + ob;
  f16x4 h;
#pragma unroll
  for (int j = 0; j < 4; ++j) {
    const float s = gv[j] * BN_S;
    float v = (float)p0[j] + (float)p1[j] + (bv[j] * s + ev[j]);
    v = v > 0.f ? v : 0.f;
    h[j] = (_Float16)v;
  }
  *(f16x4*)(out + op) = h;
}

// ---------------------------------------------------------------------------
// conv1: Cin=3, Cout=64, 512x512, fp32 NCHW data + raw fp32 weights.
// ---------------------------------------------------------------------------
__global__ __launch_bounds__(256) void conv1_k(
    const float* __restrict__ data, const float* __restrict__ w1,
    const float* __restrict__ g1, const float* __restrict__ b1,
    const float* __restrict__ e1, _Float16* __restrict__ out) {
  __shared__ float patch[3][20][20];
  const int tid = threadIdx.x;
  const int bid = blockIdx.x;
  const int tx = bid & 31, ty = (bid >> 5) & 31, b = bid >> 10;

  for (int i = tid; i < 1200; i += 256) {
    const int c = i / 400;
    const int r = i - c * 400;
    const int pyy = r / 20;
    const int pxx = r - pyy * 20;
    const int gy = (ty << 4) + pyy - 2, gx = (tx << 4) + pxx - 2;
    float v = 0.f;
    if ((unsigned)gy < 512u && (unsigned)gx < 512u)
      v = data[((size_t)(b * 3 + c) << 18) + (gy << 9) + gx];
    patch[c][pyy][pxx] = v;
  }
  __syncthreads();

  const int py = tid >> 4, px = tid & 15;
  float acc[64];
#pragma unroll
  for (int o = 0; o < 64; ++o) acc[o] = 0.f;

  for (int c = 0; c < 3; ++c)
    for (int dy = 0; dy < 5; ++dy) {
#pragma unroll
      for (int dx = 0; dx < 5; ++dx) {
        const float v = patch[c][py + dy][px + dx];
        const float* wb = w1 + c * 25 + dy * 5 + dx;
#pragma unroll
        for (int o = 0; o < 64; ++o) acc[o] = fmaf(v, wb[o * 75], acc[o]);
      }
    }

  const int y = (ty << 4) + py, x = (tx << 4) + px;
  _Float16* op = out + ((size_t)(((b << 9) + y) << 9) + x) * 64;
#pragma unroll
  for (int oc = 0; oc < 8; ++oc) {
    f16x8 h;
#pragma unroll
    for (int j = 0; j < 8; ++j) {
      const int o = (oc << 3) + j;
      const float s = g1[o] * BN_S;
      const float t = b1[o] * s + e1[o];
      float v = fmaf(acc[o], s, t);
      v = v > 0.f ? v : 0.f;
      h[j] = (_Float16)v;
    }
    *(f16x8*)(op + (oc << 3)) = h;
  }
}

// ---------------------------------------------------------------------------
// avg-pool 2x2 stride 2, NHWC fp16, generic padded/unpadded addressing
// ---------------------------------------------------------------------------
__global__ void pool_k(const _Float16* __restrict__ in, _Float16* __restrict__ out,
                       int inS, int outS, int Wpi, int bsi, int ibase,
                       int Wpo, int bso, int obase,
                       int lwo, int lho, int lcc, int total) {
  const int idx = blockIdx.x * 256 + threadIdx.x;
  if (idx >= total) return;
  const int cc = idx & ((1 << lcc) - 1);
  const int pix = idx >> lcc;
  const int x = pix & ((1 << lwo) - 1);
  const int y = (pix >> lwo) & ((1 << lho) - 1);
  const int b = pix >> (lwo + lho);
  const int ip = b * bsi + (y << 1) * Wpi + (x << 1) + ibase;
  const _Float16* p = in + (size_t)ip * inS + (cc << 3);
  const f16x8 v00 = *(const f16x8*)p;
  const f16x8 v01 = *(const f16x8*)(p + inS);
  const f16x8 v10 = *(const f16x8*)(p + (size_t)Wpi * inS);
  const f16x8 v11 = *(const f16x8*)(p + (size_t)(Wpi + 1) * inS);
  f16x8 r;
#pragma unroll
  for (int j = 0; j < 8; ++j)
    r[j] = (_Float16)(((float)v00[j] + (float)v01[j] + (float)v10[j] + (float)v11[j]) * 0.25f);
  const int op = b * bso + y * Wpo + x + obase;
  *(f16x8*)(out + (size_t)op * outS + (cc << 3)) = r;
}

// ---------------------------------------------------------------------------
// bilinear 2x upsample (align_corners=True), NHWC fp16
// ---------------------------------------------------------------------------
__global__ void up_k(const _Float16* __restrict__ in, _Float16* __restrict__ out,
                     int inS, int outS, int outOff,
                     int Wpi, int bsi, int ibase,
                     int Wpo, int bso, int obase,
                     int lwi, int lhi, int lcc, float scale, int total) {
  const int idx = blockIdx.x * 256 + threadIdx.x;
  if (idx >= total) return;
  const int cc = idx & ((1 << lcc) - 1);
  const int pix = idx >> lcc;
  const int lwo = lwi + 1, lho = lhi + 1;
  const int ox = pix & ((1 << lwo) - 1);
  const int oy = (pix >> lwo) & ((1 << lho) - 1);
  const int b = pix >> (lwo + lho);
  const int Hi = 1 << lhi, Wi = 1 << lwi;
  const float fy = oy * scale;
  const int y0 = (int)fy;
  const float wy = fy - y0;
  const int y1 = min(y0 + 1, Hi - 1);
  const float fx = ox * scale;
  const int x0 = (int)fx;
  const float wx = fx - x0;
  const int x1 = min(x0 + 1, Wi - 1);
  const int rbase = b * bsi + ibase;
  const _Float16* basep = in + (cc << 3);
  const f16x8 v00 = *(const f16x8*)(basep + (size_t)(rbase + y0 * Wpi + x0) * inS);
  const f16x8 v01 = *(const f16x8*)(basep + (size_t)(rbase + y0 * Wpi + x1) * inS);
  const f16x8 v10 = *(const f16x8*)(basep + (size_t)(rbase + y1 * Wpi + x0) * inS);
  const f16x8 v11 = *(const f16x8*)(basep + (size_t)(rbase + y1 * Wpi + x1) * inS);
  f16x8 r;
#pragma unroll
  for (int j = 0; j < 8; ++j) {
    const float top = (float)v00[j] * (1.f - wx) + (float)v01[j] * wx;
    const float bot = (float)v10[j] * (1.f - wx) + (float)v11[j] * wx;
    r[j] = (_Float16)(top * (1.f - wy) + bot * wy);
  }
  const int op = b * bso + oy * Wpo + ox + obase;
  *(f16x8*)(out + (size_t)op * outS + outOff + (cc << 3)) = r;
}

// ---------------------------------------------------------------------------
// conv8 (LDS-tiled): Cin=384 (= c2[128ch] ++ up7[256ch]), Cout=3, 256x256.
// ---------------------------------------------------------------------------
__global__ __launch_bounds__(256) void conv8_lds(
    const _Float16* __restrict__ inA, const _Float16* __restrict__ inB,
    const _Float16* __restrict__ wt, const float* __restrict__ b8,
    const float* __restrict__ g8, const float* __restrict__ e8,
    _Float16* __restrict__ out) {
  __shared__ f16x8 patch[2][20][20];
  const int tid = threadIdx.x;
  const int bid = blockIdx.x;  // 512
  const int tx = bid & 15, ty = (bid >> 4) & 15, b = bid >> 8;
  const int px = tid & 15, py = tid >> 4;
  const int x0 = tx << 4, y0 = ty << 4;

  float a0 = 0.f, a1 = 0.f, a2 = 0.f;
  for (int c = 0; c < 48; ++c) {
    const _Float16* sbase;
    int str;
    if (c < 16) { sbase = inA + ((size_t)b << 23) + (c << 3); str = 128; }
    else        { sbase = inB + ((size_t)b << 24) + ((c - 16) << 3); str = 256; }
    for (int i = tid; i < 400; i += 256) {
      const int pyy = i / 20, pxx = i - pyy * 20;
      const int gy = y0 + pyy - 2, gx = x0 + pxx - 2;
      f16x8 v = f16x8_zero();
      if ((unsigned)gy < 256u && (unsigned)gx < 256u)
        v = *(const f16x8*)(sbase + (size_t)((gy << 8) + gx) * str);
      patch[c & 1][pyy][pxx] = v;
    }
    __syncthreads();
    const _Float16* wb_c = wt + c * 600;
#pragma unroll
    for (int dy = 0; dy < 5; ++dy) {
#pragma unroll
      for (int dxx = 0; dxx < 5; ++dxx) {
        const f16x8 v = patch[c & 1][py + dy][px + dxx];
        const _Float16* wb = wb_c + (dy * 5 + dxx) * 24;
#pragma unroll
        for (int j = 0; j < 8; ++j) {
          const float f = (float)v[j];
          a0 = fmaf(f, (float)wb[j], a0);
          a1 = fmaf(f, (float)wb[8 + j], a1);
          a2 = fmaf(f, (float)wb[16 + j], a2);
        }
      }
    }
  }

  const float s0 = g8[0] * BN_S, t0 = b8[0] * s0 + e8[0];
  const float s1 = g8[1] * BN_S, t1 = b8[1] * s1 + e8[1];
  const float s2 = g8[2] * BN_S, t2 = b8[2] * s2 + e8[2];
  float r0 = a0 + t0, r1 = a1 + t1, r2 = a2 + t2;
  r0 = r0 > 0.f ? r0 : 0.f;
  r1 = r1 > 0.f ? r1 : 0.f;
  r2 = r2 > 0.f ? r2 : 0.f;
  f16x4 h;
  h[0] = (_Float16)r0; h[1] = (_Float16)r1; h[2] = (_Float16)r2; h[3] = (_Float16)0.f;
  const int opix = (b << 16) + ((y0 + py) << 8) + (x0 + px);
  *(f16x4*)(out + (size_t)opix * 4) = h;
}

// ---------------------------------------------------------------------------
// final: bilinear up(c8, 256->512) + 1x1 conv (wo,bo) + out = data*core (fp32)
// ---------------------------------------------------------------------------
__global__ void final_k(const float* __restrict__ data, const _Float16* __restrict__ c8,
                        const float* __restrict__ wo, const float* __restrict__ bo,
                        float* __restrict__ out) {
  const int idx = blockIdx.x * 256 + threadIdx.x;  // < 524288
  const int x = idx & 511, y = (idx >> 9) & 511, b = idx >> 18;
  const float sc = 255.f / 511.f;
  const float fy = y * sc;
  const int y0 = (int)fy;
  const float wy = fy - y0;
  const int y1 = min(y0 + 1, 255);
  const float fx = x * sc;
  const int x0 = (int)fx;
  const float wx = fx - x0;
  const int x1 = min(x0 + 1, 255);
  const f16x4 v00 = *(const f16x4*)(c8 + (size_t)((((b << 8) + y0) << 8) + x0) * 4);
  const f16x4 v01 = *(const f16x4*)(c8 + (size_t)((((b << 8) + y0) << 8) + x1) * 4);
  const f16x4 v10 = *(const f16x4*)(c8 + (size_t)((((b << 8) + y1) << 8) + x0) * 4);
  const f16x4 v11 = *(const f16x4*)(c8 + (size_t)((((b << 8) + y1) << 8) + x1) * 4);
  float u[3];
#pragma unroll
  for (int j = 0; j < 3; ++j) {
    const float top = (float)v00[j] * (1.f - wx) + (float)v01[j] * wx;
    const float bot = (float)v10[j] * (1.f - wx) + (float)v11[j] * wx;
    u[j] = top * (1.f - wy) + bot * wy;
  }
#pragma unroll
  for (int c = 0; c < 3; ++c) {
    const float core = bo[c] + wo[c * 3 + 0] * u[0] + wo[c * 3 + 1] * u[1] + wo[c * 3 + 2] * u[2];
    const size_t oi = ((size_t)(b * 3 + c) << 18) + (y << 9) + x;
    out[oi] = data[oi] * core;
  }
}

// ---------------------------------------------------------------------------
extern "C" void kernel_launch(void* const* d_in, const int* in_sizes, int n_in,
                              void* d_out, int out_size, void* d_ws, size_t ws_size,
                              hipStream_t stream) {
  const float* data = (const float*)d_in[0];
  const float *w[9], *bb[9], *gg[9], *ee[9];
  for (int n = 1; n <= 8; ++n) {
    w[n] = (const float*)d_in[1 + (n - 1) * 4];
    bb[n] = (const float*)d_in[2 + (n - 1) * 4];
    gg[n] = (const float*)d_in[3 + (n - 1) * 4];
    ee[n] = (const float*)d_in[4 + (n - 1) * 4];
  }
  const float* wo = (const float*)d_in[33];
  const float* bo = (const float*)d_in[34];
  float* out = (float*)d_out;
  (void)in_sizes; (void)n_in;

  // ---- workspace layout (aliased; padded activations; 194,810,112 B) ----
  // LIVENESS (r9): cat7's c3-half is live conv3->conv7; don't reuse between.
  // SPLIT partials (r14): part4 -> R1 (free at conv4 time); part5/part6 ->
  // retired W2t..W5t region (dead after conv5; W6t/W7t/W8t untouched).
  const size_t NEEDED = 194810112ull;
  if (ws_size < NEEDED) {
    zero_out_k<<<(out_size + 255) / 256, 256, 0, stream>>>(out, out_size);
    return;
  }
  char* base = (char*)d_ws;
  size_t off = 0;
  auto alloc = [&](size_t bytes) -> char* {
    char* p = base + off;
    off += (bytes + 255) & ~(size_t)255;
    return p;
  };
  _Float16* W2t = (_Float16*)alloc(409600);     // 25*128*64*2
  _Float16* W3t = (_Float16*)alloc(1638400);    // 25*256*128*2
  _Float16* W4t = (_Float16*)alloc(6553600);    // 25*512*256*2
  _Float16* W5t = (_Float16*)alloc(13107200);   // 25*512*512*2
  _Float16* W6t = (_Float16*)alloc(26214400);   // 25*512*1024*2
  _Float16* W7t = (_Float16*)alloc(9830400);    // 25*256*768*2
  _Float16* W8t = (_Float16*)alloc(57600);      // 48*25*24 fp16
  char* Rbig = alloc(72466432);   // c1(67.1M) | cat7(53.5M)+cat6(18.9M) | up7(67.1M)
  char* c2b_ = alloc(33554432);   // c2 (2,256,256,128) unpadded
  char* R1 = alloc(17305600);     // p1(17.3M) | part4(16.8M) | c6(8.4M) | c7(16.8M) | c8(1M)
  char* R2 = alloc(13672448);     // p2(8.9M) ; [p3(4.7M) | p4(2.65M)+c5(2.1M)]

  _Float16* c1 = (_Float16*)Rbig;                    // (2,512,512,64) unpadded
  _Float16* cat7 = (_Float16*)Rbig;                  // (2,132,132,768) padded
  _Float16* cat6 = (_Float16*)(Rbig + 53526528);     // (2,68,68,1024) padded
  _Float16* up7b = (_Float16*)Rbig;                  // (2,256,256,256) unpadded
  _Float16* c2buf = (_Float16*)c2b_;                 // (2,256,256,128) unpadded
  _Float16* p1 = (_Float16*)R1;                      // (2,260,260,64) padded
  _Float16* part4 = (_Float16*)R1;                   // [2][8192][512] fp16 (16.8M)
  _Float16* c6 = (_Float16*)R1;                      // (2,64,64,512) unpadded
  _Float16* c7 = (_Float16*)R1;                      // (2,128,128,256) unpadded
  _Float16* c8 = (_Float16*)R1;                      // (2,256,256,4) unpadded
  _Float16* part56 = (_Float16*)base;                // part5 [2][2048][512] (4.2M<=8.6M W2t..W4t);
                                                     // part6 [2][8192][512] (16.8M<=21.7M W2t..W5t)
  _Float16* p2 = (_Float16*)R2;                      // (2,132,132,128) padded
  _Float16* p3 = (_Float16*)(R2 + 8921088);          // (2,68,68,256) padded
  _Float16* p4 = (_Float16*)(R2 + 8921088);          // (2,36,36,512) padded (aliases p3!)
  _Float16* c5 = (_Float16*)(R2 + 8921088 + 2654208);// (2,32,32,512) unpadded

  // halo-only zeroing (interiors fully overwritten by producers; r13 audit).
  halo_k<<<(33024 + 255) / 256, 256, 0, stream>>>(p1, 260, 8, 16512, 33024);
  halo_k<<<(33280 + 255) / 256, 256, 0, stream>>>(p2, 132, 16, 16640, 33280);
  halo_k<<<(33792 + 255) / 256, 256, 0, stream>>>(p3, 68, 32, 16896, 33792);

  // weight transforms (fold BN scale into weights)
  wtrans16<<<(25 * 128 * 64 + 255) / 256, 256, 0, stream>>>(w[2], W2t, gg[2], 128, 64, 25 * 128 * 64);
  wtrans16<<<(25 * 256 * 128 + 255) / 256, 256, 0, stream>>>(w[3], W3t, gg[3], 256, 128, 25 * 256 * 128);
  wtrans16<<<(25 * 512 * 256 + 255) / 256, 256, 0, stream>>>(w[4], W4t, gg[4], 512, 256, 25 * 512 * 256);
  wtrans16<<<(25 * 512 * 512 + 255) / 256, 256, 0, stream>>>(w[5], W5t, gg[5], 512, 512, 25 * 512 * 512);
  wtrans16<<<(25 * 512 * 1024 + 255) / 256, 256, 0, stream>>>(w[6], W6t, gg[6], 512, 1024, 25 * 512 * 1024);
  wtrans16<<<(25 * 256 * 768 + 255) / 256, 256, 0, stream>>>(w[7], W7t, gg[7], 256, 768, 25 * 256 * 768);
  wtrans8<<<(28800 + 255) / 256, 256, 0, stream>>>(w[8], W8t, gg[8]);

  conv1_k<<<2048, 256, 0, stream>>>(data, w[1], gg[1], bb[1], ee[1], c1);
  pool_k<<<1048576 / 256, 256, 0, stream>>>(c1, p1, 64, 64, 512, 262144, 0,
                                            260, 67600, 522, 8, 8, 3, 1048576);
  // c1 dead -> zero cat7/cat6 halos (they alias c1's region)
  halo_k<<<(199680 + 255) / 256, 256, 0, stream>>>(cat7, 132, 96, 99840, 199680);
  halo_k<<<(135168 + 255) / 256, 256, 0, stream>>>(cat6, 68, 128, 67584, 135168);

  conv_gemm<4, 4, 1, 2, false><<<dim3(1024, 1), 256, 0, stream>>>(p1, W2t, gg[2], bb[2], ee[2], c2buf,
      64, 128, 8, 8, 64, 260, 67600, 522, 128, 0, 256, 65536, 0, nullptr, 0);
  pool_k<<<524288 / 256, 256, 0, stream>>>(c2buf, p2, 128, 128, 256, 65536, 0,
                                           132, 17424, 266, 7, 7, 4, 524288);
  // conv3: act(8.9M) > wt(1.6M) -> keep BM=128
  conv_gemm<4, 4, 2, 3, false><<<dim3(256, 2), 256, 0, stream>>>(p2, W3t, gg[3], bb[3], ee[3], cat7,
      128, 256, 7, 7, 128, 132, 17424, 266, 768, 0, 132, 17424, 266, nullptr, 0);
  pool_k<<<262144 / 256, 256, 0, stream>>>(cat7, p3, 768, 256, 132, 17424, 266,
                                           68, 4624, 138, 6, 6, 5, 262144);
  // conv4: split-K 2-way (1024 blocks, 3/CU) -> fp16 partials in R1
  conv_gemm<2, 4, 2, 4, true><<<dim3(64, 8, 2), 256, 0, stream>>>(p3, W4t, gg[4], bb[4], ee[4], cat6,
      256, 512, 6, 6, 256, 68, 4624, 138, 1024, 0, 68, 4624, 138, part4, 4194304);
  reduce_k<<<1048576 / 256, 256, 0, stream>>>(part4, cat6, gg[4], bb[4], ee[4], 4194304,
                                              6, 6, 1024, 0, 68, 4624, 138, 1048576);
  // p3 dead -> now safe to zero p4's halo (p4 aliases p3's bytes)
  halo_k<<<(34816 + 255) / 256, 256, 0, stream>>>(p4, 36, 64, 17408, 34816);
  pool_k<<<131072 / 256, 256, 0, stream>>>(cat6, p4, 1024, 512, 68, 4624, 138,
                                           36, 1296, 74, 5, 5, 6, 131072);
  // conv5: split-K 2-way (512 blocks) -> fp16 partials over dead W2t..W4t
  conv_gemm<2, 2, 2, 5, true><<<dim3(32, 8, 2), 256, 0, stream>>>(p4, W5t, gg[5], bb[5], ee[5], c5,
      512, 512, 5, 5, 512, 36, 1296, 74, 512, 0, 32, 1024, 0, part56, 1048576);
  reduce_k<<<262144 / 256, 256, 0, stream>>>(part56, c5, gg[5], bb[5], ee[5], 1048576,
                                             5, 5, 512, 0, 32, 1024, 0, 262144);
  up_k<<<524288 / 256, 256, 0, stream>>>(c5, cat6, 512, 1024, 512,
                                         32, 1024, 0, 68, 4624, 138,
                                         5, 5, 6, 31.f / 63.f, 524288);
  // conv6: split-K 2-way (1024 blocks, 3/CU) -> fp16 partials over dead W2t..W5t
  conv_gemm<2, 4, 2, 6, true><<<dim3(64, 8, 2), 256, 0, stream>>>(cat6, W6t, gg[6], bb[6], ee[6], c6,
      1024, 512, 6, 6, 1024, 68, 4624, 138, 512, 0, 64, 4096, 0, part56, 4194304);
  reduce_k<<<1048576 / 256, 256, 0, stream>>>(part56, c6, gg[6], bb[6], ee[6], 4194304,
                                              6, 6, 512, 0, 64, 4096, 0, 1048576);
  up_k<<<2097152 / 256, 256, 0, stream>>>(c6, cat7, 512, 768, 256,
                                          64, 4096, 0, 132, 17424, 266,
                                          6, 6, 6, 63.f / 127.f, 2097152);
  // conv7: act(53.5M) > wt(9.8M) -> keep BM=128, no split (r11)
  conv_gemm<4, 4, 2, 7, false><<<dim3(256, 2), 256, 0, stream>>>(cat7, W7t, gg[7], bb[7], ee[7], c7,
      768, 256, 7, 7, 768, 132, 17424, 266, 256, 0, 128, 16384, 0, nullptr, 0);
  up_k<<<4194304 / 256, 256, 0, stream>>>(c7, up7b, 256, 256, 0,
                                          128, 16384, 0, 256, 65536, 0,
                                          7, 7, 5, 127.f / 255.f, 4194304);
  conv8_lds<<<512, 256, 0, stream>>>(c2buf, up7b, W8t, bb[8], gg[8], ee[8], c8);
  final_k<<<524288 / 256, 256, 0, stream>>>(data, c8, wo, bo, out);
}

// Round 16
// 1570.267 us; speedup vs baseline: 1.5197x; 1.1325x over previous
//
#include <hip/hip_runtime.h>
#include <hip/hip_bf16.h>

typedef _Float16 f16x8 __attribute__((ext_vector_type(8)));
typedef _Float16 f16x4 __attribute__((ext_vector_type(4)));
typedef float f32x4 __attribute__((ext_vector_type(4)));

#define BN_S 0.99999500003749975f  // 1/sqrt(1+1e-5)

__device__ inline f16x8 f16x8_zero() {
  f16x8 v = {(_Float16)0.f, (_Float16)0.f, (_Float16)0.f, (_Float16)0.f,
             (_Float16)0.f, (_Float16)0.f, (_Float16)0.f, (_Float16)0.f};
  return v;
}

__device__ __forceinline__ void load_lds16(const _Float16* g, _Float16* l) {
  __builtin_amdgcn_global_load_lds(
      (const __attribute__((address_space(1))) void*)g,
      (__attribute__((address_space(3))) void*)l, 16, 0, 0);
}

__global__ void zero_out_k(float* __restrict__ out, int n) {
  const int idx = blockIdx.x * 256 + threadIdx.x;
  if (idx < n) out[idx] = 0.f;
}

// ---------------------------------------------------------------------------
// Zero only the 2-pixel halo ring of a padded square NHWC buffer.
// ---------------------------------------------------------------------------
__global__ void halo_k(_Float16* __restrict__ p, int Wp, int C8, int nb, int total) {
  const int idx = blockIdx.x * 256 + threadIdx.x;
  if (idx >= total) return;
  const int b = idx / nb;
  const int r = idx - b * nb;
  const int tb = 4 * Wp * C8;  // top+bottom strips
  int pix, cc;
  if (r < tb) {
    const int s = r / C8;
    cc = r - s * C8;
    pix = (s < 2 * Wp) ? s : (Wp * Wp - 4 * Wp + s);  // rows {0,1} | {Wp-2,Wp-1}
  } else {
    const int r2 = r - tb;
    const int s = r2 / C8;
    cc = r2 - s * C8;
    const int row = 2 + (s >> 2);
    const int k = s & 3;
    const int col = (k < 2) ? k : (Wp - 4 + k);       // cols {0,1,Wp-2,Wp-1}
    pix = row * Wp + col;
  }
  ((f16x8*)p)[(size_t)(b * Wp * Wp + pix) * C8 + cc] = f16x8_zero();
}

// ---------------------------------------------------------------------------
// Weight transform: OIHW fp32 -> [25][O][C] fp16, pre-scaled by g*BN_S.
// (o,c)-indexed, t-inner (r16): each thread reads 25 CONSECUTIVE floats
// (wave working set 6.4KB -> L1-resident across loop); writes coalesced
// per-t. The r2 output-indexed form re-streamed the whole array 25x from
// L2/L3 (stride-100B reads, reuse distance = full pass).
// ---------------------------------------------------------------------------
__global__ void wtrans16(const float* __restrict__ src, _Float16* __restrict__ dst,
                         const float* __restrict__ g, int O, int C, int total) {
  const int idx = blockIdx.x * 256 + threadIdx.x;  // (o, c); total = O*C
  if (idx >= total) return;
  const int o = idx / C;
  const int c = idx - o * C;
  const float s = g[o] * BN_S;
  const float* sp = src + (size_t)idx * 25;
#pragma unroll
  for (int t = 0; t < 25; ++t)
    dst[((size_t)t * O + o) * C + c] = (_Float16)(sp[t] * s);
}

// conv8 weights: OIHW fp32 (O=3,C=384) -> [48 chunks][25 taps][3][8] fp16.
__global__ void wtrans8(const float* __restrict__ src, _Float16* __restrict__ dst,
                        const float* __restrict__ g) {
  const int idx = blockIdx.x * 256 + threadIdx.x;
  if (idx >= 28800) return;
  const int c = idx / 600;
  const int r = idx - c * 600;
  const int tap = r / 24;
  const int q = r - tap * 24;
  const int o = q >> 3, j = q & 7;
  const int cin = (c < 16) ? (c * 8 + j) : (128 + (c - 16) * 8 + j);
  dst[idx] = (_Float16)(src[((size_t)o * 384 + cin) * 25 + tap] * g[o] * BN_S);
}

// ---------------------------------------------------------------------------
// Implicit-GEMM 5x5 conv + BN + ReLU.  Cin%(32*KS)==0, Cout%BM==0, px%BN==0.
// Block tile BM(cout) x BN(px); 4 waves 2x2; KS k-steps staged per barrier
// into double-buffered LDS via global_load_lds(16B). XOR-swizzled LDS.
// Tile-split rule (r5/r9/r11): split along the dimension whose operand
// panel is SMALLER. No XCD swizzle (r12). SPLIT (r14): blockIdx.z picks
// tap range {[0,13),[13,25)}; fp16 partials to `part` (reduce_k finishes).
// ---------------------------------------------------------------------------
template <int MF, int NF, int KS, int TAG, bool SPLIT>
__global__ __launch_bounds__(256) void conv_gemm(
    const _Float16* __restrict__ in, const _Float16* __restrict__ wt,
    const float* __restrict__ gg, const float* __restrict__ bbv,
    const float* __restrict__ ev, _Float16* __restrict__ out,
    int Cin, int Cout, int lw, int lh,
    int inS, int Wpi, int bsi, int ibase,
    int outS, int outOff, int Wpo, int bso, int obase,
    _Float16* __restrict__ part, int partN) {
  constexpr int BM = MF * 32;
  constexpr int BN = NF * 32;
  constexpr int SUB_A = BM * 32;  // halfwords per k-substep
  constexpr int SUB_B = BN * 32;
  __shared__ _Float16 sA[2][SUB_A * KS];
  __shared__ _Float16 sB[2][SUB_B * KS];

  const int tid = threadIdx.x;
  const int lane = tid & 63;
  const int wid = tid >> 6;
  const int wm = wid >> 1, wn = wid & 1;
  const int lr = lane >> 4, lc = lane & 15;
  const int n0 = blockIdx.x * BN;
  const int m0 = blockIdx.y * BM;
  const int H = 1 << lh, W = 1 << lw;
  const int nkb = Cin >> 5;

  int tap0 = 0, ntp = 25;
  if constexpr (SPLIT) {
    tap0 = blockIdx.z ? 13 : 0;
    ntp = blockIdx.z ? 12 : 13;
  }
  const int dy0 = tap0 / 5, dx0 = tap0 - dy0 * 5;

  // staging identity: linear g = issue*256 + tid; row=g>>2, slot=g&3
  const int r0 = tid >> 2;
  const int chunk = (tid & 3) ^ ((r0 >> 1) & 3);  // same for row r0+64

  const _Float16* a0 = wt + ((size_t)tap0 * Cout + m0 + r0) * Cin + (chunk << 3);
  const _Float16* a1 = a0 + ((size_t)Cin << 6);  // used only if BM==128
  const int t0off = (dy0 - 2) * Wpi + (dx0 - 2);
  const _Float16 *b0, *b1 = nullptr;
  {
    int n = n0 + r0;
    int pix0 = (n >> (lw + lh)) * bsi + ((n >> lw) & (H - 1)) * Wpi + (n & (W - 1)) + ibase;
    b0 = in + (size_t)(pix0 + t0off) * inS + (chunk << 3);
    if constexpr (BN == 128) {
      n = n0 + r0 + 64;
      int pix1 = (n >> (lw + lh)) * bsi + ((n >> lw) & (H - 1)) * Wpi + (n & (W - 1)) + ibase;
      b1 = in + (size_t)(pix1 + t0off) * inS + (chunk << 3);
    }
  }

  // ds_read fragment swizzle (halfwords)
  const int swz = (lr ^ ((lc >> 1) & 3)) << 3;

  f32x4 acc[MF][NF];
  const f32x4 vz = {0.f, 0.f, 0.f, 0.f};
#pragma unroll
  for (int i = 0; i < MF; ++i)
#pragma unroll
    for (int j = 0; j < NF; ++j) acc[i][j] = vz;

  const int np = ntp * nkb / KS;  // staged groups
  int kb = 0, dx = dx0;
  const size_t a_tap = (size_t)Cout * Cin - ((size_t)nkb << 5);
  const int woff = wid << 9;  // wave LDS base within a 4KB issue (halfwords)

  // advance staging pointers by one group (KS k-steps)
  auto advance = [&]() {
    a0 += 32 * KS; b0 += 32 * KS;
    if constexpr (BM == 128) a1 += 32 * KS;
    if constexpr (BN == 128) b1 += 32 * KS;
    kb += KS;
    if (kb == nkb) {
      kb = 0;
      a0 += a_tap;
      if constexpr (BM == 128) a1 += a_tap;
      int pd;
      if (++dx == 5) { dx = 0; pd = Wpi - 4; } else pd = 1;
      const ptrdiff_t bd = (ptrdiff_t)pd * inS - ((ptrdiff_t)nkb << 5);
      b0 += bd;
      if constexpr (BN == 128) b1 += bd;
    }
  };
  auto stage = [&](int buf) {
#pragma unroll
    for (int s = 0; s < KS; ++s) {
      _Float16* sa = sA[buf] + s * SUB_A + woff;
      _Float16* sb = sB[buf] + s * SUB_B + woff;
      load_lds16(a0 + 32 * s, sa);
      if constexpr (BM == 128) load_lds16(a1 + 32 * s, sa + 2048);
      load_lds16(b0 + 32 * s, sb);
      if constexpr (BN == 128) load_lds16(b1 + 32 * s, sb + 2048);
    }
  };

  // prologue: stage group 0 into buf 0
  stage(0);
  __syncthreads();

  int cur = 0;
  for (int t = 0; t < np; ++t) {
    if (t + 1 < np) {
      advance();
      stage(cur ^ 1);
    }
    const _Float16* pA = sA[cur];
    const _Float16* pB = sB[cur];
#pragma unroll
    for (int s = 0; s < KS; ++s) {
      f16x8 af[MF], bf[NF];
#pragma unroll
      for (int i = 0; i < MF; ++i)
        af[i] = *(const f16x8*)(pA + s * SUB_A + ((wm * (MF * 16) + (i << 4) + lc) << 5) + swz);
#pragma unroll
      for (int i = 0; i < NF; ++i)
        bf[i] = *(const f16x8*)(pB + s * SUB_B + ((wn * (NF * 16) + (i << 4) + lc) << 5) + swz);
#pragma unroll
      for (int mi = 0; mi < MF; ++mi)
#pragma unroll
        for (int ni = 0; ni < NF; ++ni)
          acc[mi][ni] =
              __builtin_amdgcn_mfma_f32_16x16x32_f16(af[mi], bf[ni], acc[mi][ni], 0, 0, 0);
    }
    __syncthreads();  // drains stage(cur^1) loads + fences buf reuse
    cur ^= 1;
  }

  // Epilogue
  if constexpr (SPLIT) {
    _Float16* pp = part + (size_t)blockIdx.z * partN;
#pragma unroll
    for (int mi = 0; mi < MF; ++mi) {
      const int ob = m0 + wm * (MF * 16) + (mi << 4) + (lr << 2);
#pragma unroll
      for (int ni = 0; ni < NF; ++ni) {
        const int n = n0 + wn * (NF * 16) + (ni << 4) + lc;
        f16x4 h;
#pragma unroll
        for (int j = 0; j < 4; ++j) h[j] = (_Float16)acc[mi][ni][j];
        *(f16x4*)(pp + (size_t)n * Cout + ob) = h;
      }
    }
  } else {
#pragma unroll
    for (int mi = 0; mi < MF; ++mi) {
      const int ob = m0 + wm * (MF * 16) + (mi << 4) + (lr << 2);
      const f32x4 gv = *(const f32x4*)(gg + ob);
      const f32x4 bv = *(const f32x4*)(bbv + ob);
      const f32x4 evv = *(const f32x4*)(ev + ob);
#pragma unroll
      for (int ni = 0; ni < NF; ++ni) {
        const int n = n0 + wn * (NF * 16) + (ni << 4) + lc;
        const int y = (n >> lw) & (H - 1);
        const int x = n & (W - 1);
        const int bb_ = n >> (lw + lh);
        const size_t op = (size_t)(bb_ * bso + y * Wpo + x + obase) * outS + outOff + ob;
        f16x4 h;
#pragma unroll
        for (int j = 0; j < 4; ++j) {
          const float s = gv[j] * BN_S;
          float v = acc[mi][ni][j] + (bv[j] * s + evv[j]);
          v = v > 0.f ? v : 0.f;
          h[j] = (_Float16)v;
        }
        *(f16x4*)(out + op) = h;
      }
    }
  }
}

// ---------------------------------------------------------------------------
// reduce split partials: sum 2 fp16 partials + BN + ReLU -> NHWC fp16 out
// ---------------------------------------------------------------------------
__global__ void reduce_k(const _Float16* __restrict__ part, _Float16* __restrict__ out,
                         const float* __restrict__ g, const float* __restrict__ b,
                         const float* __restrict__ e, int partN,
                         int lw, int lh, int outS, int outOff,
                         int Wpo, int bso, int obase, int total) {
  const int idx = blockIdx.x * 256 + threadIdx.x;
  if (idx >= total) return;
  const int i4 = idx << 2;
  const int n = i4 >> 9;        // Cout = 512
  const int ob = i4 & 511;
  const f16x4 p0 = *(const f16x4*)(part + i4);
  const f16x4 p1 = *(const f16x4*)(part + partN + i4);
  const f32x4 gv = *(const f32x4*)(g + ob);
  const f32x4 bv = *(const f32x4*)(b + ob);
  const f32x4 ev = *(const f32x4*)(e + ob);
  const int H = 1 << lh, W = 1 << lw;
  const int y = (n >> lw) & (H - 1);
  const int x = n & (W - 1);
  const int bb_ = n >> (lw + lh);
  const size_t op = (size_t)(bb_ * bso + y * Wpo + x + obase) * outS + outOff + ob;
  f16x4 h;
#pragma unroll
  for (int j = 0; j < 4; ++j) {
    const float s = gv[j] * BN_S;
    float v = (float)p0[j] + (float)p1[j] + (bv[j] * s + ev[j]);
    v = v > 0.f ? v : 0.f;
    h[j] = (_Float16)v;
  }
  *(f16x4*)(out + op) = h;
}

// ---------------------------------------------------------------------------
// conv1: Cin=3, Cout=64, 512x512, fp32 NCHW data + raw fp32 weights.
// ---------------------------------------------------------------------------
__global__ __launch_bounds__(256) void conv1_k(
    const float* __restrict__ data, const float* __restrict__ w1,
    const float* __restrict__ g1, const float* __restrict__ b1,
    const float* __restrict__ e1, _Float16* __restrict__ out) {
  __shared__ float patch[3][20][20];
  const int tid = threadIdx.x;
  const int bid = blockIdx.x;
  const int tx = bid & 31, ty = (bid >> 5) & 31, b = bid >> 10;

  for (int i = tid; i < 1200; i += 256) {
    const int c = i / 400;
    const int r = i - c * 400;
    const int pyy = r / 20;
    const int pxx = r - pyy * 20;
    const int gy = (ty << 4) + pyy - 2, gx = (tx << 4) + pxx - 2;
    float v = 0.f;
    if ((unsigned)gy < 512u && (unsigned)gx < 512u)
      v = data[((size_t)(b * 3 + c) << 18) + (gy << 9) + gx];
    patch[c][pyy][pxx] = v;
  }
  __syncthreads();

  const int py = tid >> 4, px = tid & 15;
  float acc[64];
#pragma unroll
  for (int o = 0; o < 64; ++o) acc[o] = 0.f;

  for (int c = 0; c < 3; ++c)
    for (int dy = 0; dy < 5; ++dy) {
#pragma unroll
      for (int dx = 0; dx < 5; ++dx) {
        const float v = patch[c][py + dy][px + dx];
        const float* wb = w1 + c * 25 + dy * 5 + dx;
#pragma unroll
        for (int o = 0; o < 64; ++o) acc[o] = fmaf(v, wb[o * 75], acc[o]);
      }
    }

  const int y = (ty << 4) + py, x = (tx << 4) + px;
  _Float16* op = out + ((size_t)(((b << 9) + y) << 9) + x) * 64;
#pragma unroll
  for (int oc = 0; oc < 8; ++oc) {
    f16x8 h;
#pragma unroll
    for (int j = 0; j < 8; ++j) {
      const int o = (oc << 3) + j;
      const float s = g1[o] * BN_S;
      const float t = b1[o] * s + e1[o];
      float v = fmaf(acc[o], s, t);
      v = v > 0.f ? v : 0.f;
      h[j] = (_Float16)v;
    }
    *(f16x8*)(op + (oc << 3)) = h;
  }
}

// ---------------------------------------------------------------------------
// avg-pool 2x2 stride 2, NHWC fp16, generic padded/unpadded addressing
// ---------------------------------------------------------------------------
__global__ void pool_k(const _Float16* __restrict__ in, _Float16* __restrict__ out,
                       int inS, int outS, int Wpi, int bsi, int ibase,
                       int Wpo, int bso, int obase,
                       int lwo, int lho, int lcc, int total) {
  const int idx = blockIdx.x * 256 + threadIdx.x;
  if (idx >= total) return;
  const int cc = idx & ((1 << lcc) - 1);
  const int pix = idx >> lcc;
  const int x = pix & ((1 << lwo) - 1);
  const int y = (pix >> lwo) & ((1 << lho) - 1);
  const int b = pix >> (lwo + lho);
  const int ip = b * bsi + (y << 1) * Wpi + (x << 1) + ibase;
  const _Float16* p = in + (size_t)ip * inS + (cc << 3);
  const f16x8 v00 = *(const f16x8*)p;
  const f16x8 v01 = *(const f16x8*)(p + inS);
  const f16x8 v10 = *(const f16x8*)(p + (size_t)Wpi * inS);
  const f16x8 v11 = *(const f16x8*)(p + (size_t)(Wpi + 1) * inS);
  f16x8 r;
#pragma unroll
  for (int j = 0; j < 8; ++j)
    r[j] = (_Float16)(((float)v00[j] + (float)v01[j] + (float)v10[j] + (float)v11[j]) * 0.25f);
  const int op = b * bso + y * Wpo + x + obase;
  *(f16x8*)(out + (size_t)op * outS + (cc << 3)) = r;
}

// ---------------------------------------------------------------------------
// bilinear 2x upsample (align_corners=True), NHWC fp16
// ---------------------------------------------------------------------------
__global__ void up_k(const _Float16* __restrict__ in, _Float16* __restrict__ out,
                     int inS, int outS, int outOff,
                     int Wpi, int bsi, int ibase,
                     int Wpo, int bso, int obase,
                     int lwi, int lhi, int lcc, float scale, int total) {
  const int idx = blockIdx.x * 256 + threadIdx.x;
  if (idx >= total) return;
  const int cc = idx & ((1 << lcc) - 1);
  const int pix = idx >> lcc;
  const int lwo = lwi + 1, lho = lhi + 1;
  const int ox = pix & ((1 << lwo) - 1);
  const int oy = (pix >> lwo) & ((1 << lho) - 1);
  const int b = pix >> (lwo + lho);
  const int Hi = 1 << lhi, Wi = 1 << lwi;
  const float fy = oy * scale;
  const int y0 = (int)fy;
  const float wy = fy - y0;
  const int y1 = min(y0 + 1, Hi - 1);
  const float fx = ox * scale;
  const int x0 = (int)fx;
  const float wx = fx - x0;
  const int x1 = min(x0 + 1, Wi - 1);
  const int rbase = b * bsi + ibase;
  const _Float16* basep = in + (cc << 3);
  const f16x8 v00 = *(const f16x8*)(basep + (size_t)(rbase + y0 * Wpi + x0) * inS);
  const f16x8 v01 = *(const f16x8*)(basep + (size_t)(rbase + y0 * Wpi + x1) * inS);
  const f16x8 v10 = *(const f16x8*)(basep + (size_t)(rbase + y1 * Wpi + x0) * inS);
  const f16x8 v11 = *(const f16x8*)(basep + (size_t)(rbase + y1 * Wpi + x1) * inS);
  f16x8 r;
#pragma unroll
  for (int j = 0; j < 8; ++j) {
    const float top = (float)v00[j] * (1.f - wx) + (float)v01[j] * wx;
    const float bot = (float)v10[j] * (1.f - wx) + (float)v11[j] * wx;
    r[j] = (_Float16)(top * (1.f - wy) + bot * wy);
  }
  const int op = b * bso + oy * Wpo + ox + obase;
  *(f16x8*)(out + (size_t)op * outS + outOff + (cc << 3)) = r;
}

// ---------------------------------------------------------------------------
// conv8 (LDS-tiled): Cin=384 (= c2[128ch] ++ up7[256ch]), Cout=3, 256x256.
// r16: weights ALSO staged in LDS (double-buffered, same parity/barrier
// structure) -> compute reads are wave-uniform ds_read broadcasts instead
// of ~3600 per-thread global loads (the VMEM-issue bottleneck).
// ---------------------------------------------------------------------------
__global__ __launch_bounds__(256) void conv8_lds(
    const _Float16* __restrict__ inA, const _Float16* __restrict__ inB,
    const _Float16* __restrict__ wt, const float* __restrict__ b8,
    const float* __restrict__ g8, const float* __restrict__ e8,
    _Float16* __restrict__ out) {
  __shared__ f16x8 patch[2][20][20];
  __shared__ f16x8 wldsv[2][76];  // 75 used: 600 halfwords per chunk
  const int tid = threadIdx.x;
  const int bid = blockIdx.x;  // 512
  const int tx = bid & 15, ty = (bid >> 4) & 15, b = bid >> 8;
  const int px = tid & 15, py = tid >> 4;
  const int x0 = tx << 4, y0 = ty << 4;

  float a0 = 0.f, a1 = 0.f, a2 = 0.f;
  for (int c = 0; c < 48; ++c) {
    const _Float16* sbase;
    int str;
    if (c < 16) { sbase = inA + ((size_t)b << 23) + (c << 3); str = 128; }
    else        { sbase = inB + ((size_t)b << 24) + ((c - 16) << 3); str = 256; }
    for (int i = tid; i < 475; i += 256) {
      if (i < 400) {
        const int pyy = i / 20, pxx = i - pyy * 20;
        const int gy = y0 + pyy - 2, gx = x0 + pxx - 2;
        f16x8 v = f16x8_zero();
        if ((unsigned)gy < 256u && (unsigned)gx < 256u)
          v = *(const f16x8*)(sbase + (size_t)((gy << 8) + gx) * str);
        patch[c & 1][pyy][pxx] = v;
      } else {
        const int wj = i - 400;  // 0..74
        wldsv[c & 1][wj] = *(const f16x8*)(wt + c * 600 + (wj << 3));
      }
    }
    __syncthreads();
    const _Float16* wb_c = (const _Float16*)wldsv[c & 1];
#pragma unroll
    for (int dy = 0; dy < 5; ++dy) {
#pragma unroll
      for (int dxx = 0; dxx < 5; ++dxx) {
        const f16x8 v = patch[c & 1][py + dy][px + dxx];
        const _Float16* wb = wb_c + (dy * 5 + dxx) * 24;
#pragma unroll
        for (int j = 0; j < 8; ++j) {
          const float f = (float)v[j];
          a0 = fmaf(f, (float)wb[j], a0);
          a1 = fmaf(f, (float)wb[8 + j], a1);
          a2 = fmaf(f, (float)wb[16 + j], a2);
        }
      }
    }
    // no trailing barrier: parity dbuf + next iteration's barrier fences reuse
  }

  const float s0 = g8[0] * BN_S, t0 = b8[0] * s0 + e8[0];
  const float s1 = g8[1] * BN_S, t1 = b8[1] * s1 + e8[1];
  const float s2 = g8[2] * BN_S, t2 = b8[2] * s2 + e8[2];
  float r0 = a0 + t0, r1 = a1 + t1, r2 = a2 + t2;
  r0 = r0 > 0.f ? r0 : 0.f;
  r1 = r1 > 0.f ? r1 : 0.f;
  r2 = r2 > 0.f ? r2 : 0.f;
  f16x4 h;
  h[0] = (_Float16)r0; h[1] = (_Float16)r1; h[2] = (_Float16)r2; h[3] = (_Float16)0.f;
  const int opix = (b << 16) + ((y0 + py) << 8) + (x0 + px);
  *(f16x4*)(out + (size_t)opix * 4) = h;
}

// ---------------------------------------------------------------------------
// final: bilinear up(c8, 256->512) + 1x1 conv (wo,bo) + out = data*core (fp32)
// ---------------------------------------------------------------------------
__global__ void final_k(const float* __restrict__ data, const _Float16* __restrict__ c8,
                        const float* __restrict__ wo, const float* __restrict__ bo,
                        float* __restrict__ out) {
  const int idx = blockIdx.x * 256 + threadIdx.x;  // < 524288
  const int x = idx & 511, y = (idx >> 9) & 511, b = idx >> 18;
  const float sc = 255.f / 511.f;
  const float fy = y * sc;
  const int y0 = (int)fy;
  const float wy = fy - y0;
  const int y1 = min(y0 + 1, 255);
  const float fx = x * sc;
  const int x0 = (int)fx;
  const float wx = fx - x0;
  const int x1 = min(x0 + 1, 255);
  const f16x4 v00 = *(const f16x4*)(c8 + (size_t)((((b << 8) + y0) << 8) + x0) * 4);
  const f16x4 v01 = *(const f16x4*)(c8 + (size_t)((((b << 8) + y0) << 8) + x1) * 4);
  const f16x4 v10 = *(const f16x4*)(c8 + (size_t)((((b << 8) + y1) << 8) + x0) * 4);
  const f16x4 v11 = *(const f16x4*)(c8 + (size_t)((((b << 8) + y1) << 8) + x1) * 4);
  float u[3];
#pragma unroll
  for (int j = 0; j < 3; ++j) {
    const float top = (float)v00[j] * (1.f - wx) + (float)v01[j] * wx;
    const float bot = (float)v10[j] * (1.f - wx) + (float)v11[j] * wx;
    u[j] = top * (1.f - wy) + bot * wy;
  }
#pragma unroll
  for (int c = 0; c < 3; ++c) {
    const float core = bo[c] + wo[c * 3 + 0] * u[0] + wo[c * 3 + 1] * u[1] + wo[c * 3 + 2] * u[2];
    const size_t oi = ((size_t)(b * 3 + c) << 18) + (y << 9) + x;
    out[oi] = data[oi] * core;
  }
}

// ---------------------------------------------------------------------------
extern "C" void kernel_launch(void* const* d_in, const int* in_sizes, int n_in,
                              void* d_out, int out_size, void* d_ws, size_t ws_size,
                              hipStream_t stream) {
  const float* data = (const float*)d_in[0];
  const float *w[9], *bb[9], *gg[9], *ee[9];
  for (int n = 1; n <= 8; ++n) {
    w[n] = (const float*)d_in[1 + (n - 1) * 4];
    bb[n] = (const float*)d_in[2 + (n - 1) * 4];
    gg[n] = (const float*)d_in[3 + (n - 1) * 4];
    ee[n] = (const float*)d_in[4 + (n - 1) * 4];
  }
  const float* wo = (const float*)d_in[33];
  const float* bo = (const float*)d_in[34];
  float* out = (float*)d_out;
  (void)in_sizes; (void)n_in;

  // ---- workspace layout (aliased; padded activations; 194,810,112 B) ----
  // LIVENESS (r9): cat7's c3-half is live conv3->conv7; don't reuse between.
  // SPLIT partials (r14): part4 -> R1 (free at conv4 time); part5/part6 ->
  // retired W2t..W5t region (dead after conv5; W6t/W7t/W8t untouched).
  const size_t NEEDED = 194810112ull;
  if (ws_size < NEEDED) {
    zero_out_k<<<(out_size + 255) / 256, 256, 0, stream>>>(out, out_size);
    return;
  }
  char* base = (char*)d_ws;
  size_t off = 0;
  auto alloc = [&](size_t bytes) -> char* {
    char* p = base + off;
    off += (bytes + 255) & ~(size_t)255;
    return p;
  };
  _Float16* W2t = (_Float16*)alloc(409600);     // 25*128*64*2
  _Float16* W3t = (_Float16*)alloc(1638400);    // 25*256*128*2
  _Float16* W4t = (_Float16*)alloc(6553600);    // 25*512*256*2
  _Float16* W5t = (_Float16*)alloc(13107200);   // 25*512*512*2
  _Float16* W6t = (_Float16*)alloc(26214400);   // 25*512*1024*2
  _Float16* W7t = (_Float16*)alloc(9830400);    // 25*256*768*2
  _Float16* W8t = (_Float16*)alloc(57600);      // 48*25*24 fp16
  char* Rbig = alloc(72466432);   // c1(67.1M) | cat7(53.5M)+cat6(18.9M) | up7(67.1M)
  char* c2b_ = alloc(33554432);   // c2 (2,256,256,128) unpadded
  char* R1 = alloc(17305600);     // p1(17.3M) | part4(16.8M) | c6(8.4M) | c7(16.8M) | c8(1M)
  char* R2 = alloc(13672448);     // p2(8.9M) ; [p3(4.7M) | p4(2.65M)+c5(2.1M)]

  _Float16* c1 = (_Float16*)Rbig;                    // (2,512,512,64) unpadded
  _Float16* cat7 = (_Float16*)Rbig;                  // (2,132,132,768) padded
  _Float16* cat6 = (_Float16*)(Rbig + 53526528);     // (2,68,68,1024) padded
  _Float16* up7b = (_Float16*)Rbig;                  // (2,256,256,256) unpadded
  _Float16* c2buf = (_Float16*)c2b_;                 // (2,256,256,128) unpadded
  _Float16* p1 = (_Float16*)R1;                      // (2,260,260,64) padded
  _Float16* part4 = (_Float16*)R1;                   // [2][8192][512] fp16 (16.8M)
  _Float16* c6 = (_Float16*)R1;                      // (2,64,64,512) unpadded
  _Float16* c7 = (_Float16*)R1;                      // (2,128,128,256) unpadded
  _Float16* c8 = (_Float16*)R1;                      // (2,256,256,4) unpadded
  _Float16* part56 = (_Float16*)base;                // part5/part6 over dead W2t..W5t
  _Float16* p2 = (_Float16*)R2;                      // (2,132,132,128) padded
  _Float16* p3 = (_Float16*)(R2 + 8921088);          // (2,68,68,256) padded
  _Float16* p4 = (_Float16*)(R2 + 8921088);          // (2,36,36,512) padded (aliases p3!)
  _Float16* c5 = (_Float16*)(R2 + 8921088 + 2654208);// (2,32,32,512) unpadded

  // halo-only zeroing (interiors fully overwritten by producers; r13 audit).
  halo_k<<<(33024 + 255) / 256, 256, 0, stream>>>(p1, 260, 8, 16512, 33024);
  halo_k<<<(33280 + 255) / 256, 256, 0, stream>>>(p2, 132, 16, 16640, 33280);
  halo_k<<<(33792 + 255) / 256, 256, 0, stream>>>(p3, 68, 32, 16896, 33792);

  // weight transforms (fold BN scale into weights)
  wtrans16<<<(128 * 64 + 255) / 256, 256, 0, stream>>>(w[2], W2t, gg[2], 128, 64, 128 * 64);
  wtrans16<<<(256 * 128 + 255) / 256, 256, 0, stream>>>(w[3], W3t, gg[3], 256, 128, 256 * 128);
  wtrans16<<<(512 * 256 + 255) / 256, 256, 0, stream>>>(w[4], W4t, gg[4], 512, 256, 512 * 256);
  wtrans16<<<(512 * 512 + 255) / 256, 256, 0, stream>>>(w[5], W5t, gg[5], 512, 512, 512 * 512);
  wtrans16<<<(512 * 1024 + 255) / 256, 256, 0, stream>>>(w[6], W6t, gg[6], 512, 1024, 512 * 1024);
  wtrans16<<<(256 * 768 + 255) / 256, 256, 0, stream>>>(w[7], W7t, gg[7], 256, 768, 256 * 768);
  wtrans8<<<(28800 + 255) / 256, 256, 0, stream>>>(w[8], W8t, gg[8]);

  conv1_k<<<2048, 256, 0, stream>>>(data, w[1], gg[1], bb[1], ee[1], c1);
  pool_k<<<1048576 / 256, 256, 0, stream>>>(c1, p1, 64, 64, 512, 262144, 0,
                                            260, 67600, 522, 8, 8, 3, 1048576);
  // c1 dead -> zero cat7/cat6 halos (they alias c1's region)
  halo_k<<<(199680 + 255) / 256, 256, 0, stream>>>(cat7, 132, 96, 99840, 199680);
  halo_k<<<(135168 + 255) / 256, 256, 0, stream>>>(cat6, 68, 128, 67584, 135168);

  conv_gemm<4, 4, 1, 2, false><<<dim3(1024, 1), 256, 0, stream>>>(p1, W2t, gg[2], bb[2], ee[2], c2buf,
      64, 128, 8, 8, 64, 260, 67600, 522, 128, 0, 256, 65536, 0, nullptr, 0);
  pool_k<<<524288 / 256, 256, 0, stream>>>(c2buf, p2, 128, 128, 256, 65536, 0,
                                           132, 17424, 266, 7, 7, 4, 524288);
  // conv3: act(8.9M) > wt(1.6M) -> keep BM=128
  conv_gemm<4, 4, 2, 3, false><<<dim3(256, 2), 256, 0, stream>>>(p2, W3t, gg[3], bb[3], ee[3], cat7,
      128, 256, 7, 7, 128, 132, 17424, 266, 768, 0, 132, 17424, 266, nullptr, 0);
  pool_k<<<262144 / 256, 256, 0, stream>>>(cat7, p3, 768, 256, 132, 17424, 266,
                                           68, 4624, 138, 6, 6, 5, 262144);
  // conv4: split-K 2-way (1024 blocks, 3/CU) -> fp16 partials in R1
  conv_gemm<2, 4, 2, 4, true><<<dim3(64, 8, 2), 256, 0, stream>>>(p3, W4t, gg[4], bb[4], ee[4], cat6,
      256, 512, 6, 6, 256, 68, 4624, 138, 1024, 0, 68, 4624, 138, part4, 4194304);
  reduce_k<<<1048576 / 256, 256, 0, stream>>>(part4, cat6, gg[4], bb[4], ee[4], 4194304,
                                              6, 6, 1024, 0, 68, 4624, 138, 1048576);
  // p3 dead -> now safe to zero p4's halo (p4 aliases p3's bytes)
  halo_k<<<(34816 + 255) / 256, 256, 0, stream>>>(p4, 36, 64, 17408, 34816);
  pool_k<<<131072 / 256, 256, 0, stream>>>(cat6, p4, 1024, 512, 68, 4624, 138,
                                           36, 1296, 74, 5, 5, 6, 131072);
  // conv5: split-K 2-way (512 blocks) -> fp16 partials over dead W2t..W4t
  conv_gemm<2, 2, 2, 5, true><<<dim3(32, 8, 2), 256, 0, stream>>>(p4, W5t, gg[5], bb[5], ee[5], c5,
      512, 512, 5, 5, 512, 36, 1296, 74, 512, 0, 32, 1024, 0, part56, 1048576);
  reduce_k<<<262144 / 256, 256, 0, stream>>>(part56, c5, gg[5], bb[5], ee[5], 1048576,
                                             5, 5, 512, 0, 32, 1024, 0, 262144);
  up_k<<<524288 / 256, 256, 0, stream>>>(c5, cat6, 512, 1024, 512,
                                         32, 1024, 0, 68, 4624, 138,
                                         5, 5, 6, 31.f / 63.f, 524288);
  // conv6: split-K 2-way (1024 blocks, 3/CU) -> fp16 partials over dead W2t..W5t
  conv_gemm<2, 4, 2, 6, true><<<dim3(64, 8, 2), 256, 0, stream>>>(cat6, W6t, gg[6], bb[6], ee[6], c6,
      1024, 512, 6, 6, 1024, 68, 4624, 138, 512, 0, 64, 4096, 0, part56, 4194304);
  reduce_k<<<1048576 / 256, 256, 0, stream>>>(part56, c6, gg[6], bb[6], ee[6], 4194304,
                                              6, 6, 512, 0, 64, 4096, 0, 1048576);
  up_k<<<2097152 / 256, 256, 0, stream>>>(c6, cat7, 512, 768, 256,
                                          64, 4096, 0, 132, 17424, 266,
                                          6, 6, 6, 63.f / 127.f, 2097152);
  // conv7: act(53.5M) > wt(9.8M) -> keep BM=128, no split (r11)
  conv_gemm<4, 4, 2, 7, false><<<dim3(256, 2), 256, 0, stream>>>(cat7, W7t, gg[7], bb[7], ee[7], c7,
      768, 256, 7, 7, 768, 132, 17424, 266, 256, 0, 128, 16384, 0, nullptr, 0);
  up_k<<<4194304 / 256, 256, 0, stream>>>(c7, up7b, 256, 256, 0,
                                          128, 16384, 0, 256, 65536, 0,
                                          7, 7, 5, 127.f / 255.f, 4194304);
  conv8_lds<<<512, 256, 0, stream>>>(c2buf, up7b, W8t, bb[8], gg[8], ee[8], c8);
  final_k<<<524288 / 256, 256, 0, stream>>>(data, c8, wo, bo, out);
}